// Round 5
// baseline (873.054 us; speedup 1.0000x reference)
//
#include <hip/hip_runtime.h>
#include <math.h>
#include <stdint.h>

#define M_NODES 8192
#define E_DIM   512
#define NTOPK   6
#define ATTN_SCALE 0.04419417382415922f  // 512^-0.5
#define NEG_BIG (-1e38f)
#define BAND    1024

typedef __attribute__((ext_vector_type(8))) short short8;
typedef __attribute__((ext_vector_type(4))) float f32x4;

__device__ __forceinline__ float lrelu(float v) { return v > 0.f ? v : 0.01f * v; }

__device__ __forceinline__ unsigned short f2bf(float f) {
  uint32_t u = __float_as_uint(f);
  uint32_t r = (u + 0x7FFFu + ((u >> 16) & 1u)) >> 16;
  return (unsigned short)r;
}
__device__ __forceinline__ float bf2f(unsigned short s) {
  return __uint_as_float(((uint32_t)s) << 16);
}

// async 16B/lane global->LDS (wave-uniform LDS base, lane i lands at base+16i)
__device__ __forceinline__ void async_cp16(const void* gptr, void* lds) {
  auto g1 = reinterpret_cast<const __attribute__((address_space(1))) unsigned int*>(
      reinterpret_cast<uintptr_t>(gptr));
  auto l3 = reinterpret_cast<__attribute__((address_space(3))) unsigned int*>(
      reinterpret_cast<uintptr_t>(lds));
  __builtin_amdgcn_global_load_lds(g1, l3, 16, 0, 0);
}

// tiled bf16 layout: value (m,k), Ktiles=K/32:
//   idx = ((m>>4)*Ktiles + (k>>5))*512 + ((m&15) + 16*((k>>3)&3))*8 + (k&7)

// ---------------------------------------------------------------------------
// Cast fp32 x + 6 weight matrices into bf16 frag-tiled layout.
// ---------------------------------------------------------------------------
__global__ __launch_bounds__(256) void wcast_kernel(
    const float* __restrict__ x, const float* __restrict__ fc1w,
    const float* __restrict__ whw, const float* __restrict__ wtw,
    const float* __restrict__ l1w, const float* __restrict__ l2w,
    const float* __restrict__ a1w,
    unsigned short* __restrict__ xT, unsigned short* __restrict__ fc1T,
    unsigned short* __restrict__ whT, unsigned short* __restrict__ wtT,
    unsigned short* __restrict__ l1T, unsigned short* __restrict__ l2T,
    unsigned short* __restrict__ a1T)
{
  const int gid = blockIdx.x * 256 + threadIdx.x;  // 0 .. 565247
  const float* src; unsigned short* dst; int K8, local;
  if (gid < 417792) {
    K8 = 48;
    if (gid < 393216) { src = x; dst = xT; local = gid; }
    else { src = fc1w; dst = fc1T; local = gid - 393216; }
  } else {
    K8 = 64;
    if (gid < 450560)      { src = whw; dst = whT; local = gid - 417792; }
    else if (gid < 483328) { src = wtw; dst = wtT; local = gid - 450560; }
    else if (gid < 516096) { src = l1w; dst = l1T; local = gid - 483328; }
    else if (gid < 548864) { src = l2w; dst = l2T; local = gid - 516096; }
    else                   { src = a1w; dst = a1T; local = gid - 548864; }
  }
  const int m = local / K8;
  const int k8 = local - m * K8;
  const float* p = src + (size_t)m * (K8 * 8) + k8 * 8;
  float4 v0 = ((const float4*)p)[0];
  float4 v1 = ((const float4*)p)[1];
  const int Kt = K8 >> 2;
  const size_t ti = ((size_t)(m >> 4) * Kt + (k8 >> 2)) * 512 + ((m & 15) + 16 * (k8 & 3)) * 8;
  uint4 pk;
  pk.x = (uint32_t)f2bf(v0.x) | ((uint32_t)f2bf(v0.y) << 16);
  pk.y = (uint32_t)f2bf(v0.z) | ((uint32_t)f2bf(v0.w) << 16);
  pk.z = (uint32_t)f2bf(v1.x) | ((uint32_t)f2bf(v1.y) << 16);
  pk.w = (uint32_t)f2bf(v1.z) | ((uint32_t)f2bf(v1.w) << 16);
  *(uint4*)(dst + ti) = pk;
}

// ---------------------------------------------------------------------------
// MFMA GEMM, tile 128(M) x 64(N), 4 waves each 32x64, K-step 32.
// MODE 0: Cf fp32 = lrelu(A@W1^T + b1)
// MODE 1: T1 = bf16(A@W1^T+b1) tiled ; T2 = bf16(A@W2^T+b2) tiled  (no fp32 out)
// MODE 2: e = lrelu(A1@W1^T+b1)+lrelu(A2@W2^T+b2) ; T1 = bf16(e) tiled ;
//         Cbf = bf16(e) row-major
// ---------------------------------------------------------------------------
template <int MODE>
__global__ __launch_bounds__(256) void mfma_gemm(
    const unsigned short* __restrict__ At1, const unsigned short* __restrict__ At2,
    const unsigned short* __restrict__ Wt1, const unsigned short* __restrict__ Wt2,
    const float* __restrict__ b1, const float* __restrict__ b2,
    float* __restrict__ Cf, unsigned short* __restrict__ T1,
    unsigned short* __restrict__ T2, unsigned short* __restrict__ Cbf,
    int N, int K)
{
  __shared__ unsigned short As[2][8 * 512];
  __shared__ unsigned short Bs[2][4 * 512];
  const int Kt = K >> 5;
  const int tid = threadIdx.x, lane = tid & 63, w = tid >> 6;
  const int m0 = blockIdx.y * 128, n0 = blockIdx.x * 64;

  f32x4 acc0[2][4], acc1[2][4];
#pragma unroll
  for (int p = 0; p < 2; p++)
#pragma unroll
    for (int j = 0; j < 4; j++) {
      acc0[p][j] = (f32x4){0.f, 0.f, 0.f, 0.f};
      acc1[p][j] = (f32x4){0.f, 0.f, 0.f, 0.f};
    }

  for (int kt = 0; kt < Kt; kt++) {
    const unsigned short* a1p = At1 + ((size_t)((m0 >> 4) + 2 * w) * Kt + kt) * 512 + lane * 8;
    async_cp16(a1p, &As[0][(2 * w) * 512]);
    async_cp16(a1p + (size_t)Kt * 512, &As[0][(2 * w + 1) * 512]);
    if (MODE == 2) {
      const unsigned short* a2p = At2 + ((size_t)((m0 >> 4) + 2 * w) * Kt + kt) * 512 + lane * 8;
      async_cp16(a2p, &As[1][(2 * w) * 512]);
      async_cp16(a2p + (size_t)Kt * 512, &As[1][(2 * w + 1) * 512]);
    }
    const unsigned short* bp1 = Wt1 + ((size_t)((n0 >> 4) + w) * Kt + kt) * 512 + lane * 8;
    async_cp16(bp1, &Bs[0][w * 512]);
    if (MODE >= 1) {
      const unsigned short* bp2 = Wt2 + ((size_t)((n0 >> 4) + w) * Kt + kt) * 512 + lane * 8;
      async_cp16(bp2, &Bs[1][w * 512]);
    }
    __syncthreads();
    short8 a[2], a2[2], bb[4], bb2[4];
#pragma unroll
    for (int p = 0; p < 2; p++) a[p] = *(const short8*)&As[0][(2 * w + p) * 512 + lane * 8];
    if (MODE == 2) {
#pragma unroll
      for (int p = 0; p < 2; p++) a2[p] = *(const short8*)&As[1][(2 * w + p) * 512 + lane * 8];
    }
#pragma unroll
    for (int j = 0; j < 4; j++) bb[j] = *(const short8*)&Bs[0][j * 512 + lane * 8];
    if (MODE >= 1) {
#pragma unroll
      for (int j = 0; j < 4; j++) bb2[j] = *(const short8*)&Bs[1][j * 512 + lane * 8];
    }
#pragma unroll
    for (int p = 0; p < 2; p++)
#pragma unroll
      for (int j = 0; j < 4; j++) {
        acc0[p][j] = __builtin_amdgcn_mfma_f32_16x16x32_bf16(a[p], bb[j], acc0[p][j], 0, 0, 0);
        if (MODE == 1)
          acc1[p][j] = __builtin_amdgcn_mfma_f32_16x16x32_bf16(a[p], bb2[j], acc1[p][j], 0, 0, 0);
        if (MODE == 2)
          acc1[p][j] = __builtin_amdgcn_mfma_f32_16x16x32_bf16(a2[p], bb2[j], acc1[p][j], 0, 0, 0);
      }
    __syncthreads();
  }

  const int lrow = (lane >> 4) * 4, lcol = lane & 15;
  const int NT = N >> 5;
#pragma unroll
  for (int p = 0; p < 2; p++)
#pragma unroll
    for (int j = 0; j < 4; j++) {
      const int c = n0 + j * 16 + lcol;
      const float bias1 = b1[c];
      const float bias2 = (MODE >= 1) ? b2[c] : 0.f;
#pragma unroll
      for (int d = 0; d < 4; d++) {
        const int r = m0 + w * 32 + p * 16 + lrow + d;
        const float v0 = acc0[p][j][d] + bias1;
        if (MODE == 0) {
          Cf[(size_t)r * N + c] = lrelu(v0);
        } else {
          const size_t ti = ((size_t)(r >> 4) * NT + (c >> 5)) * 512 +
                            ((r & 15) + 16 * ((c >> 3) & 3)) * 8 + (c & 7);
          if (MODE == 1) {
            T1[ti] = f2bf(v0);
            T2[ti] = f2bf(acc1[p][j][d] + bias2);
          } else {
            const float e = lrelu(v0) + lrelu(acc1[p][j][d] + bias2);
            T1[ti] = f2bf(e);
            Cbf[(size_t)r * N + c] = f2bf(e);
          }
        }
      }
    }
}

// ---------------------------------------------------------------------------
// Column sum of h over M
// ---------------------------------------------------------------------------
__global__ __launch_bounds__(256) void colsum_kernel(const float* __restrict__ h,
                                                     float* __restrict__ colsum)
{
  const int t = threadIdx.x;
  const int r0 = blockIdx.x * 128;
  float s0 = 0.f, s1 = 0.f;
  for (int r = 0; r < 128; r++) {
    s0 += h[(size_t)(r0 + r) * E_DIM + t];
    s1 += h[(size_t)(r0 + r) * E_DIM + 256 + t];
  }
  atomicAdd(&colsum[t], s0);
  atomicAdd(&colsum[t + 256], s1);
}

// h' = (h + colmean)*0.5 fused with bf16 tiled cast (Ktiles=16)
__global__ __launch_bounds__(256) void hupd_cast_kernel(
    const float* __restrict__ h, const float* __restrict__ colsum,
    unsigned short* __restrict__ hT)
{
  const int gid = blockIdx.x * 256 + threadIdx.x;  // 8192*64
  const int m = gid >> 6, k8 = gid & 63;
  const float* p = h + (size_t)m * E_DIM + k8 * 8;
  float4 v0 = ((const float4*)p)[0];
  float4 v1 = ((const float4*)p)[1];
  float4 c0 = *(const float4*)(colsum + k8 * 8);
  float4 c1 = *(const float4*)(colsum + k8 * 8 + 4);
  const float im = 1.f / (float)M_NODES;
  v0.x = (v0.x + c0.x * im) * 0.5f; v0.y = (v0.y + c0.y * im) * 0.5f;
  v0.z = (v0.z + c0.z * im) * 0.5f; v0.w = (v0.w + c0.w * im) * 0.5f;
  v1.x = (v1.x + c1.x * im) * 0.5f; v1.y = (v1.y + c1.y * im) * 0.5f;
  v1.z = (v1.z + c1.z * im) * 0.5f; v1.w = (v1.w + c1.w * im) * 0.5f;
  const size_t ti = ((size_t)(m >> 4) * 16 + (k8 >> 2)) * 512 + ((m & 15) + 16 * (k8 & 3)) * 8;
  uint4 pk;
  pk.x = (uint32_t)f2bf(v0.x) | ((uint32_t)f2bf(v0.y) << 16);
  pk.y = (uint32_t)f2bf(v0.z) | ((uint32_t)f2bf(v0.w) << 16);
  pk.z = (uint32_t)f2bf(v1.x) | ((uint32_t)f2bf(v1.y) << 16);
  pk.w = (uint32_t)f2bf(v1.z) | ((uint32_t)f2bf(v1.w) << 16);
  *(uint4*)(hT + ti) = pk;
}

// ---------------------------------------------------------------------------
// Score GEMM (one band of 1024 rows): sc[band_row][8192] = bf16(eh . et)
// 128x128 tile, 4 waves each 64x64, BK=32, m97-style 2-barrier K-loop.
// ---------------------------------------------------------------------------
__global__ __launch_bounds__(256) void sgemm_kernel(
    const unsigned short* __restrict__ ehT, const unsigned short* __restrict__ etT,
    unsigned short* __restrict__ sc, int mbase)
{
  __shared__ unsigned short As[8 * 512];
  __shared__ unsigned short Bs[8 * 512];
  __shared__ unsigned short Sc[128 * 136];
  const int tid = threadIdx.x, lane = tid & 63, w = tid >> 6;
  const int wr = w >> 1, wc = w & 1;
  const int m0 = mbase + blockIdx.y * 128;
  const int n0 = blockIdx.x * 128;

  f32x4 acc[4][4];
#pragma unroll
  for (int i = 0; i < 4; i++)
#pragma unroll
    for (int j = 0; j < 4; j++) acc[i][j] = (f32x4){0.f, 0.f, 0.f, 0.f};

  for (int kt = 0; kt < 16; kt++) {
    const int s0 = w, s1 = w + 4;
    async_cp16(ehT + ((size_t)((m0 >> 4) + s0) * 16 + kt) * 512 + lane * 8, &As[s0 * 512]);
    async_cp16(ehT + ((size_t)((m0 >> 4) + s1) * 16 + kt) * 512 + lane * 8, &As[s1 * 512]);
    async_cp16(etT + ((size_t)((n0 >> 4) + s0) * 16 + kt) * 512 + lane * 8, &Bs[s0 * 512]);
    async_cp16(etT + ((size_t)((n0 >> 4) + s1) * 16 + kt) * 512 + lane * 8, &Bs[s1 * 512]);
    __syncthreads();
    short8 a[4], b[4];
#pragma unroll
    for (int i = 0; i < 4; i++) a[i] = *(const short8*)&As[(wr * 4 + i) * 512 + lane * 8];
#pragma unroll
    for (int j = 0; j < 4; j++) b[j] = *(const short8*)&Bs[(wc * 4 + j) * 512 + lane * 8];
#pragma unroll
    for (int i = 0; i < 4; i++)
#pragma unroll
      for (int j = 0; j < 4; j++)
        acc[i][j] = __builtin_amdgcn_mfma_f32_16x16x32_bf16(a[i], b[j], acc[i][j], 0, 0, 0);
    __syncthreads();
  }

  // frags -> LDS bf16 (C layout: col=lane&15, row=quad*4+reg)
  const int lrow = (lane >> 4) * 4, lcol = lane & 15;
#pragma unroll
  for (int i = 0; i < 4; i++) {
    const int row = wr * 64 + i * 16 + lrow;
#pragma unroll
    for (int j = 0; j < 4; j++) {
      const int col = wc * 64 + j * 16 + lcol;
      Sc[(row + 0) * 136 + col] = f2bf(acc[i][j][0]);
      Sc[(row + 1) * 136 + col] = f2bf(acc[i][j][1]);
      Sc[(row + 2) * 136 + col] = f2bf(acc[i][j][2]);
      Sc[(row + 3) * 136 + col] = f2bf(acc[i][j][3]);
    }
  }
  __syncthreads();

  // coalesced store: thread t -> row t>>1, 64-col half t&1
  const int row = tid >> 1, half = tid & 1;
  const unsigned short* src = &Sc[row * 136 + half * 64];
  unsigned short* dst = sc + (size_t)(m0 - mbase + row) * M_NODES + n0 + half * 64;
#pragma unroll
  for (int q = 0; q < 8; q++)
    *(short8*)(dst + q * 8) = *(const short8*)(src + q * 8);
}

// ---------------------------------------------------------------------------
// Streaming top-6 state (predicated sorted-free insert)
// ---------------------------------------------------------------------------
struct Top6 { float v[NTOPK]; int id[NTOPK]; float cmin; int cslot; };
__device__ __forceinline__ void t6_init(Top6& t) {
#pragma unroll
  for (int k = 0; k < NTOPK; k++) { t.v[k] = NEG_BIG; t.id[k] = 0; }
  t.cmin = NEG_BIG; t.cslot = 0;
}
__device__ __forceinline__ void t6_ins(Top6& t, float vv, int ii) {
  if (vv > t.cmin) {
    t.v[t.cslot] = vv; t.id[t.cslot] = ii;
    t.cmin = t.v[0]; t.cslot = 0;
#pragma unroll
    for (int k = 1; k < NTOPK; k++)
      if (t.v[k] < t.cmin) { t.cmin = t.v[k]; t.cslot = k; }
  }
}

// ---------------------------------------------------------------------------
// Parallel top-6 scan: one wave per (row, 2048-col chunk) -> 4096 waves/band.
// Per-lane private top-6 over 32 strided elements, then 6-round shfl_xor
// butterfly merge. Lane 0 writes the chunk list (scaled).
// ---------------------------------------------------------------------------
__global__ __launch_bounds__(256) void scan_topk_kernel(
    const unsigned short* __restrict__ sc, int mbase,
    float* __restrict__ tkv, int* __restrict__ tki)
{
  const int lane = threadIdx.x & 63;
  const int wid = blockIdx.x * 4 + (threadIdx.x >> 6);
  const int row = wid >> 2;
  const int chunk = wid & 3;
  const unsigned short* rp = sc + (size_t)row * M_NODES + chunk * 2048 + lane * 8;

  Top6 t; t6_init(t);
#pragma unroll
  for (int b = 0; b < 4; b++) {
    short8 u = *(const short8*)(rp + b * 512);
    const int cg = chunk * 2048 + b * 512 + lane * 8;
#pragma unroll
    for (int e = 0; e < 8; e++)
      t6_ins(t, bf2f((unsigned short)u[e]), cg + e);
  }
  // butterfly merge across 64 lanes
#pragma unroll
  for (int off = 1; off < 64; off <<= 1) {
    float ov[NTOPK]; int oi[NTOPK];
#pragma unroll
    for (int k = 0; k < NTOPK; k++) {
      ov[k] = __shfl_xor(t.v[k], off);
      oi[k] = __shfl_xor(t.id[k], off);
    }
#pragma unroll
    for (int k = 0; k < NTOPK; k++) t6_ins(t, ov[k], oi[k]);
  }
  if (lane == 0) {
    const size_t base = ((size_t)(mbase + row) * 4 + chunk) * NTOPK;
#pragma unroll
    for (int k = 0; k < NTOPK; k++) {
      tkv[base + k] = t.v[k] * ATTN_SCALE;
      tki[base + k] = t.id[k];
    }
  }
}

// ---------------------------------------------------------------------------
// Per-row combine: merge 4 chunk lists -> top-6, softmax, gather Nb from etT
// (bf16 tiled), gate tanh, ka softmax, e_Nh; write s1=eh+eNh, s2=eh*eNh
// bf16 tiled. One wave per row.
// ---------------------------------------------------------------------------
__global__ __launch_bounds__(256) void combine_kernel(
    const unsigned short* __restrict__ ehT, const unsigned short* __restrict__ etT,
    const float* __restrict__ tkv, const int* __restrict__ tki,
    unsigned short* __restrict__ s1T, unsigned short* __restrict__ s2T)
{
  const int lane = threadIdx.x & 63;
  const int m = blockIdx.x * 4 + (threadIdx.x >> 6);

  Top6 t; t6_init(t);
  const float* lv = tkv + (size_t)m * 24;
  const int* li = tki + (size_t)m * 24;
#pragma unroll
  for (int l = 0; l < 24; l++) t6_ins(t, lv[l], li[l]);

  float wv[NTOPK]; int id[NTOPK];
#pragma unroll
  for (int k = 0; k < NTOPK; k++) { wv[k] = t.v[k]; id[k] = t.id[k]; }

  float mx = wv[0];
#pragma unroll
  for (int k = 1; k < NTOPK; k++) mx = fmaxf(mx, wv[k]);
  float p[NTOPK]; float s = 0.f;
#pragma unroll
  for (int k = 0; k < NTOPK; k++) { p[k] = expf(wv[k] - mx); s += p[k]; }
  const float inv = 1.f / s;
#pragma unroll
  for (int k = 0; k < NTOPK; k++) p[k] *= inv;

  // tiled per-lane addressing: k-dim index = lane + 64*i
  const int wconst_base = 16 * ((lane >> 3) & 3) * 8 + (lane & 7);
  const unsigned short* ep = ehT + ((size_t)(m >> 4) * 16 + (lane >> 5)) * 512 +
                             (m & 15) * 8 + wconst_base;
  float ehv[8];
#pragma unroll
  for (int i = 0; i < 8; i++) ehv[i] = bf2f(ep[i * 1024]);

  float nv[NTOPK][8];
#pragma unroll
  for (int k = 0; k < NTOPK; k++) {
    const int n = id[k];
    const unsigned short* bp = etT + ((size_t)(n >> 4) * 16 + (lane >> 5)) * 512 +
                               (n & 15) * 8 + wconst_base;
#pragma unroll
    for (int i = 0; i < 8; i++) nv[k][i] = bf2f(bp[i * 1024]);
  }

  float ka[NTOPK];
#pragma unroll
  for (int k = 0; k < NTOPK; k++) {
    float snb = 0.f, sg = 0.f;
    const float aa = 2.f - p[k], bb = p[k];
#pragma unroll
    for (int i = 0; i < 8; i++) {
      snb += nv[k][i];
      sg += tanhf(fmaf(aa, ehv[i], bb * nv[k][i]));
    }
#pragma unroll
    for (int off = 32; off; off >>= 1) {
      snb += __shfl_xor(snb, off);
      sg += __shfl_xor(sg, off);
    }
    ka[k] = snb * sg;
  }
  float km = ka[0];
#pragma unroll
  for (int k = 1; k < NTOPK; k++) km = fmaxf(km, ka[k]);
  float kp[NTOPK]; float ks = 0.f;
#pragma unroll
  for (int k = 0; k < NTOPK; k++) { kp[k] = expf(ka[k] - km); ks += kp[k]; }
  const float kinv = 1.f / ks;

  unsigned short* o1 = s1T + ((size_t)(m >> 4) * 16 + (lane >> 5)) * 512 +
                       (m & 15) * 8 + wconst_base;
  unsigned short* o2 = s2T + ((size_t)(m >> 4) * 16 + (lane >> 5)) * 512 +
                       (m & 15) * 8 + wconst_base;
#pragma unroll
  for (int i = 0; i < 8; i++) {
    float o = 0.f;
#pragma unroll
    for (int k = 0; k < NTOPK; k++) o = fmaf(kp[k], nv[k][i], o);
    o *= kinv;
    o1[i * 1024] = f2bf(ehv[i] + o);
    o2[i * 1024] = f2bf(ehv[i] * o);
  }
}

// ---------------------------------------------------------------------------
__global__ __launch_bounds__(256) void gate_g_kernel(
    const float* __restrict__ ahid, const float* __restrict__ a2w,
    const float* __restrict__ a2b, float* __restrict__ g)
{
  const int lane = threadIdx.x & 63;
  const int m = blockIdx.x * 4 + (threadIdx.x >> 6);
  float s = 0.f;
  for (int j = lane; j < 256; j += 64)
    s = fmaf(a2w[j], ahid[(size_t)m * 256 + j], s);
#pragma unroll
  for (int off = 32; off; off >>= 1) s += __shfl_xor(s, off);
  if (lane == 0) g[m] = s + a2b[0];
}

__global__ __launch_bounds__(1024) void softmax_stats_kernel(
    const float* __restrict__ g, float* __restrict__ stats)
{
  __shared__ float red[16];
  __shared__ float red2[16];
  const int t = threadIdx.x;
  float mx = NEG_BIG;
  for (int i = t; i < M_NODES; i += 1024) mx = fmaxf(mx, g[i]);
#pragma unroll
  for (int off = 32; off; off >>= 1) mx = fmaxf(mx, __shfl_xor(mx, off));
  if ((t & 63) == 0) red[t >> 6] = mx;
  __syncthreads();
  float gmx = red[0];
  for (int i = 1; i < 16; i++) gmx = fmaxf(gmx, red[i]);
  float s = 0.f;
  for (int i = t; i < M_NODES; i += 1024) s += expf(g[i] - gmx);
#pragma unroll
  for (int off = 32; off; off >>= 1) s += __shfl_xor(s, off);
  if ((t & 63) == 0) red2[t >> 6] = s;
  __syncthreads();
  if (t == 0) {
    float tot = 0.f;
    for (int i = 0; i < 16; i++) tot += red2[i];
    stats[0] = gmx; stats[1] = tot;
  }
}

__global__ __launch_bounds__(256) void pooled_kernel(
    const unsigned short* __restrict__ emb, const float* __restrict__ g,
    const float* __restrict__ stats, float* __restrict__ pooled)
{
  const int t = threadIdx.x;
  const int r0 = blockIdx.x * 128;
  const float mx = stats[0];
  const float inv = 1.f / stats[1];
  float a0 = 0.f, a1 = 0.f;
  for (int r = 0; r < 128; r++) {
    const int m = r0 + r;
    const float wv = expf(g[m] - mx) * inv;
    a0 = fmaf(wv, bf2f(emb[(size_t)m * E_DIM + t]), a0);
    a1 = fmaf(wv, bf2f(emb[(size_t)m * E_DIM + 256 + t]), a1);
  }
  atomicAdd(&pooled[t], a0);
  atomicAdd(&pooled[t + 256], a1);
}

__global__ __launch_bounds__(512) void ln_kernel(
    const float* __restrict__ pooled, const float* __restrict__ lng,
    const float* __restrict__ lnb, float* __restrict__ out)
{
  __shared__ float red[8];
  __shared__ float red2[8];
  const int t = threadIdx.x;
  const float v = pooled[t];
  float s = v;
#pragma unroll
  for (int off = 32; off; off >>= 1) s += __shfl_xor(s, off);
  if ((t & 63) == 0) red[t >> 6] = s;
  __syncthreads();
  float tot = 0.f;
  for (int i = 0; i < 8; i++) tot += red[i];
  const float mu = tot / (float)E_DIM;
  const float d = v - mu;
  float q = d * d;
#pragma unroll
  for (int off = 32; off; off >>= 1) q += __shfl_xor(q, off);
  if ((t & 63) == 0) red2[t >> 6] = q;
  __syncthreads();
  float vt = 0.f;
  for (int i = 0; i < 8; i++) vt += red2[i];
  const float var = vt / (float)E_DIM;
  out[t] = d * rsqrtf(var + 1e-5f) * lng[t] + lnb[t];
}

// ---------------------------------------------------------------------------
extern "C" void kernel_launch(void* const* d_in, const int* in_sizes, int n_in,
                              void* d_out, int out_size, void* d_ws, size_t ws_size,
                              hipStream_t stream)
{
  const float* x     = (const float*)d_in[0];
  const float* fc1_w = (const float*)d_in[1];
  const float* fc1_b = (const float*)d_in[2];
  const float* wh_w  = (const float*)d_in[3];
  const float* wh_b  = (const float*)d_in[4];
  const float* wt_w  = (const float*)d_in[5];
  const float* wt_b  = (const float*)d_in[6];
  const float* l1_w  = (const float*)d_in[7];
  const float* l1_b  = (const float*)d_in[8];
  const float* l2_w  = (const float*)d_in[9];
  const float* l2_b  = (const float*)d_in[10];
  const float* a1_w  = (const float*)d_in[11];
  const float* a1_b  = (const float*)d_in[12];
  const float* a2_w  = (const float*)d_in[13];
  const float* a2_b  = (const float*)d_in[14];
  const float* ln_g  = (const float*)d_in[15];
  const float* ln_b  = (const float*)d_in[16];

  char* ws = (char*)d_ws;
  const size_t MiB = 1 << 20;
  // weight tiles [0, 2.75Mi) — live whole run
  unsigned short* fc1T = (unsigned short*)(ws + 0);
  unsigned short* whT  = (unsigned short*)(ws + 393216);
  unsigned short* wtT  = (unsigned short*)(ws + 917504);
  unsigned short* l1T  = (unsigned short*)(ws + 1441792);
  unsigned short* l2T  = (unsigned short*)(ws + 1966080);
  unsigned short* a1T  = (unsigned short*)(ws + 2490368);
  // activations (overlaid, liveness-checked):
  unsigned short* xT     = (unsigned short*)(ws + 3 * MiB);    // [3,9) wcast->gemm1
  float*          h      = (float*)(ws + 9 * MiB);             // [9,25) gemm1->hupd
  unsigned short* hT     = (unsigned short*)(ws + 25 * MiB);   // [25,33) hupd->gemm2
  unsigned short* ehT    = (unsigned short*)(ws + 3 * MiB);    // [3,11) gemm2->combine
  unsigned short* etT    = (unsigned short*)(ws + 11 * MiB);   // [11,19) gemm2->combine
  unsigned short* scores = (unsigned short*)(ws + 19 * MiB);   // [19,35) band (hT dead)
  unsigned short* s1T    = (unsigned short*)(ws + 19 * MiB);   // [19,27) combine->gemm3
  unsigned short* s2T    = (unsigned short*)(ws + 27 * MiB);   // [27,35) combine->gemm3
  unsigned short* embT   = (unsigned short*)(ws + 3 * MiB);    // [3,11) gemm3->gemm4
  unsigned short* embRow = (unsigned short*)(ws + 11 * MiB);   // [11,19) gemm3->pooled
  float*          ahid   = (float*)(ws + 19 * MiB);            // [19,27) gemm4->gate
  char*           smal   = ws + 37 * MiB;
  float* tkv    = (float*)(smal);                              // 8192*24*4 = 786432
  int*   tki    = (int*)(smal + 786432);                       // 786432
  float* colsum = (float*)(smal + 1572864);
  float* g      = (float*)(smal + 1576960);
  float* stats  = (float*)(smal + 1609728);
  float* pooled = (float*)(smal + 1613824);

  hipMemsetAsync(smal + 1572864, 0, 43008, stream);

  // 0. cast x + all weights to bf16 tiled
  wcast_kernel<<<2208, 256, 0, stream>>>(x, fc1_w, wh_w, wt_w, l1_w, l2_w, a1_w,
                                         xT, fc1T, whT, wtT, l1T, l2T, a1T);
  // 1. h = lrelu(x @ fc1^T + b)
  mfma_gemm<0><<<dim3(8, 64), 256, 0, stream>>>(
      xT, nullptr, fc1T, nullptr, fc1_b, nullptr, h, nullptr, nullptr, nullptr, 512, 384);
  // 2. colmean + mix + bf16 tiled cast
  colsum_kernel<<<64, 256, 0, stream>>>(h, colsum);
  hupd_cast_kernel<<<2048, 256, 0, stream>>>(h, colsum, hT);
  // 3. e_h, e_t (bf16 tiled, unscaled)
  mfma_gemm<1><<<dim3(8, 64), 256, 0, stream>>>(
      hT, nullptr, whT, wtT, wh_b, wt_b, nullptr, ehT, etT, nullptr, 512, 512);
  // 4. banded score GEMM + parallel exact top-6 scan
  for (int band = 0; band < M_NODES / BAND; band++) {
    sgemm_kernel<<<dim3(64, BAND / 128), 256, 0, stream>>>(ehT, etT, scores, band * BAND);
    scan_topk_kernel<<<BAND, 256, 0, stream>>>(scores, band * BAND, tkv, tki);
  }
  // 5. combine -> s1T, s2T (bf16 tiled)
  combine_kernel<<<M_NODES / 4, 256, 0, stream>>>(ehT, etT, tkv, tki, s1T, s2T);
  // 6. emb = lrelu(s1@l1^T+b1)+lrelu(s2@l2^T+b2) -> bf16 tiled + bf16 row
  mfma_gemm<2><<<dim3(8, 64), 256, 0, stream>>>(
      s1T, s2T, l1T, l2T, l1_b, l2_b, nullptr, embT, nullptr, embRow, 512, 512);
  // 7. ahid = lrelu(emb @ a1^T + b)  [8192x256]
  mfma_gemm<0><<<dim3(4, 64), 256, 0, stream>>>(
      embT, nullptr, a1T, nullptr, a1_b, nullptr, ahid, nullptr, nullptr, nullptr, 256, 512);
  // 8-11. readout
  gate_g_kernel<<<M_NODES / 4, 256, 0, stream>>>(ahid, a2_w, a2_b, g);
  softmax_stats_kernel<<<1, 1024, 0, stream>>>(g, stats);
  pooled_kernel<<<64, 256, 0, stream>>>(embRow, g, stats, pooled);
  ln_kernel<<<1, 512, 0, stream>>>(pooled, ln_g, ln_b, (float*)d_out);
}

// Round 6
// 479.352 us; speedup vs baseline: 1.8213x; 1.8213x over previous
//
#include <hip/hip_runtime.h>
#include <math.h>
#include <stdint.h>

#define M_NODES 8192
#define E_DIM   512
#define NTOPK   6
#define ATTN_SCALE 0.04419417382415922f  // 512^-0.5
#define NEG_BIG (-1e38f)
#define BAND    1024
#define CAND_CAP 192

typedef __attribute__((ext_vector_type(8))) short short8;
typedef __attribute__((ext_vector_type(4))) float f32x4;

__device__ __forceinline__ float lrelu(float v) { return v > 0.f ? v : 0.01f * v; }

__device__ __forceinline__ unsigned short f2bf(float f) {
  uint32_t u = __float_as_uint(f);
  uint32_t r = (u + 0x7FFFu + ((u >> 16) & 1u)) >> 16;
  return (unsigned short)r;
}
__device__ __forceinline__ float bf2f(unsigned short s) {
  return __uint_as_float(((uint32_t)s) << 16);
}

// async 16B/lane global->LDS (wave-uniform LDS base, lane i lands at base+16i)
__device__ __forceinline__ void async_cp16(const void* gptr, void* lds) {
  auto g1 = reinterpret_cast<const __attribute__((address_space(1))) unsigned int*>(
      reinterpret_cast<uintptr_t>(gptr));
  auto l3 = reinterpret_cast<__attribute__((address_space(3))) unsigned int*>(
      reinterpret_cast<uintptr_t>(lds));
  __builtin_amdgcn_global_load_lds(g1, l3, 16, 0, 0);
}

// tiled bf16 layout: value (m,k), Ktiles=K/32:
//   idx = ((m>>4)*Ktiles + (k>>5))*512 + ((m&15) + 16*((k>>3)&3))*8 + (k&7)

// ---------------------------------------------------------------------------
// Cast fp32 x + 6 weight matrices into bf16 frag-tiled layout.
// ---------------------------------------------------------------------------
__global__ __launch_bounds__(256) void wcast_kernel(
    const float* __restrict__ x, const float* __restrict__ fc1w,
    const float* __restrict__ whw, const float* __restrict__ wtw,
    const float* __restrict__ l1w, const float* __restrict__ l2w,
    const float* __restrict__ a1w,
    unsigned short* __restrict__ xT, unsigned short* __restrict__ fc1T,
    unsigned short* __restrict__ whT, unsigned short* __restrict__ wtT,
    unsigned short* __restrict__ l1T, unsigned short* __restrict__ l2T,
    unsigned short* __restrict__ a1T)
{
  const int gid = blockIdx.x * 256 + threadIdx.x;  // 0 .. 565247
  const float* src; unsigned short* dst; int K8, local;
  if (gid < 417792) {
    K8 = 48;
    if (gid < 393216) { src = x; dst = xT; local = gid; }
    else { src = fc1w; dst = fc1T; local = gid - 393216; }
  } else {
    K8 = 64;
    if (gid < 450560)      { src = whw; dst = whT; local = gid - 417792; }
    else if (gid < 483328) { src = wtw; dst = wtT; local = gid - 450560; }
    else if (gid < 516096) { src = l1w; dst = l1T; local = gid - 483328; }
    else if (gid < 548864) { src = l2w; dst = l2T; local = gid - 516096; }
    else                   { src = a1w; dst = a1T; local = gid - 548864; }
  }
  const int m = local / K8;
  const int k8 = local - m * K8;
  const float* p = src + (size_t)m * (K8 * 8) + k8 * 8;
  float4 v0 = ((const float4*)p)[0];
  float4 v1 = ((const float4*)p)[1];
  const int Kt = K8 >> 2;
  const size_t ti = ((size_t)(m >> 4) * Kt + (k8 >> 2)) * 512 + ((m & 15) + 16 * (k8 & 3)) * 8;
  uint4 pk;
  pk.x = (uint32_t)f2bf(v0.x) | ((uint32_t)f2bf(v0.y) << 16);
  pk.y = (uint32_t)f2bf(v0.z) | ((uint32_t)f2bf(v0.w) << 16);
  pk.z = (uint32_t)f2bf(v1.x) | ((uint32_t)f2bf(v1.y) << 16);
  pk.w = (uint32_t)f2bf(v1.z) | ((uint32_t)f2bf(v1.w) << 16);
  *(uint4*)(dst + ti) = pk;
}

// ---------------------------------------------------------------------------
// MFMA GEMM, tile 128(M) x 64(N), 4 waves each 32x64, K-step 32.
// MODE 0: Cf fp32 = lrelu(A@W1^T + b1)
// MODE 1: T1 = bf16(A@W1^T+b1) tiled ; T2 = bf16(A@W2^T+b2) tiled  (no fp32 out)
// MODE 2: e = lrelu(A1@W1^T+b1)+lrelu(A2@W2^T+b2) ; T1 = bf16(e) tiled ;
//         Cbf = bf16(e) row-major
// ---------------------------------------------------------------------------
template <int MODE>
__global__ __launch_bounds__(256) void mfma_gemm(
    const unsigned short* __restrict__ At1, const unsigned short* __restrict__ At2,
    const unsigned short* __restrict__ Wt1, const unsigned short* __restrict__ Wt2,
    const float* __restrict__ b1, const float* __restrict__ b2,
    float* __restrict__ Cf, unsigned short* __restrict__ T1,
    unsigned short* __restrict__ T2, unsigned short* __restrict__ Cbf,
    int N, int K)
{
  __shared__ unsigned short As[2][8 * 512];
  __shared__ unsigned short Bs[2][4 * 512];
  const int Kt = K >> 5;
  const int tid = threadIdx.x, lane = tid & 63, w = tid >> 6;
  const int m0 = blockIdx.y * 128, n0 = blockIdx.x * 64;

  f32x4 acc0[2][4], acc1[2][4];
#pragma unroll
  for (int p = 0; p < 2; p++)
#pragma unroll
    for (int j = 0; j < 4; j++) {
      acc0[p][j] = (f32x4){0.f, 0.f, 0.f, 0.f};
      acc1[p][j] = (f32x4){0.f, 0.f, 0.f, 0.f};
    }

  for (int kt = 0; kt < Kt; kt++) {
    const unsigned short* a1p = At1 + ((size_t)((m0 >> 4) + 2 * w) * Kt + kt) * 512 + lane * 8;
    async_cp16(a1p, &As[0][(2 * w) * 512]);
    async_cp16(a1p + (size_t)Kt * 512, &As[0][(2 * w + 1) * 512]);
    if (MODE == 2) {
      const unsigned short* a2p = At2 + ((size_t)((m0 >> 4) + 2 * w) * Kt + kt) * 512 + lane * 8;
      async_cp16(a2p, &As[1][(2 * w) * 512]);
      async_cp16(a2p + (size_t)Kt * 512, &As[1][(2 * w + 1) * 512]);
    }
    const unsigned short* bp1 = Wt1 + ((size_t)((n0 >> 4) + w) * Kt + kt) * 512 + lane * 8;
    async_cp16(bp1, &Bs[0][w * 512]);
    if (MODE >= 1) {
      const unsigned short* bp2 = Wt2 + ((size_t)((n0 >> 4) + w) * Kt + kt) * 512 + lane * 8;
      async_cp16(bp2, &Bs[1][w * 512]);
    }
    __syncthreads();
    short8 a[2], a2[2], bb[4], bb2[4];
#pragma unroll
    for (int p = 0; p < 2; p++) a[p] = *(const short8*)&As[0][(2 * w + p) * 512 + lane * 8];
    if (MODE == 2) {
#pragma unroll
      for (int p = 0; p < 2; p++) a2[p] = *(const short8*)&As[1][(2 * w + p) * 512 + lane * 8];
    }
#pragma unroll
    for (int j = 0; j < 4; j++) bb[j] = *(const short8*)&Bs[0][j * 512 + lane * 8];
    if (MODE >= 1) {
#pragma unroll
      for (int j = 0; j < 4; j++) bb2[j] = *(const short8*)&Bs[1][j * 512 + lane * 8];
    }
#pragma unroll
    for (int p = 0; p < 2; p++)
#pragma unroll
      for (int j = 0; j < 4; j++) {
        acc0[p][j] = __builtin_amdgcn_mfma_f32_16x16x32_bf16(a[p], bb[j], acc0[p][j], 0, 0, 0);
        if (MODE == 1)
          acc1[p][j] = __builtin_amdgcn_mfma_f32_16x16x32_bf16(a[p], bb2[j], acc1[p][j], 0, 0, 0);
        if (MODE == 2)
          acc1[p][j] = __builtin_amdgcn_mfma_f32_16x16x32_bf16(a2[p], bb2[j], acc1[p][j], 0, 0, 0);
      }
    __syncthreads();
  }

  const int lrow = (lane >> 4) * 4, lcol = lane & 15;
  const int NT = N >> 5;
#pragma unroll
  for (int p = 0; p < 2; p++)
#pragma unroll
    for (int j = 0; j < 4; j++) {
      const int c = n0 + j * 16 + lcol;
      const float bias1 = b1[c];
      const float bias2 = (MODE >= 1) ? b2[c] : 0.f;
#pragma unroll
      for (int d = 0; d < 4; d++) {
        const int r = m0 + w * 32 + p * 16 + lrow + d;
        const float v0 = acc0[p][j][d] + bias1;
        if (MODE == 0) {
          Cf[(size_t)r * N + c] = lrelu(v0);
        } else {
          const size_t ti = ((size_t)(r >> 4) * NT + (c >> 5)) * 512 +
                            ((r & 15) + 16 * ((c >> 3) & 3)) * 8 + (c & 7);
          if (MODE == 1) {
            T1[ti] = f2bf(v0);
            T2[ti] = f2bf(acc1[p][j][d] + bias2);
          } else {
            const float e = lrelu(v0) + lrelu(acc1[p][j][d] + bias2);
            T1[ti] = f2bf(e);
            Cbf[(size_t)r * N + c] = f2bf(e);
          }
        }
      }
    }
}

// ---------------------------------------------------------------------------
// Column sum of h over M
// ---------------------------------------------------------------------------
__global__ __launch_bounds__(256) void colsum_kernel(const float* __restrict__ h,
                                                     float* __restrict__ colsum)
{
  const int t = threadIdx.x;
  const int r0 = blockIdx.x * 128;
  float s0 = 0.f, s1 = 0.f;
  for (int r = 0; r < 128; r++) {
    s0 += h[(size_t)(r0 + r) * E_DIM + t];
    s1 += h[(size_t)(r0 + r) * E_DIM + 256 + t];
  }
  atomicAdd(&colsum[t], s0);
  atomicAdd(&colsum[t + 256], s1);
}

// h' = (h + colmean)*0.5 fused with bf16 tiled cast (Ktiles=16)
__global__ __launch_bounds__(256) void hupd_cast_kernel(
    const float* __restrict__ h, const float* __restrict__ colsum,
    unsigned short* __restrict__ hT)
{
  const int gid = blockIdx.x * 256 + threadIdx.x;  // 8192*64
  const int m = gid >> 6, k8 = gid & 63;
  const float* p = h + (size_t)m * E_DIM + k8 * 8;
  float4 v0 = ((const float4*)p)[0];
  float4 v1 = ((const float4*)p)[1];
  float4 c0 = *(const float4*)(colsum + k8 * 8);
  float4 c1 = *(const float4*)(colsum + k8 * 8 + 4);
  const float im = 1.f / (float)M_NODES;
  v0.x = (v0.x + c0.x * im) * 0.5f; v0.y = (v0.y + c0.y * im) * 0.5f;
  v0.z = (v0.z + c0.z * im) * 0.5f; v0.w = (v0.w + c0.w * im) * 0.5f;
  v1.x = (v1.x + c1.x * im) * 0.5f; v1.y = (v1.y + c1.y * im) * 0.5f;
  v1.z = (v1.z + c1.z * im) * 0.5f; v1.w = (v1.w + c1.w * im) * 0.5f;
  const size_t ti = ((size_t)(m >> 4) * 16 + (k8 >> 2)) * 512 + ((m & 15) + 16 * (k8 & 3)) * 8;
  uint4 pk;
  pk.x = (uint32_t)f2bf(v0.x) | ((uint32_t)f2bf(v0.y) << 16);
  pk.y = (uint32_t)f2bf(v0.z) | ((uint32_t)f2bf(v0.w) << 16);
  pk.z = (uint32_t)f2bf(v1.x) | ((uint32_t)f2bf(v1.y) << 16);
  pk.w = (uint32_t)f2bf(v1.z) | ((uint32_t)f2bf(v1.w) << 16);
  *(uint4*)(hT + ti) = pk;
}

// ---------------------------------------------------------------------------
// Score GEMM (one band of 1024 rows): sc[band_row][8192] = bf16(eh . et)
// + per-row 64-col segment maxima tmax[band_row][128] (fp32).
// 128x128 tile, 4 waves each 64x64, BK=32, m97-style 2-barrier K-loop.
// ---------------------------------------------------------------------------
__global__ __launch_bounds__(256) void sgemm_kernel(
    const unsigned short* __restrict__ ehT, const unsigned short* __restrict__ etT,
    unsigned short* __restrict__ sc, float* __restrict__ tmax, int mbase)
{
  __shared__ unsigned short As[8 * 512];
  __shared__ unsigned short Bs[8 * 512];
  __shared__ unsigned short Sc[128 * 136];
  const int tid = threadIdx.x, lane = tid & 63, w = tid >> 6;
  const int wr = w >> 1, wc = w & 1;
  const int m0 = mbase + blockIdx.y * 128;
  const int n0 = blockIdx.x * 128;

  f32x4 acc[4][4];
#pragma unroll
  for (int i = 0; i < 4; i++)
#pragma unroll
    for (int j = 0; j < 4; j++) acc[i][j] = (f32x4){0.f, 0.f, 0.f, 0.f};

  for (int kt = 0; kt < 16; kt++) {
    const int s0 = w, s1 = w + 4;
    async_cp16(ehT + ((size_t)((m0 >> 4) + s0) * 16 + kt) * 512 + lane * 8, &As[s0 * 512]);
    async_cp16(ehT + ((size_t)((m0 >> 4) + s1) * 16 + kt) * 512 + lane * 8, &As[s1 * 512]);
    async_cp16(etT + ((size_t)((n0 >> 4) + s0) * 16 + kt) * 512 + lane * 8, &Bs[s0 * 512]);
    async_cp16(etT + ((size_t)((n0 >> 4) + s1) * 16 + kt) * 512 + lane * 8, &Bs[s1 * 512]);
    __syncthreads();
    short8 a[4], b[4];
#pragma unroll
    for (int i = 0; i < 4; i++) a[i] = *(const short8*)&As[(wr * 4 + i) * 512 + lane * 8];
#pragma unroll
    for (int j = 0; j < 4; j++) b[j] = *(const short8*)&Bs[(wc * 4 + j) * 512 + lane * 8];
#pragma unroll
    for (int i = 0; i < 4; i++)
#pragma unroll
      for (int j = 0; j < 4; j++)
        acc[i][j] = __builtin_amdgcn_mfma_f32_16x16x32_bf16(a[i], b[j], acc[i][j], 0, 0, 0);
    __syncthreads();
  }

  // frags -> LDS bf16 (C layout: col=lane&15, row=quad*4+reg)
  const int lrow = (lane >> 4) * 4, lcol = lane & 15;
#pragma unroll
  for (int i = 0; i < 4; i++) {
    const int row = wr * 64 + i * 16 + lrow;
#pragma unroll
    for (int j = 0; j < 4; j++) {
      const int col = wc * 64 + j * 16 + lcol;
      Sc[(row + 0) * 136 + col] = f2bf(acc[i][j][0]);
      Sc[(row + 1) * 136 + col] = f2bf(acc[i][j][1]);
      Sc[(row + 2) * 136 + col] = f2bf(acc[i][j][2]);
      Sc[(row + 3) * 136 + col] = f2bf(acc[i][j][3]);
    }
  }
  __syncthreads();

  // coalesced store + 64-col segment max: thread t -> row t>>1, half t&1
  const int row = tid >> 1, half = tid & 1;
  const unsigned short* src = &Sc[row * 136 + half * 64];
  unsigned short* dst = sc + (size_t)(m0 - mbase + row) * M_NODES + n0 + half * 64;
  float mx = NEG_BIG;
#pragma unroll
  for (int q = 0; q < 8; q++) {
    short8 s8 = *(const short8*)(src + q * 8);
    *(short8*)(dst + q * 8) = s8;
#pragma unroll
    for (int e = 0; e < 8; e++) mx = fmaxf(mx, bf2f((unsigned short)s8[e]));
  }
  tmax[(size_t)(m0 - mbase + row) * 128 + blockIdx.x * 2 + half] = mx;
}

// ---------------------------------------------------------------------------
// Exact top-6 via threshold prefilter. One wave per row.
// Phase A: tau = 6th largest of 128 segment maxima (pairwise-maxed to 64).
//   Provably tau <= v6 (6th largest element) and >= 6 elements >= tau.
// Phase B: single pass over 8192 scores, append elems >= tau to LDS (~25/row).
// Phase C: parallel rank-select among candidates (ties -> lower index first).
// ---------------------------------------------------------------------------
__global__ __launch_bounds__(256) void scan_topk_kernel(
    const unsigned short* __restrict__ sc, const float* __restrict__ tmax,
    int mbase, float* __restrict__ tkv, int* __restrict__ tki)
{
  __shared__ float cv[4][CAND_CAP];
  __shared__ int   ci[4][CAND_CAP];
  __shared__ int   cnt[4];
  const int lane = threadIdx.x & 63;
  const int w = threadIdx.x >> 6;
  const int row = blockIdx.x * 4 + w;
  if (lane == 0) cnt[w] = 0;
  __syncthreads();

  // Phase A: tau (bf16-derived f32 has zero low 16 mantissa bits -> &~63 lossless)
  const float* tm = tmax + (size_t)row * 128;
  const float v2 = fmaxf(tm[lane], tm[lane + 64]);
  uint32_t u = __float_as_uint(v2);
  u = ((int)u >= 0) ? (u | 0x80000000u) : ~u;
  uint32_t key = (u & ~63u) | (uint32_t)lane;
  float tau = 0.f;
#pragma unroll
  for (int it = 0; it < 6; it++) {
    uint32_t k = key;
#pragma unroll
    for (int off = 32; off; off >>= 1) {
      const uint32_t o = (uint32_t)__shfl_xor((int)k, off);
      k = k > o ? k : o;
    }
    const int wl = (int)(k & 63u);
    if (it == 5) tau = __shfl(v2, wl);
    if (lane == wl) key = 0u;
  }

  // Phase B: collect candidates >= tau
  const unsigned short* rp = sc + (size_t)row * M_NODES;
  for (int g = 0; g < 16; g++) {
    const int base = (g * 64 + lane) * 8;
    short8 s8 = *(const short8*)(rp + base);
#pragma unroll
    for (int e = 0; e < 8; e++) {
      const float f = bf2f((unsigned short)s8[e]);
      if (f >= tau) {
        const int slot = atomicAdd(&cnt[w], 1);
        if (slot < CAND_CAP) { cv[w][slot] = f; ci[w][slot] = base + e; }
      }
    }
  }

  // Phase C: rank-select (wave-local LDS; same-wave DS ops are program-ordered)
  int n = cnt[w];
  n = n < CAND_CAP ? n : CAND_CAP;
  for (int c = lane; c < n; c += 64) {
    const float v = cv[w][c];
    const int idx = ci[w][c];
    int rank = 0;
    for (int j = 0; j < n; j++) {
      const float vj = cv[w][j];
      rank += (vj > v) || (vj == v && ci[w][j] < idx);
    }
    if (rank < NTOPK) {
      const size_t base = (size_t)(mbase + row) * NTOPK + rank;
      tkv[base] = v * ATTN_SCALE;
      tki[base] = idx;
    }
  }
}

// ---------------------------------------------------------------------------
// Per-row combine: softmax over exact top-6, gather Nb from etT (bf16 tiled),
// gate tanh, ka softmax, e_Nh; write s1=eh+eNh, s2=eh*eNh bf16 tiled.
// One wave per row.
// ---------------------------------------------------------------------------
__global__ __launch_bounds__(256) void combine_kernel(
    const unsigned short* __restrict__ ehT, const unsigned short* __restrict__ etT,
    const float* __restrict__ tkv, const int* __restrict__ tki,
    unsigned short* __restrict__ s1T, unsigned short* __restrict__ s2T)
{
  const int lane = threadIdx.x & 63;
  const int m = blockIdx.x * 4 + (threadIdx.x >> 6);

  float wv[NTOPK]; int id[NTOPK];
#pragma unroll
  for (int k = 0; k < NTOPK; k++) {
    wv[k] = tkv[(size_t)m * NTOPK + k];
    id[k] = tki[(size_t)m * NTOPK + k];
  }

  float mx = wv[0];
#pragma unroll
  for (int k = 1; k < NTOPK; k++) mx = fmaxf(mx, wv[k]);
  float p[NTOPK]; float s = 0.f;
#pragma unroll
  for (int k = 0; k < NTOPK; k++) { p[k] = expf(wv[k] - mx); s += p[k]; }
  const float inv = 1.f / s;
#pragma unroll
  for (int k = 0; k < NTOPK; k++) p[k] *= inv;

  // tiled per-lane addressing: k-dim index = lane + 64*i
  const int wconst_base = 16 * ((lane >> 3) & 3) * 8 + (lane & 7);
  const unsigned short* ep = ehT + ((size_t)(m >> 4) * 16 + (lane >> 5)) * 512 +
                             (m & 15) * 8 + wconst_base;
  float ehv[8];
#pragma unroll
  for (int i = 0; i < 8; i++) ehv[i] = bf2f(ep[i * 1024]);

  float nv[NTOPK][8];
#pragma unroll
  for (int k = 0; k < NTOPK; k++) {
    const int n = id[k];
    const unsigned short* bp = etT + ((size_t)(n >> 4) * 16 + (lane >> 5)) * 512 +
                               (n & 15) * 8 + wconst_base;
#pragma unroll
    for (int i = 0; i < 8; i++) nv[k][i] = bf2f(bp[i * 1024]);
  }

  float ka[NTOPK];
#pragma unroll
  for (int k = 0; k < NTOPK; k++) {
    float snb = 0.f, sg = 0.f;
    const float aa = 2.f - p[k], bb = p[k];
#pragma unroll
    for (int i = 0; i < 8; i++) {
      snb += nv[k][i];
      sg += tanhf(fmaf(aa, ehv[i], bb * nv[k][i]));
    }
#pragma unroll
    for (int off = 32; off; off >>= 1) {
      snb += __shfl_xor(snb, off);
      sg += __shfl_xor(sg, off);
    }
    ka[k] = snb * sg;
  }
  float km = ka[0];
#pragma unroll
  for (int k = 1; k < NTOPK; k++) km = fmaxf(km, ka[k]);
  float kp[NTOPK]; float ks = 0.f;
#pragma unroll
  for (int k = 0; k < NTOPK; k++) { kp[k] = expf(ka[k] - km); ks += kp[k]; }
  const float kinv = 1.f / ks;

  unsigned short* o1 = s1T + ((size_t)(m >> 4) * 16 + (lane >> 5)) * 512 +
                       (m & 15) * 8 + wconst_base;
  unsigned short* o2 = s2T + ((size_t)(m >> 4) * 16 + (lane >> 5)) * 512 +
                       (m & 15) * 8 + wconst_base;
#pragma unroll
  for (int i = 0; i < 8; i++) {
    float o = 0.f;
#pragma unroll
    for (int k = 0; k < NTOPK; k++) o = fmaf(kp[k], nv[k][i], o);
    o *= kinv;
    o1[i * 1024] = f2bf(ehv[i] + o);
    o2[i * 1024] = f2bf(ehv[i] * o);
  }
}

// ---------------------------------------------------------------------------
__global__ __launch_bounds__(256) void gate_g_kernel(
    const float* __restrict__ ahid, const float* __restrict__ a2w,
    const float* __restrict__ a2b, float* __restrict__ g)
{
  const int lane = threadIdx.x & 63;
  const int m = blockIdx.x * 4 + (threadIdx.x >> 6);
  float s = 0.f;
  for (int j = lane; j < 256; j += 64)
    s = fmaf(a2w[j], ahid[(size_t)m * 256 + j], s);
#pragma unroll
  for (int off = 32; off; off >>= 1) s += __shfl_xor(s, off);
  if (lane == 0) g[m] = s + a2b[0];
}

__global__ __launch_bounds__(1024) void softmax_stats_kernel(
    const float* __restrict__ g, float* __restrict__ stats)
{
  __shared__ float red[16];
  __shared__ float red2[16];
  const int t = threadIdx.x;
  float mx = NEG_BIG;
  for (int i = t; i < M_NODES; i += 1024) mx = fmaxf(mx, g[i]);
#pragma unroll
  for (int off = 32; off; off >>= 1) mx = fmaxf(mx, __shfl_xor(mx, off));
  if ((t & 63) == 0) red[t >> 6] = mx;
  __syncthreads();
  float gmx = red[0];
  for (int i = 1; i < 16; i++) gmx = fmaxf(gmx, red[i]);
  float s = 0.f;
  for (int i = t; i < M_NODES; i += 1024) s += expf(g[i] - gmx);
#pragma unroll
  for (int off = 32; off; off >>= 1) s += __shfl_xor(s, off);
  if ((t & 63) == 0) red2[t >> 6] = s;
  __syncthreads();
  if (t == 0) {
    float tot = 0.f;
    for (int i = 0; i < 16; i++) tot += red2[i];
    stats[0] = gmx; stats[1] = tot;
  }
}

__global__ __launch_bounds__(256) void pooled_kernel(
    const unsigned short* __restrict__ emb, const float* __restrict__ g,
    const float* __restrict__ stats, float* __restrict__ pooled)
{
  const int t = threadIdx.x;
  const int r0 = blockIdx.x * 128;
  const float mx = stats[0];
  const float inv = 1.f / stats[1];
  float a0 = 0.f, a1 = 0.f;
  for (int r = 0; r < 128; r++) {
    const int m = r0 + r;
    const float wv = expf(g[m] - mx) * inv;
    a0 = fmaf(wv, bf2f(emb[(size_t)m * E_DIM + t]), a0);
    a1 = fmaf(wv, bf2f(emb[(size_t)m * E_DIM + 256 + t]), a1);
  }
  atomicAdd(&pooled[t], a0);
  atomicAdd(&pooled[t + 256], a1);
}

__global__ __launch_bounds__(512) void ln_kernel(
    const float* __restrict__ pooled, const float* __restrict__ lng,
    const float* __restrict__ lnb, float* __restrict__ out)
{
  __shared__ float red[8];
  __shared__ float red2[8];
  const int t = threadIdx.x;
  const float v = pooled[t];
  float s = v;
#pragma unroll
  for (int off = 32; off; off >>= 1) s += __shfl_xor(s, off);
  if ((t & 63) == 0) red[t >> 6] = s;
  __syncthreads();
  float tot = 0.f;
  for (int i = 0; i < 8; i++) tot += red[i];
  const float mu = tot / (float)E_DIM;
  const float d = v - mu;
  float q = d * d;
#pragma unroll
  for (int off = 32; off; off >>= 1) q += __shfl_xor(q, off);
  if ((t & 63) == 0) red2[t >> 6] = q;
  __syncthreads();
  float vt = 0.f;
  for (int i = 0; i < 8; i++) vt += red2[i];
  const float var = vt / (float)E_DIM;
  out[t] = d * rsqrtf(var + 1e-5f) * lng[t] + lnb[t];
}

// ---------------------------------------------------------------------------
extern "C" void kernel_launch(void* const* d_in, const int* in_sizes, int n_in,
                              void* d_out, int out_size, void* d_ws, size_t ws_size,
                              hipStream_t stream)
{
  const float* x     = (const float*)d_in[0];
  const float* fc1_w = (const float*)d_in[1];
  const float* fc1_b = (const float*)d_in[2];
  const float* wh_w  = (const float*)d_in[3];
  const float* wh_b  = (const float*)d_in[4];
  const float* wt_w  = (const float*)d_in[5];
  const float* wt_b  = (const float*)d_in[6];
  const float* l1_w  = (const float*)d_in[7];
  const float* l1_b  = (const float*)d_in[8];
  const float* l2_w  = (const float*)d_in[9];
  const float* l2_b  = (const float*)d_in[10];
  const float* a1_w  = (const float*)d_in[11];
  const float* a1_b  = (const float*)d_in[12];
  const float* a2_w  = (const float*)d_in[13];
  const float* a2_b  = (const float*)d_in[14];
  const float* ln_g  = (const float*)d_in[15];
  const float* ln_b  = (const float*)d_in[16];

  char* ws = (char*)d_ws;
  const size_t MiB = 1 << 20;
  // weight tiles [0, 2.75Mi) — live whole run
  unsigned short* fc1T = (unsigned short*)(ws + 0);
  unsigned short* whT  = (unsigned short*)(ws + 393216);
  unsigned short* wtT  = (unsigned short*)(ws + 917504);
  unsigned short* l1T  = (unsigned short*)(ws + 1441792);
  unsigned short* l2T  = (unsigned short*)(ws + 1966080);
  unsigned short* a1T  = (unsigned short*)(ws + 2490368);
  // activations (overlaid, liveness-checked):
  unsigned short* xT     = (unsigned short*)(ws + 3 * MiB);    // [3,9) wcast->gemm1
  float*          h      = (float*)(ws + 9 * MiB);             // [9,25) gemm1->hupd
  unsigned short* hT     = (unsigned short*)(ws + 25 * MiB);   // [25,33) hupd->gemm2
  unsigned short* ehT    = (unsigned short*)(ws + 3 * MiB);    // [3,11) gemm2->combine
  unsigned short* etT    = (unsigned short*)(ws + 11 * MiB);   // [11,19) gemm2->combine
  unsigned short* scores = (unsigned short*)(ws + 19 * MiB);   // [19,35) band (hT dead)
  unsigned short* s1T    = (unsigned short*)(ws + 19 * MiB);   // [19,27) combine->gemm3
  unsigned short* s2T    = (unsigned short*)(ws + 27 * MiB);   // [27,35) combine->gemm3
  unsigned short* embT   = (unsigned short*)(ws + 3 * MiB);    // [3,11) gemm3->gemm4
  unsigned short* embRow = (unsigned short*)(ws + 11 * MiB);   // [11,19) gemm3->pooled
  float*          ahid   = (float*)(ws + 19 * MiB);            // [19,27) gemm4->gate
  float*          tmaxb  = (float*)(ws + 35 * MiB);            // [35,35.5) per-band seg maxima
  char*           smal   = ws + 37 * MiB;
  float* tkv    = (float*)(smal);                              // 8192*6*4 = 196608
  int*   tki    = (int*)(smal + 196608);                       // 196608
  float* colsum = (float*)(smal + 393216);
  float* g      = (float*)(smal + 395264);
  float* stats  = (float*)(smal + 428032);
  float* pooled = (float*)(smal + 432128);

  hipMemsetAsync(smal + 393216, 0, 43008, stream);

  // 0. cast x + all weights to bf16 tiled
  wcast_kernel<<<2208, 256, 0, stream>>>(x, fc1_w, wh_w, wt_w, l1_w, l2_w, a1_w,
                                         xT, fc1T, whT, wtT, l1T, l2T, a1T);
  // 1. h = lrelu(x @ fc1^T + b)
  mfma_gemm<0><<<dim3(8, 64), 256, 0, stream>>>(
      xT, nullptr, fc1T, nullptr, fc1_b, nullptr, h, nullptr, nullptr, nullptr, 512, 384);
  // 2. colmean + mix + bf16 tiled cast
  colsum_kernel<<<64, 256, 0, stream>>>(h, colsum);
  hupd_cast_kernel<<<2048, 256, 0, stream>>>(h, colsum, hT);
  // 3. e_h, e_t (bf16 tiled, unscaled)
  mfma_gemm<1><<<dim3(8, 64), 256, 0, stream>>>(
      hT, nullptr, whT, wtT, wh_b, wt_b, nullptr, ehT, etT, nullptr, 512, 512);
  // 4. banded score GEMM (+seg maxima) + threshold-filtered exact top-6
  for (int band = 0; band < M_NODES / BAND; band++) {
    sgemm_kernel<<<dim3(64, BAND / 128), 256, 0, stream>>>(
        ehT, etT, scores, tmaxb, band * BAND);
    scan_topk_kernel<<<BAND / 4, 256, 0, stream>>>(scores, tmaxb, band * BAND, tkv, tki);
  }
  // 5. combine -> s1T, s2T (bf16 tiled)
  combine_kernel<<<M_NODES / 4, 256, 0, stream>>>(ehT, etT, tkv, tki, s1T, s2T);
  // 6. emb = lrelu(s1@l1^T+b1)+lrelu(s2@l2^T+b2) -> bf16 tiled + bf16 row
  mfma_gemm<2><<<dim3(8, 64), 256, 0, stream>>>(
      s1T, s2T, l1T, l2T, l1_b, l2_b, nullptr, embT, nullptr, embRow, 512, 512);
  // 7. ahid = lrelu(emb @ a1^T + b)  [8192x256]
  mfma_gemm<0><<<dim3(4, 64), 256, 0, stream>>>(
      embT, nullptr, a1T, nullptr, a1_b, nullptr, ahid, nullptr, nullptr, nullptr, 256, 512);
  // 8-11. readout
  gate_g_kernel<<<M_NODES / 4, 256, 0, stream>>>(ahid, a2_w, a2_b, g);
  softmax_stats_kernel<<<1, 1024, 0, stream>>>(g, stats);
  pooled_kernel<<<64, 256, 0, stream>>>(embRow, g, stats, pooled);
  ln_kernel<<<1, 512, 0, stream>>>(pooled, ln_g, ln_b, (float*)d_out);
}

// Round 7
// 357.749 us; speedup vs baseline: 2.4404x; 1.3399x over previous
//
#include <hip/hip_runtime.h>
#include <math.h>
#include <stdint.h>

#define M_NODES 8192
#define E_DIM   512
#define NTOPK   6
#define ATTN_SCALE 0.04419417382415922f  // 512^-0.5
#define NEG_BIG (-1e38f)
#define CAND_CAP 192

typedef __attribute__((ext_vector_type(8))) short short8;
typedef __attribute__((ext_vector_type(4))) float f32x4;

__device__ __forceinline__ float lrelu(float v) { return v > 0.f ? v : 0.01f * v; }

__device__ __forceinline__ unsigned short f2bf(float f) {
  uint32_t u = __float_as_uint(f);
  uint32_t r = (u + 0x7FFFu + ((u >> 16) & 1u)) >> 16;
  return (unsigned short)r;
}
__device__ __forceinline__ float bf2f(unsigned short s) {
  return __uint_as_float(((uint32_t)s) << 16);
}

// async 16B/lane global->LDS (wave-uniform LDS base, lane i lands at base+16i)
__device__ __forceinline__ void async_cp16(const void* gptr, void* lds) {
  auto g1 = reinterpret_cast<const __attribute__((address_space(1))) unsigned int*>(
      reinterpret_cast<uintptr_t>(gptr));
  auto l3 = reinterpret_cast<__attribute__((address_space(3))) unsigned int*>(
      reinterpret_cast<uintptr_t>(lds));
  __builtin_amdgcn_global_load_lds(g1, l3, 16, 0, 0);
}

// tiled bf16 layout: value (m,k), Ktiles=K/32:
//   idx = ((m>>4)*Ktiles + (k>>5))*512 + ((m&15) + 16*((k>>3)&3))*8 + (k&7)

// ---------------------------------------------------------------------------
// Cast fp32 x + 6 weight matrices into bf16 frag-tiled layout.
// ---------------------------------------------------------------------------
__global__ __launch_bounds__(256) void wcast_kernel(
    const float* __restrict__ x, const float* __restrict__ fc1w,
    const float* __restrict__ whw, const float* __restrict__ wtw,
    const float* __restrict__ l1w, const float* __restrict__ l2w,
    const float* __restrict__ a1w,
    unsigned short* __restrict__ xT, unsigned short* __restrict__ fc1T,
    unsigned short* __restrict__ whT, unsigned short* __restrict__ wtT,
    unsigned short* __restrict__ l1T, unsigned short* __restrict__ l2T,
    unsigned short* __restrict__ a1T)
{
  const int gid = blockIdx.x * 256 + threadIdx.x;  // 0 .. 565247
  const float* src; unsigned short* dst; int K8, local;
  if (gid < 417792) {
    K8 = 48;
    if (gid < 393216) { src = x; dst = xT; local = gid; }
    else { src = fc1w; dst = fc1T; local = gid - 393216; }
  } else {
    K8 = 64;
    if (gid < 450560)      { src = whw; dst = whT; local = gid - 417792; }
    else if (gid < 483328) { src = wtw; dst = wtT; local = gid - 450560; }
    else if (gid < 516096) { src = l1w; dst = l1T; local = gid - 483328; }
    else if (gid < 548864) { src = l2w; dst = l2T; local = gid - 516096; }
    else                   { src = a1w; dst = a1T; local = gid - 548864; }
  }
  const int m = local / K8;
  const int k8 = local - m * K8;
  const float* p = src + (size_t)m * (K8 * 8) + k8 * 8;
  float4 v0 = ((const float4*)p)[0];
  float4 v1 = ((const float4*)p)[1];
  const int Kt = K8 >> 2;
  const size_t ti = ((size_t)(m >> 4) * Kt + (k8 >> 2)) * 512 + ((m & 15) + 16 * (k8 & 3)) * 8;
  uint4 pk;
  pk.x = (uint32_t)f2bf(v0.x) | ((uint32_t)f2bf(v0.y) << 16);
  pk.y = (uint32_t)f2bf(v0.z) | ((uint32_t)f2bf(v0.w) << 16);
  pk.z = (uint32_t)f2bf(v1.x) | ((uint32_t)f2bf(v1.y) << 16);
  pk.w = (uint32_t)f2bf(v1.z) | ((uint32_t)f2bf(v1.w) << 16);
  *(uint4*)(dst + ti) = pk;
}

// ---------------------------------------------------------------------------
// MFMA GEMM, tile 128(M) x 64(N), 4 waves each 32x64, K-step 32.
// MODE 0: Cf fp32 = lrelu(A@W1^T + b1)
// MODE 1: T1/T2 = bf16 tiled; Cbf/Cbf2 = bf16 row-major (both linear outputs)
// MODE 2: e = lrelu(A1@W1^T+b1)+lrelu(A2@W2^T+b2); T1 = bf16(e) tiled;
//         Cbf = bf16(e) row-major
// ---------------------------------------------------------------------------
template <int MODE>
__global__ __launch_bounds__(256) void mfma_gemm(
    const unsigned short* __restrict__ At1, const unsigned short* __restrict__ At2,
    const unsigned short* __restrict__ Wt1, const unsigned short* __restrict__ Wt2,
    const float* __restrict__ b1, const float* __restrict__ b2,
    float* __restrict__ Cf, unsigned short* __restrict__ T1,
    unsigned short* __restrict__ T2, unsigned short* __restrict__ Cbf,
    unsigned short* __restrict__ Cbf2, int N, int K)
{
  __shared__ unsigned short As[2][8 * 512];
  __shared__ unsigned short Bs[2][4 * 512];
  const int Kt = K >> 5;
  const int tid = threadIdx.x, lane = tid & 63, w = tid >> 6;
  const int m0 = blockIdx.y * 128, n0 = blockIdx.x * 64;

  f32x4 acc0[2][4], acc1[2][4];
#pragma unroll
  for (int p = 0; p < 2; p++)
#pragma unroll
    for (int j = 0; j < 4; j++) {
      acc0[p][j] = (f32x4){0.f, 0.f, 0.f, 0.f};
      acc1[p][j] = (f32x4){0.f, 0.f, 0.f, 0.f};
    }

  for (int kt = 0; kt < Kt; kt++) {
    const unsigned short* a1p = At1 + ((size_t)((m0 >> 4) + 2 * w) * Kt + kt) * 512 + lane * 8;
    async_cp16(a1p, &As[0][(2 * w) * 512]);
    async_cp16(a1p + (size_t)Kt * 512, &As[0][(2 * w + 1) * 512]);
    if (MODE == 2) {
      const unsigned short* a2p = At2 + ((size_t)((m0 >> 4) + 2 * w) * Kt + kt) * 512 + lane * 8;
      async_cp16(a2p, &As[1][(2 * w) * 512]);
      async_cp16(a2p + (size_t)Kt * 512, &As[1][(2 * w + 1) * 512]);
    }
    const unsigned short* bp1 = Wt1 + ((size_t)((n0 >> 4) + w) * Kt + kt) * 512 + lane * 8;
    async_cp16(bp1, &Bs[0][w * 512]);
    if (MODE >= 1) {
      const unsigned short* bp2 = Wt2 + ((size_t)((n0 >> 4) + w) * Kt + kt) * 512 + lane * 8;
      async_cp16(bp2, &Bs[1][w * 512]);
    }
    __syncthreads();
    short8 a[2], a2[2], bb[4], bb2[4];
#pragma unroll
    for (int p = 0; p < 2; p++) a[p] = *(const short8*)&As[0][(2 * w + p) * 512 + lane * 8];
    if (MODE == 2) {
#pragma unroll
      for (int p = 0; p < 2; p++) a2[p] = *(const short8*)&As[1][(2 * w + p) * 512 + lane * 8];
    }
#pragma unroll
    for (int j = 0; j < 4; j++) bb[j] = *(const short8*)&Bs[0][j * 512 + lane * 8];
    if (MODE >= 1) {
#pragma unroll
      for (int j = 0; j < 4; j++) bb2[j] = *(const short8*)&Bs[1][j * 512 + lane * 8];
    }
#pragma unroll
    for (int p = 0; p < 2; p++)
#pragma unroll
      for (int j = 0; j < 4; j++) {
        acc0[p][j] = __builtin_amdgcn_mfma_f32_16x16x32_bf16(a[p], bb[j], acc0[p][j], 0, 0, 0);
        if (MODE == 1)
          acc1[p][j] = __builtin_amdgcn_mfma_f32_16x16x32_bf16(a[p], bb2[j], acc1[p][j], 0, 0, 0);
        if (MODE == 2)
          acc1[p][j] = __builtin_amdgcn_mfma_f32_16x16x32_bf16(a2[p], bb2[j], acc1[p][j], 0, 0, 0);
      }
    __syncthreads();
  }

  const int lrow = (lane >> 4) * 4, lcol = lane & 15;
  const int NT = N >> 5;
#pragma unroll
  for (int p = 0; p < 2; p++)
#pragma unroll
    for (int j = 0; j < 4; j++) {
      const int c = n0 + j * 16 + lcol;
      const float bias1 = b1[c];
      const float bias2 = (MODE >= 1) ? b2[c] : 0.f;
#pragma unroll
      for (int d = 0; d < 4; d++) {
        const int r = m0 + w * 32 + p * 16 + lrow + d;
        const float v0 = acc0[p][j][d] + bias1;
        if (MODE == 0) {
          Cf[(size_t)r * N + c] = lrelu(v0);
        } else {
          const size_t ti = ((size_t)(r >> 4) * NT + (c >> 5)) * 512 +
                            ((r & 15) + 16 * ((c >> 3) & 3)) * 8 + (c & 7);
          if (MODE == 1) {
            const float v1 = acc1[p][j][d] + bias2;
            T1[ti] = f2bf(v0);
            T2[ti] = f2bf(v1);
            Cbf[(size_t)r * N + c] = f2bf(v0);
            Cbf2[(size_t)r * N + c] = f2bf(v1);
          } else {
            const float e = lrelu(v0) + lrelu(acc1[p][j][d] + bias2);
            T1[ti] = f2bf(e);
            Cbf[(size_t)r * N + c] = f2bf(e);
          }
        }
      }
    }
}

// ---------------------------------------------------------------------------
// Column sum of h over M
// ---------------------------------------------------------------------------
__global__ __launch_bounds__(256) void colsum_kernel(const float* __restrict__ h,
                                                     float* __restrict__ colsum)
{
  const int t = threadIdx.x;
  const int r0 = blockIdx.x * 128;
  float s0 = 0.f, s1 = 0.f;
  for (int r = 0; r < 128; r++) {
    s0 += h[(size_t)(r0 + r) * E_DIM + t];
    s1 += h[(size_t)(r0 + r) * E_DIM + 256 + t];
  }
  atomicAdd(&colsum[t], s0);
  atomicAdd(&colsum[t + 256], s1);
}

// h' = (h + colmean)*0.5 fused with bf16 tiled cast (Ktiles=16)
__global__ __launch_bounds__(256) void hupd_cast_kernel(
    const float* __restrict__ h, const float* __restrict__ colsum,
    unsigned short* __restrict__ hT)
{
  const int gid = blockIdx.x * 256 + threadIdx.x;  // 8192*64
  const int m = gid >> 6, k8 = gid & 63;
  const float* p = h + (size_t)m * E_DIM + k8 * 8;
  float4 v0 = ((const float4*)p)[0];
  float4 v1 = ((const float4*)p)[1];
  float4 c0 = *(const float4*)(colsum + k8 * 8);
  float4 c1 = *(const float4*)(colsum + k8 * 8 + 4);
  const float im = 1.f / (float)M_NODES;
  v0.x = (v0.x + c0.x * im) * 0.5f; v0.y = (v0.y + c0.y * im) * 0.5f;
  v0.z = (v0.z + c0.z * im) * 0.5f; v0.w = (v0.w + c0.w * im) * 0.5f;
  v1.x = (v1.x + c1.x * im) * 0.5f; v1.y = (v1.y + c1.y * im) * 0.5f;
  v1.z = (v1.z + c1.z * im) * 0.5f; v1.w = (v1.w + c1.w * im) * 0.5f;
  const size_t ti = ((size_t)(m >> 4) * 16 + (k8 >> 2)) * 512 + ((m & 15) + 16 * (k8 & 3)) * 8;
  uint4 pk;
  pk.x = (uint32_t)f2bf(v0.x) | ((uint32_t)f2bf(v0.y) << 16);
  pk.y = (uint32_t)f2bf(v0.z) | ((uint32_t)f2bf(v0.w) << 16);
  pk.z = (uint32_t)f2bf(v1.x) | ((uint32_t)f2bf(v1.y) << 16);
  pk.w = (uint32_t)f2bf(v1.z) | ((uint32_t)f2bf(v1.w) << 16);
  *(uint4*)(hT + ti) = pk;
}

// ---------------------------------------------------------------------------
// Full score GEMM: sc[8192][8192] = bf16(eh . et) + per-row 64-col segment
// maxima tmax[8192][128]. Grid (64,64); 128x128 tile, 4 waves each 64x64.
// ---------------------------------------------------------------------------
__global__ __launch_bounds__(256) void sgemm_kernel(
    const unsigned short* __restrict__ ehT, const unsigned short* __restrict__ etT,
    unsigned short* __restrict__ sc, float* __restrict__ tmax)
{
  __shared__ unsigned short As[8 * 512];
  __shared__ unsigned short Bs[8 * 512];
  __shared__ unsigned short Sc[128 * 136];
  const int tid = threadIdx.x, lane = tid & 63, w = tid >> 6;
  const int wr = w >> 1, wc = w & 1;
  const int m0 = blockIdx.y * 128;
  const int n0 = blockIdx.x * 128;

  f32x4 acc[4][4];
#pragma unroll
  for (int i = 0; i < 4; i++)
#pragma unroll
    for (int j = 0; j < 4; j++) acc[i][j] = (f32x4){0.f, 0.f, 0.f, 0.f};

  for (int kt = 0; kt < 16; kt++) {
    const int s0 = w, s1 = w + 4;
    async_cp16(ehT + ((size_t)((m0 >> 4) + s0) * 16 + kt) * 512 + lane * 8, &As[s0 * 512]);
    async_cp16(ehT + ((size_t)((m0 >> 4) + s1) * 16 + kt) * 512 + lane * 8, &As[s1 * 512]);
    async_cp16(etT + ((size_t)((n0 >> 4) + s0) * 16 + kt) * 512 + lane * 8, &Bs[s0 * 512]);
    async_cp16(etT + ((size_t)((n0 >> 4) + s1) * 16 + kt) * 512 + lane * 8, &Bs[s1 * 512]);
    __syncthreads();
    short8 a[4], b[4];
#pragma unroll
    for (int i = 0; i < 4; i++) a[i] = *(const short8*)&As[(wr * 4 + i) * 512 + lane * 8];
#pragma unroll
    for (int j = 0; j < 4; j++) b[j] = *(const short8*)&Bs[(wc * 4 + j) * 512 + lane * 8];
#pragma unroll
    for (int i = 0; i < 4; i++)
#pragma unroll
      for (int j = 0; j < 4; j++)
        acc[i][j] = __builtin_amdgcn_mfma_f32_16x16x32_bf16(a[i], b[j], acc[i][j], 0, 0, 0);
    __syncthreads();
  }

  // frags -> LDS bf16 (C layout: col=lane&15, row=quad*4+reg)
  const int lrow = (lane >> 4) * 4, lcol = lane & 15;
#pragma unroll
  for (int i = 0; i < 4; i++) {
    const int row = wr * 64 + i * 16 + lrow;
#pragma unroll
    for (int j = 0; j < 4; j++) {
      const int col = wc * 64 + j * 16 + lcol;
      Sc[(row + 0) * 136 + col] = f2bf(acc[i][j][0]);
      Sc[(row + 1) * 136 + col] = f2bf(acc[i][j][1]);
      Sc[(row + 2) * 136 + col] = f2bf(acc[i][j][2]);
      Sc[(row + 3) * 136 + col] = f2bf(acc[i][j][3]);
    }
  }
  __syncthreads();

  // coalesced store + 64-col segment max: thread t -> row t>>1, half t&1
  const int row = tid >> 1, half = tid & 1;
  const unsigned short* src = &Sc[row * 136 + half * 64];
  unsigned short* dst = sc + (size_t)(m0 + row) * M_NODES + n0 + half * 64;
  float mx = NEG_BIG;
#pragma unroll
  for (int q = 0; q < 8; q++) {
    short8 s8 = *(const short8*)(src + q * 8);
    *(short8*)(dst + q * 8) = s8;
#pragma unroll
    for (int e = 0; e < 8; e++) mx = fmaxf(mx, bf2f((unsigned short)s8[e]));
  }
  tmax[(size_t)(m0 + row) * 128 + blockIdx.x * 2 + half] = mx;
}

// ---------------------------------------------------------------------------
// Exact top-6 via threshold prefilter. One wave per row, grid 2048 x 4 waves.
// Phase A: tau = 6th largest of 128 segment maxima.
// Phase B: single pass over 8192 scores, append elems >= tau to LDS (~25/row).
// Phase C: parallel rank-select among candidates (ties -> lower index first).
// ---------------------------------------------------------------------------
__global__ __launch_bounds__(256) void scan_topk_kernel(
    const unsigned short* __restrict__ sc, const float* __restrict__ tmax,
    float* __restrict__ tkv, int* __restrict__ tki)
{
  __shared__ float cv[4][CAND_CAP];
  __shared__ int   ci[4][CAND_CAP];
  __shared__ int   cnt[4];
  const int lane = threadIdx.x & 63;
  const int w = threadIdx.x >> 6;
  const int row = blockIdx.x * 4 + w;
  if (lane == 0) cnt[w] = 0;
  __syncthreads();

  // Phase A: tau (bf16-derived f32 has zero low 16 mantissa bits -> &~63 lossless)
  const float* tm = tmax + (size_t)row * 128;
  const float v2 = fmaxf(tm[lane], tm[lane + 64]);
  uint32_t u = __float_as_uint(v2);
  u = ((int)u >= 0) ? (u | 0x80000000u) : ~u;
  uint32_t key = (u & ~63u) | (uint32_t)lane;
  float tau = 0.f;
#pragma unroll
  for (int it = 0; it < 6; it++) {
    uint32_t k = key;
#pragma unroll
    for (int off = 32; off; off >>= 1) {
      const uint32_t o = (uint32_t)__shfl_xor((int)k, off);
      k = k > o ? k : o;
    }
    const int wl = (int)(k & 63u);
    if (it == 5) tau = __shfl(v2, wl);
    if (lane == wl) key = 0u;
  }

  // Phase B: collect candidates >= tau
  const unsigned short* rp = sc + (size_t)row * M_NODES;
  for (int g = 0; g < 16; g++) {
    const int base = (g * 64 + lane) * 8;
    short8 s8 = *(const short8*)(rp + base);
#pragma unroll
    for (int e = 0; e < 8; e++) {
      const float f = bf2f((unsigned short)s8[e]);
      if (f >= tau) {
        const int slot = atomicAdd(&cnt[w], 1);
        if (slot < CAND_CAP) { cv[w][slot] = f; ci[w][slot] = base + e; }
      }
    }
  }

  // Phase C: rank-select (wave-local LDS; same-wave DS ops are program-ordered)
  int n = cnt[w];
  n = n < CAND_CAP ? n : CAND_CAP;
  for (int c = lane; c < n; c += 64) {
    const float v = cv[w][c];
    const int idx = ci[w][c];
    int rank = 0;
    for (int j = 0; j < n; j++) {
      const float vj = cv[w][j];
      rank += (vj > v) || (vj == v && ci[w][j] < idx);
    }
    if (rank < NTOPK) {
      const size_t base = (size_t)row * NTOPK + rank;
      tkv[base] = v * ATTN_SCALE;
      tki[base] = idx;
    }
  }
}

// ---------------------------------------------------------------------------
// Per-row combine with row-major coalesced gathers: softmax over top-6,
// gather Nb rows from etRow (1KB coalesced each), gate tanh, ka softmax,
// e_Nh; write s1=eh+eNh, s2=eh*eNh bf16 tiled (one 16B granule per lane).
// One wave per row.
// ---------------------------------------------------------------------------
__global__ __launch_bounds__(256) void combine_kernel(
    const unsigned short* __restrict__ ehRow, const unsigned short* __restrict__ etRow,
    const float* __restrict__ tkv, const int* __restrict__ tki,
    unsigned short* __restrict__ s1T, unsigned short* __restrict__ s2T)
{
  const int lane = threadIdx.x & 63;
  const int m = blockIdx.x * 4 + (threadIdx.x >> 6);

  float wv[NTOPK]; int id[NTOPK];
#pragma unroll
  for (int k = 0; k < NTOPK; k++) {
    wv[k] = tkv[(size_t)m * NTOPK + k];
    id[k] = tki[(size_t)m * NTOPK + k];
  }

  float mx = wv[0];
#pragma unroll
  for (int k = 1; k < NTOPK; k++) mx = fmaxf(mx, wv[k]);
  float p[NTOPK]; float s = 0.f;
#pragma unroll
  for (int k = 0; k < NTOPK; k++) { p[k] = expf(wv[k] - mx); s += p[k]; }
  const float inv = 1.f / s;
#pragma unroll
  for (int k = 0; k < NTOPK; k++) p[k] *= inv;

  // coalesced row reads: lane covers k = lane*8 .. lane*8+7
  short8 eh8 = *(const short8*)(ehRow + (size_t)m * E_DIM + lane * 8);
  float ehv[8];
#pragma unroll
  for (int e = 0; e < 8; e++) ehv[e] = bf2f((unsigned short)eh8[e]);

  float nv[NTOPK][8];
#pragma unroll
  for (int k = 0; k < NTOPK; k++) {
    short8 nb = *(const short8*)(etRow + (size_t)id[k] * E_DIM + lane * 8);
#pragma unroll
    for (int e = 0; e < 8; e++) nv[k][e] = bf2f((unsigned short)nb[e]);
  }

  float ka[NTOPK];
#pragma unroll
  for (int k = 0; k < NTOPK; k++) {
    float snb = 0.f, sg = 0.f;
    const float aa = 2.f - p[k], bb = p[k];
#pragma unroll
    for (int e = 0; e < 8; e++) {
      snb += nv[k][e];
      sg += tanhf(fmaf(aa, ehv[e], bb * nv[k][e]));
    }
#pragma unroll
    for (int off = 32; off; off >>= 1) {
      snb += __shfl_xor(snb, off);
      sg += __shfl_xor(sg, off);
    }
    ka[k] = snb * sg;
  }
  float km = ka[0];
#pragma unroll
  for (int k = 1; k < NTOPK; k++) km = fmaxf(km, ka[k]);
  float kp[NTOPK]; float ks = 0.f;
#pragma unroll
  for (int k = 0; k < NTOPK; k++) { kp[k] = expf(ka[k] - km); ks += kp[k]; }
  const float kinv = 1.f / ks;

  // tiled granule for (m, k=lane*8+e): block (m>>4)*16 + (lane>>2),
  // within ((m&15) + 16*(lane&3))*8 + e  -> contiguous in e (16B store)
  const size_t tbase = ((size_t)(m >> 4) * 16 + (lane >> 2)) * 512 +
                       ((m & 15) + 16 * (lane & 3)) * 8;
  unsigned short o1[8], o2[8];
#pragma unroll
  for (int e = 0; e < 8; e++) {
    float o = 0.f;
#pragma unroll
    for (int k = 0; k < NTOPK; k++) o = fmaf(kp[k], nv[k][e], o);
    o *= kinv;
    o1[e] = f2bf(ehv[e] + o);
    o2[e] = f2bf(ehv[e] * o);
  }
  *(short8*)(s1T + tbase) = *(short8*)o1;
  *(short8*)(s2T + tbase) = *(short8*)o2;
}

// ---------------------------------------------------------------------------
__global__ __launch_bounds__(256) void gate_g_kernel(
    const float* __restrict__ ahid, const float* __restrict__ a2w,
    const float* __restrict__ a2b, float* __restrict__ g)
{
  const int lane = threadIdx.x & 63;
  const int m = blockIdx.x * 4 + (threadIdx.x >> 6);
  float s = 0.f;
  for (int j = lane; j < 256; j += 64)
    s = fmaf(a2w[j], ahid[(size_t)m * 256 + j], s);
#pragma unroll
  for (int off = 32; off; off >>= 1) s += __shfl_xor(s, off);
  if (lane == 0) g[m] = s + a2b[0];
}

__global__ __launch_bounds__(1024) void softmax_stats_kernel(
    const float* __restrict__ g, float* __restrict__ stats)
{
  __shared__ float red[16];
  __shared__ float red2[16];
  const int t = threadIdx.x;
  float mx = NEG_BIG;
  for (int i = t; i < M_NODES; i += 1024) mx = fmaxf(mx, g[i]);
#pragma unroll
  for (int off = 32; off; off >>= 1) mx = fmaxf(mx, __shfl_xor(mx, off));
  if ((t & 63) == 0) red[t >> 6] = mx;
  __syncthreads();
  float gmx = red[0];
  for (int i = 1; i < 16; i++) gmx = fmaxf(gmx, red[i]);
  float s = 0.f;
  for (int i = t; i < M_NODES; i += 1024) s += expf(g[i] - gmx);
#pragma unroll
  for (int off = 32; off; off >>= 1) s += __shfl_xor(s, off);
  if ((t & 63) == 0) red2[t >> 6] = s;
  __syncthreads();
  if (t == 0) {
    float tot = 0.f;
    for (int i = 0; i < 16; i++) tot += red2[i];
    stats[0] = gmx; stats[1] = tot;
  }
}

__global__ __launch_bounds__(256) void pooled_kernel(
    const unsigned short* __restrict__ emb, const float* __restrict__ g,
    const float* __restrict__ stats, float* __restrict__ pooled)
{
  const int t = threadIdx.x;
  const int r0 = blockIdx.x * 128;
  const float mx = stats[0];
  const float inv = 1.f / stats[1];
  float a0 = 0.f, a1 = 0.f;
  for (int r = 0; r < 128; r++) {
    const int m = r0 + r;
    const float wv = expf(g[m] - mx) * inv;
    a0 = fmaf(wv, bf2f(emb[(size_t)m * E_DIM + t]), a0);
    a1 = fmaf(wv, bf2f(emb[(size_t)m * E_DIM + 256 + t]), a1);
  }
  atomicAdd(&pooled[t], a0);
  atomicAdd(&pooled[t + 256], a1);
}

__global__ __launch_bounds__(512) void ln_kernel(
    const float* __restrict__ pooled, const float* __restrict__ lng,
    const float* __restrict__ lnb, float* __restrict__ out)
{
  __shared__ float red[8];
  __shared__ float red2[8];
  const int t = threadIdx.x;
  const float v = pooled[t];
  float s = v;
#pragma unroll
  for (int off = 32; off; off >>= 1) s += __shfl_xor(s, off);
  if ((t & 63) == 0) red[t >> 6] = s;
  __syncthreads();
  float tot = 0.f;
  for (int i = 0; i < 8; i++) tot += red[i];
  const float mu = tot / (float)E_DIM;
  const float d = v - mu;
  float q = d * d;
#pragma unroll
  for (int off = 32; off; off >>= 1) q += __shfl_xor(q, off);
  if ((t & 63) == 0) red2[t >> 6] = q;
  __syncthreads();
  float vt = 0.f;
  for (int i = 0; i < 8; i++) vt += red2[i];
  const float var = vt / (float)E_DIM;
  out[t] = d * rsqrtf(var + 1e-5f) * lng[t] + lnb[t];
}

// ---------------------------------------------------------------------------
extern "C" void kernel_launch(void* const* d_in, const int* in_sizes, int n_in,
                              void* d_out, int out_size, void* d_ws, size_t ws_size,
                              hipStream_t stream)
{
  const float* x     = (const float*)d_in[0];
  const float* fc1_w = (const float*)d_in[1];
  const float* fc1_b = (const float*)d_in[2];
  const float* wh_w  = (const float*)d_in[3];
  const float* wh_b  = (const float*)d_in[4];
  const float* wt_w  = (const float*)d_in[5];
  const float* wt_b  = (const float*)d_in[6];
  const float* l1_w  = (const float*)d_in[7];
  const float* l1_b  = (const float*)d_in[8];
  const float* l2_w  = (const float*)d_in[9];
  const float* l2_b  = (const float*)d_in[10];
  const float* a1_w  = (const float*)d_in[11];
  const float* a1_b  = (const float*)d_in[12];
  const float* a2_w  = (const float*)d_in[13];
  const float* a2_b  = (const float*)d_in[14];
  const float* ln_g  = (const float*)d_in[15];
  const float* ln_b  = (const float*)d_in[16];

  char* ws = (char*)d_ws;
  const size_t MiB = 1 << 20;
  // ws_size = 256 MiB (observed via harness poison fill). Layout:
  // weight tiles [0, 3M) — live whole run
  unsigned short* fc1T = (unsigned short*)(ws + 0);
  unsigned short* whT  = (unsigned short*)(ws + 393216);
  unsigned short* wtT  = (unsigned short*)(ws + 917504);
  unsigned short* l1T  = (unsigned short*)(ws + 1441792);
  unsigned short* l2T  = (unsigned short*)(ws + 1966080);
  unsigned short* a1T  = (unsigned short*)(ws + 2490368);
  // activations:
  unsigned short* xT     = (unsigned short*)(ws + 3 * MiB);    // [3,9) wcast->gemm1
  float*          h      = (float*)(ws + 9 * MiB);             // [9,25) gemm1->hupd
  unsigned short* hT     = (unsigned short*)(ws + 25 * MiB);   // [25,33) hupd->gemm2
  unsigned short* ehT    = (unsigned short*)(ws + 33 * MiB);   // [33,41) gemm2->sgemm
  unsigned short* etT    = (unsigned short*)(ws + 41 * MiB);   // [41,49) gemm2->sgemm
  unsigned short* ehRow  = (unsigned short*)(ws + 49 * MiB);   // [49,57) gemm2->combine
  unsigned short* etRow  = (unsigned short*)(ws + 57 * MiB);   // [57,65) gemm2->combine
  float*          tmaxb  = (float*)(ws + 65 * MiB);            // [65,69) sgemm->scan
  unsigned short* s1T    = (unsigned short*)(ws + 3 * MiB);    // [3,11) combine->gemm3 (xT,h dead)
  unsigned short* s2T    = (unsigned short*)(ws + 11 * MiB);   // [11,19) combine->gemm3
  unsigned short* embT   = (unsigned short*)(ws + 19 * MiB);   // [19,27) gemm3->gemm4 (h,hT dead)
  unsigned short* embRow = (unsigned short*)(ws + 27 * MiB);   // [27,35) gemm3->pooled (hT,ehT dead)
  float*          ahid   = (float*)(ws + 41 * MiB);            // [41,49) gemm4->gate (etT dead)
  unsigned short* scores = (unsigned short*)(ws + 96 * MiB);   // [96,224) sgemm->scan
  char*           smal   = ws + 69 * MiB;
  float* tkv    = (float*)(smal);                              // 8192*6*4 = 196608
  int*   tki    = (int*)(smal + 196608);                       // 196608
  float* colsum = (float*)(smal + 393216);
  float* g      = (float*)(smal + 395264);
  float* stats  = (float*)(smal + 428032);
  float* pooled = (float*)(smal + 432128);

  hipMemsetAsync(smal + 393216, 0, 43008, stream);

  // 0. cast x + all weights to bf16 tiled
  wcast_kernel<<<2208, 256, 0, stream>>>(x, fc1_w, wh_w, wt_w, l1_w, l2_w, a1_w,
                                         xT, fc1T, whT, wtT, l1T, l2T, a1T);
  // 1. h = lrelu(x @ fc1^T + b)
  mfma_gemm<0><<<dim3(8, 64), 256, 0, stream>>>(
      xT, nullptr, fc1T, nullptr, fc1_b, nullptr, h, nullptr, nullptr, nullptr, nullptr,
      512, 384);
  // 2. colmean + mix + bf16 tiled cast
  colsum_kernel<<<64, 256, 0, stream>>>(h, colsum);
  hupd_cast_kernel<<<2048, 256, 0, stream>>>(h, colsum, hT);
  // 3. e_h, e_t: tiled (for sgemm) + row-major (for combine)
  mfma_gemm<1><<<dim3(8, 64), 256, 0, stream>>>(
      hT, nullptr, whT, wtT, wh_b, wt_b, nullptr, ehT, etT, ehRow, etRow, 512, 512);
  // 4. full score GEMM (+seg maxima), then threshold-filtered exact top-6
  sgemm_kernel<<<dim3(64, 64), 256, 0, stream>>>(ehT, etT, scores, tmaxb);
  scan_topk_kernel<<<M_NODES / 4, 256, 0, stream>>>(scores, tmaxb, tkv, tki);
  // 5. combine -> s1T, s2T (bf16 tiled)
  combine_kernel<<<M_NODES / 4, 256, 0, stream>>>(ehRow, etRow, tkv, tki, s1T, s2T);
  // 6. emb = lrelu(s1@l1^T+b1)+lrelu(s2@l2^T+b2) -> bf16 tiled + bf16 row
  mfma_gemm<2><<<dim3(8, 64), 256, 0, stream>>>(
      s1T, s2T, l1T, l2T, l1_b, l2_b, nullptr, embT, nullptr, embRow, nullptr, 512, 512);
  // 7. ahid = lrelu(emb @ a1^T + b)  [8192x256]
  mfma_gemm<0><<<dim3(4, 64), 256, 0, stream>>>(
      embT, nullptr, a1T, nullptr, a1_b, nullptr, ahid, nullptr, nullptr, nullptr, nullptr,
      256, 512);
  // 8-11. readout
  gate_g_kernel<<<M_NODES / 4, 256, 0, stream>>>(ahid, a2_w, a2_b, g);
  softmax_stats_kernel<<<1, 1024, 0, stream>>>(g, stats);
  pooled_kernel<<<64, 256, 0, stream>>>(embRow, g, stats, pooled);
  ln_kernel<<<1, 512, 0, stream>>>(pooled, ln_g, ln_b, (float*)d_out);
}

// Round 9
// 338.038 us; speedup vs baseline: 2.5827x; 1.0583x over previous
//
#include <hip/hip_runtime.h>
#include <math.h>
#include <stdint.h>

#define M_NODES 8192
#define E_DIM   512
#define NTOPK   6
#define ATTN_SCALE 0.04419417382415922f  // 512^-0.5
#define NEG_BIG (-1e38f)
#define CAND_CAP 192

typedef __attribute__((ext_vector_type(8))) short short8;
typedef __attribute__((ext_vector_type(4))) float f32x4;

__device__ __forceinline__ float lrelu(float v) { return v > 0.f ? v : 0.01f * v; }

__device__ __forceinline__ unsigned short f2bf(float f) {
  uint32_t u = __float_as_uint(f);
  uint32_t r = (u + 0x7FFFu + ((u >> 16) & 1u)) >> 16;
  return (unsigned short)r;
}
__device__ __forceinline__ float bf2f(unsigned short s) {
  return __uint_as_float(((uint32_t)s) << 16);
}

// async 16B/lane global->LDS (wave-uniform LDS base, lane i lands at base+16i)
__device__ __forceinline__ void async_cp16(const void* gptr, void* lds) {
  auto g1 = reinterpret_cast<const __attribute__((address_space(1))) unsigned int*>(
      reinterpret_cast<uintptr_t>(gptr));
  auto l3 = reinterpret_cast<__attribute__((address_space(3))) unsigned int*>(
      reinterpret_cast<uintptr_t>(lds));
  __builtin_amdgcn_global_load_lds(g1, l3, 16, 0, 0);
}

// tiled bf16 layout: value (m,k), Ktiles=K/32:
//   idx = ((m>>4)*Ktiles + (k>>5))*512 + ((m&15) + 16*((k>>3)&3))*8 + (k&7)

// packed score layout (per 128x128 block bm,bn):
//   elem (r=wr*64+i*16+q*4+d, c=wc*64+(2*jj+ph)*16+lcol) at
//   (bm*64+bn)*16384 + (wr*4+i)*2048 + q*512 + (wc*32+jj*16+lcol)*8 + ph*4 + d

// ---------------------------------------------------------------------------
// Cast fp32 x + 6 weight matrices into bf16 frag-tiled layout.
// ---------------------------------------------------------------------------
__global__ __launch_bounds__(256) void wcast_kernel(
    const float* __restrict__ x, const float* __restrict__ fc1w,
    const float* __restrict__ whw, const float* __restrict__ wtw,
    const float* __restrict__ l1w, const float* __restrict__ l2w,
    const float* __restrict__ a1w,
    unsigned short* __restrict__ xT, unsigned short* __restrict__ fc1T,
    unsigned short* __restrict__ whT, unsigned short* __restrict__ wtT,
    unsigned short* __restrict__ l1T, unsigned short* __restrict__ l2T,
    unsigned short* __restrict__ a1T)
{
  const int gid = blockIdx.x * 256 + threadIdx.x;  // 0 .. 565247
  const float* src; unsigned short* dst; int K8, local;
  if (gid < 417792) {
    K8 = 48;
    if (gid < 393216) { src = x; dst = xT; local = gid; }
    else { src = fc1w; dst = fc1T; local = gid - 393216; }
  } else {
    K8 = 64;
    if (gid < 450560)      { src = whw; dst = whT; local = gid - 417792; }
    else if (gid < 483328) { src = wtw; dst = wtT; local = gid - 450560; }
    else if (gid < 516096) { src = l1w; dst = l1T; local = gid - 483328; }
    else if (gid < 548864) { src = l2w; dst = l2T; local = gid - 516096; }
    else                   { src = a1w; dst = a1T; local = gid - 548864; }
  }
  const int m = local / K8;
  const int k8 = local - m * K8;
  const float* p = src + (size_t)m * (K8 * 8) + k8 * 8;
  float4 v0 = ((const float4*)p)[0];
  float4 v1 = ((const float4*)p)[1];
  const int Kt = K8 >> 2;
  const size_t ti = ((size_t)(m >> 4) * Kt + (k8 >> 2)) * 512 + ((m & 15) + 16 * (k8 & 3)) * 8;
  uint4 pk;
  pk.x = (uint32_t)f2bf(v0.x) | ((uint32_t)f2bf(v0.y) << 16);
  pk.y = (uint32_t)f2bf(v0.z) | ((uint32_t)f2bf(v0.w) << 16);
  pk.z = (uint32_t)f2bf(v1.x) | ((uint32_t)f2bf(v1.y) << 16);
  pk.w = (uint32_t)f2bf(v1.z) | ((uint32_t)f2bf(v1.w) << 16);
  *(uint4*)(dst + ti) = pk;
}

// ---------------------------------------------------------------------------
// MFMA GEMM, tile 128(M) x 64(N), 4 waves each 32x64, K-step 32.
// MODE 0: Cf fp32 = lrelu(A@W1^T + b1)
// MODE 1: T1/T2 = bf16 tiled; Cbf/Cbf2 = bf16 row-major (both linear outputs)
// MODE 2: e = lrelu(A1@W1^T+b1)+lrelu(A2@W2^T+b2); T1 = bf16(e) tiled;
//         Cbf = bf16(e) row-major
// ---------------------------------------------------------------------------
template <int MODE>
__global__ __launch_bounds__(256) void mfma_gemm(
    const unsigned short* __restrict__ At1, const unsigned short* __restrict__ At2,
    const unsigned short* __restrict__ Wt1, const unsigned short* __restrict__ Wt2,
    const float* __restrict__ b1, const float* __restrict__ b2,
    float* __restrict__ Cf, unsigned short* __restrict__ T1,
    unsigned short* __restrict__ T2, unsigned short* __restrict__ Cbf,
    unsigned short* __restrict__ Cbf2, int N, int K)
{
  __shared__ unsigned short As[2][8 * 512];
  __shared__ unsigned short Bs[2][4 * 512];
  const int Kt = K >> 5;
  const int tid = threadIdx.x, lane = tid & 63, w = tid >> 6;
  const int m0 = blockIdx.y * 128, n0 = blockIdx.x * 64;

  f32x4 acc0[2][4], acc1[2][4];
#pragma unroll
  for (int p = 0; p < 2; p++)
#pragma unroll
    for (int j = 0; j < 4; j++) {
      acc0[p][j] = (f32x4){0.f, 0.f, 0.f, 0.f};
      acc1[p][j] = (f32x4){0.f, 0.f, 0.f, 0.f};
    }

  for (int kt = 0; kt < Kt; kt++) {
    const unsigned short* a1p = At1 + ((size_t)((m0 >> 4) + 2 * w) * Kt + kt) * 512 + lane * 8;
    async_cp16(a1p, &As[0][(2 * w) * 512]);
    async_cp16(a1p + (size_t)Kt * 512, &As[0][(2 * w + 1) * 512]);
    if (MODE == 2) {
      const unsigned short* a2p = At2 + ((size_t)((m0 >> 4) + 2 * w) * Kt + kt) * 512 + lane * 8;
      async_cp16(a2p, &As[1][(2 * w) * 512]);
      async_cp16(a2p + (size_t)Kt * 512, &As[1][(2 * w + 1) * 512]);
    }
    const unsigned short* bp1 = Wt1 + ((size_t)((n0 >> 4) + w) * Kt + kt) * 512 + lane * 8;
    async_cp16(bp1, &Bs[0][w * 512]);
    if (MODE >= 1) {
      const unsigned short* bp2 = Wt2 + ((size_t)((n0 >> 4) + w) * Kt + kt) * 512 + lane * 8;
      async_cp16(bp2, &Bs[1][w * 512]);
    }
    __syncthreads();
    short8 a[2], a2[2], bb[4], bb2[4];
#pragma unroll
    for (int p = 0; p < 2; p++) a[p] = *(const short8*)&As[0][(2 * w + p) * 512 + lane * 8];
    if (MODE == 2) {
#pragma unroll
      for (int p = 0; p < 2; p++) a2[p] = *(const short8*)&As[1][(2 * w + p) * 512 + lane * 8];
    }
#pragma unroll
    for (int j = 0; j < 4; j++) bb[j] = *(const short8*)&Bs[0][j * 512 + lane * 8];
    if (MODE >= 1) {
#pragma unroll
      for (int j = 0; j < 4; j++) bb2[j] = *(const short8*)&Bs[1][j * 512 + lane * 8];
    }
#pragma unroll
    for (int p = 0; p < 2; p++)
#pragma unroll
      for (int j = 0; j < 4; j++) {
        acc0[p][j] = __builtin_amdgcn_mfma_f32_16x16x32_bf16(a[p], bb[j], acc0[p][j], 0, 0, 0);
        if (MODE == 1)
          acc1[p][j] = __builtin_amdgcn_mfma_f32_16x16x32_bf16(a[p], bb2[j], acc1[p][j], 0, 0, 0);
        if (MODE == 2)
          acc1[p][j] = __builtin_amdgcn_mfma_f32_16x16x32_bf16(a2[p], bb2[j], acc1[p][j], 0, 0, 0);
      }
    __syncthreads();
  }

  const int lrow = (lane >> 4) * 4, lcol = lane & 15;
  const int NT = N >> 5;
#pragma unroll
  for (int p = 0; p < 2; p++)
#pragma unroll
    for (int j = 0; j < 4; j++) {
      const int c = n0 + j * 16 + lcol;
      const float bias1 = b1[c];
      const float bias2 = (MODE >= 1) ? b2[c] : 0.f;
#pragma unroll
      for (int d = 0; d < 4; d++) {
        const int r = m0 + w * 32 + p * 16 + lrow + d;
        const float v0 = acc0[p][j][d] + bias1;
        if (MODE == 0) {
          Cf[(size_t)r * N + c] = lrelu(v0);
        } else {
          const size_t ti = ((size_t)(r >> 4) * NT + (c >> 5)) * 512 +
                            ((r & 15) + 16 * ((c >> 3) & 3)) * 8 + (c & 7);
          if (MODE == 1) {
            const float v1 = acc1[p][j][d] + bias2;
            T1[ti] = f2bf(v0);
            T2[ti] = f2bf(v1);
            Cbf[(size_t)r * N + c] = f2bf(v0);
            Cbf2[(size_t)r * N + c] = f2bf(v1);
          } else {
            const float e = lrelu(v0) + lrelu(acc1[p][j][d] + bias2);
            T1[ti] = f2bf(e);
            Cbf[(size_t)r * N + c] = f2bf(e);
          }
        }
      }
    }
}

// ---------------------------------------------------------------------------
// Column sum of h over M
// ---------------------------------------------------------------------------
__global__ __launch_bounds__(256) void colsum_kernel(const float* __restrict__ h,
                                                     float* __restrict__ colsum)
{
  const int t = threadIdx.x;
  const int r0 = blockIdx.x * 128;
  float s0 = 0.f, s1 = 0.f;
  for (int r = 0; r < 128; r++) {
    s0 += h[(size_t)(r0 + r) * E_DIM + t];
    s1 += h[(size_t)(r0 + r) * E_DIM + 256 + t];
  }
  atomicAdd(&colsum[t], s0);
  atomicAdd(&colsum[t + 256], s1);
}

// h' = (h + colmean)*0.5 fused with bf16 tiled cast (Ktiles=16)
__global__ __launch_bounds__(256) void hupd_cast_kernel(
    const float* __restrict__ h, const float* __restrict__ colsum,
    unsigned short* __restrict__ hT)
{
  const int gid = blockIdx.x * 256 + threadIdx.x;  // 8192*64
  const int m = gid >> 6, k8 = gid & 63;
  const float* p = h + (size_t)m * E_DIM + k8 * 8;
  float4 v0 = ((const float4*)p)[0];
  float4 v1 = ((const float4*)p)[1];
  float4 c0 = *(const float4*)(colsum + k8 * 8);
  float4 c1 = *(const float4*)(colsum + k8 * 8 + 4);
  const float im = 1.f / (float)M_NODES;
  v0.x = (v0.x + c0.x * im) * 0.5f; v0.y = (v0.y + c0.y * im) * 0.5f;
  v0.z = (v0.z + c0.z * im) * 0.5f; v0.w = (v0.w + c0.w * im) * 0.5f;
  v1.x = (v1.x + c1.x * im) * 0.5f; v1.y = (v1.y + c1.y * im) * 0.5f;
  v1.z = (v1.z + c1.z * im) * 0.5f; v1.w = (v1.w + c1.w * im) * 0.5f;
  const size_t ti = ((size_t)(m >> 4) * 16 + (k8 >> 2)) * 512 + ((m & 15) + 16 * (k8 & 3)) * 8;
  uint4 pk;
  pk.x = (uint32_t)f2bf(v0.x) | ((uint32_t)f2bf(v0.y) << 16);
  pk.y = (uint32_t)f2bf(v0.z) | ((uint32_t)f2bf(v0.w) << 16);
  pk.z = (uint32_t)f2bf(v1.x) | ((uint32_t)f2bf(v1.y) << 16);
  pk.w = (uint32_t)f2bf(v1.z) | ((uint32_t)f2bf(v1.w) << 16);
  *(uint4*)(hT + ti) = pk;
}

// ---------------------------------------------------------------------------
// Full score GEMM: packed-fragment bf16 store (no LDS round-trip) + in-register
// 64-col segment maxima computed from the bf16-ROUNDED values (must match the
// stored scores exactly, else the scan's >=tau guarantee breaks — R8 bug).
// ---------------------------------------------------------------------------
__global__ __launch_bounds__(256) void sgemm_kernel(
    const unsigned short* __restrict__ ehT, const unsigned short* __restrict__ etT,
    unsigned short* __restrict__ sc, float* __restrict__ tmax)
{
  __shared__ unsigned short As[8 * 512];
  __shared__ unsigned short Bs[8 * 512];
  const int tid = threadIdx.x, lane = tid & 63, w = tid >> 6;
  const int wr = w >> 1, wc = w & 1;
  const int m0 = blockIdx.y * 128;
  const int n0 = blockIdx.x * 128;

  f32x4 acc[4][4];
#pragma unroll
  for (int i = 0; i < 4; i++)
#pragma unroll
    for (int j = 0; j < 4; j++) acc[i][j] = (f32x4){0.f, 0.f, 0.f, 0.f};

  for (int kt = 0; kt < 16; kt++) {
    const int s0 = w, s1 = w + 4;
    async_cp16(ehT + ((size_t)((m0 >> 4) + s0) * 16 + kt) * 512 + lane * 8, &As[s0 * 512]);
    async_cp16(ehT + ((size_t)((m0 >> 4) + s1) * 16 + kt) * 512 + lane * 8, &As[s1 * 512]);
    async_cp16(etT + ((size_t)((n0 >> 4) + s0) * 16 + kt) * 512 + lane * 8, &Bs[s0 * 512]);
    async_cp16(etT + ((size_t)((n0 >> 4) + s1) * 16 + kt) * 512 + lane * 8, &Bs[s1 * 512]);
    __syncthreads();
    short8 a[4], b[4];
#pragma unroll
    for (int i = 0; i < 4; i++) a[i] = *(const short8*)&As[(wr * 4 + i) * 512 + lane * 8];
#pragma unroll
    for (int j = 0; j < 4; j++) b[j] = *(const short8*)&Bs[(wc * 4 + j) * 512 + lane * 8];
#pragma unroll
    for (int i = 0; i < 4; i++)
#pragma unroll
      for (int j = 0; j < 4; j++)
        acc[i][j] = __builtin_amdgcn_mfma_f32_16x16x32_bf16(a[i], b[j], acc[i][j], 0, 0, 0);
    __syncthreads();
  }

  // epilogue: direct fragment-packed store (C layout: col=lane&15, row=q*4+d)
  const int q = lane >> 4, lcol = lane & 15;
  const size_t blkbase = ((size_t)blockIdx.y * 64 + blockIdx.x) * 16384;

  float rm[4][4];
#pragma unroll
  for (int i = 0; i < 4; i++)
#pragma unroll
    for (int d = 0; d < 4; d++) rm[i][d] = NEG_BIG;

#pragma unroll
  for (int i = 0; i < 4; i++)
#pragma unroll
    for (int jj = 0; jj < 2; jj++) {
      unsigned short o[8];
#pragma unroll
      for (int d = 0; d < 4; d++) {
        o[d] = f2bf(acc[i][2 * jj][d]);
        o[4 + d] = f2bf(acc[i][2 * jj + 1][d]);
        rm[i][d] = fmaxf(rm[i][d], fmaxf(bf2f(o[d]), bf2f(o[4 + d])));
      }
      const size_t off = blkbase + (size_t)(wr * 4 + i) * 2048 + q * 512 +
                         (wc * 32 + jj * 16 + lcol) * 8;
      *(short8*)(sc + off) = *(short8*)o;
    }

  // butterfly max across the 16-lane lcol group (same q)
#pragma unroll
  for (int i = 0; i < 4; i++)
#pragma unroll
    for (int d = 0; d < 4; d++) {
#pragma unroll
      for (int off = 1; off < 16; off <<= 1)
        rm[i][d] = fmaxf(rm[i][d], __shfl_xor(rm[i][d], off));
    }

  if (lcol == 0) {
#pragma unroll
    for (int i = 0; i < 4; i++)
#pragma unroll
      for (int d = 0; d < 4; d++)
        tmax[(size_t)(m0 + wr * 64 + i * 16 + q * 4 + d) * 128 +
             blockIdx.x * 2 + wc] = rm[i][d];
  }
}

// ---------------------------------------------------------------------------
// Exact top-6 via threshold prefilter on packed scores.
// Workgroup (4 waves) per 4-row group; wave w: tau for row w (Phase A),
// bn-quarter scan (Phase B, shared LDS lists), rank-select row w (Phase C).
// ---------------------------------------------------------------------------
__global__ __launch_bounds__(256) void scan_topk_kernel(
    const unsigned short* __restrict__ sc, const float* __restrict__ tmax,
    float* __restrict__ tkv, int* __restrict__ tki)
{
  __shared__ float cv[4][CAND_CAP];
  __shared__ int   ci[4][CAND_CAP];
  __shared__ int   cnt[4];
  __shared__ float taus[4];
  const int tid = threadIdx.x;
  const int lane = tid & 63;
  const int w = tid >> 6;
  const int rg = blockIdx.x;            // 4-row group id
  const int bm = rg >> 5;               // 128-row block
  const int g = rg & 31;                // group within block
  const int wr = g >> 4, gi = (g >> 2) & 3, gq = g & 3;
  const int r0 = bm * 128 + wr * 64 + gi * 16 + gq * 4;

  if (tid < 4) cnt[tid] = 0;

  // Phase A: wave w computes tau for row r0+w from its 128 segment maxima
  {
    const float* tm = tmax + (size_t)(r0 + w) * 128;
    const float v2 = fmaxf(tm[lane], tm[lane + 64]);
    uint32_t u = __float_as_uint(v2);
    u = ((int)u >= 0) ? (u | 0x80000000u) : ~u;
    uint32_t key = (u & ~63u) | (uint32_t)lane;
    float tau = 0.f;
#pragma unroll
    for (int it = 0; it < 6; it++) {
      uint32_t k = key;
#pragma unroll
      for (int off = 32; off; off >>= 1) {
        const uint32_t o = (uint32_t)__shfl_xor((int)k, off);
        k = k > o ? k : o;
      }
      const int wl = (int)(k & 63u);
      if (it == 5) tau = __shfl(v2, wl);
      if (lane == wl) key = 0u;
    }
    if (lane == 0) taus[w] = tau;
  }
  __syncthreads();
  const float t0 = taus[0], t1 = taus[1], t2 = taus[2], t3 = taus[3];

  // Phase B: wave w scans bn = 16w .. 16w+15 (1KB coalesced per bn)
  const size_t rowoff = (size_t)(wr * 4 + gi) * 2048 + gq * 512 + lane * 8;
  const int colbase = (lane >> 5) * 64 + 2 * ((lane >> 4) & 1) * 16 + (lane & 15);
  for (int t = 0; t < 16; t++) {
    const int bn = w * 16 + t;
    short8 u = *(const short8*)(sc + ((size_t)(bm * 64 + bn)) * 16384 + rowoff);
    const int cb = bn * 128 + colbase;
#pragma unroll
    for (int e = 0; e < 8; e++) {
      const float f = bf2f((unsigned short)u[e]);
      const int d = e & 3;
      const float tau = (d == 0) ? t0 : (d == 1) ? t1 : (d == 2) ? t2 : t3;
      if (f >= tau) {
        const int slot = atomicAdd(&cnt[d], 1);
        if (slot < CAND_CAP) {
          cv[d][slot] = f;
          ci[d][slot] = cb + (e >> 2) * 16;
        }
      }
    }
  }
  __syncthreads();

  // Phase C: wave w rank-selects row r0+w
  int n = cnt[w];
  n = n < CAND_CAP ? n : CAND_CAP;
  for (int c = lane; c < n; c += 64) {
    const float v = cv[w][c];
    const int idx = ci[w][c];
    int rank = 0;
    for (int j = 0; j < n; j++) {
      const float vj = cv[w][j];
      rank += (vj > v) || (vj == v && ci[w][j] < idx);
    }
    if (rank < NTOPK) {
      const size_t base = (size_t)(r0 + w) * NTOPK + rank;
      tkv[base] = v * ATTN_SCALE;
      tki[base] = idx;
    }
  }
}

// ---------------------------------------------------------------------------
// Per-row combine with row-major coalesced gathers.
// ---------------------------------------------------------------------------
__global__ __launch_bounds__(256) void combine_kernel(
    const unsigned short* __restrict__ ehRow, const unsigned short* __restrict__ etRow,
    const float* __restrict__ tkv, const int* __restrict__ tki,
    unsigned short* __restrict__ s1T, unsigned short* __restrict__ s2T)
{
  const int lane = threadIdx.x & 63;
  const int m = blockIdx.x * 4 + (threadIdx.x >> 6);

  float wv[NTOPK]; int id[NTOPK];
#pragma unroll
  for (int k = 0; k < NTOPK; k++) {
    wv[k] = tkv[(size_t)m * NTOPK + k];
    id[k] = tki[(size_t)m * NTOPK + k];
  }

  float mx = wv[0];
#pragma unroll
  for (int k = 1; k < NTOPK; k++) mx = fmaxf(mx, wv[k]);
  float p[NTOPK]; float s = 0.f;
#pragma unroll
  for (int k = 0; k < NTOPK; k++) { p[k] = expf(wv[k] - mx); s += p[k]; }
  const float inv = 1.f / s;
#pragma unroll
  for (int k = 0; k < NTOPK; k++) p[k] *= inv;

  short8 eh8 = *(const short8*)(ehRow + (size_t)m * E_DIM + lane * 8);
  float ehv[8];
#pragma unroll
  for (int e = 0; e < 8; e++) ehv[e] = bf2f((unsigned short)eh8[e]);

  float nv[NTOPK][8];
#pragma unroll
  for (int k = 0; k < NTOPK; k++) {
    short8 nb = *(const short8*)(etRow + (size_t)id[k] * E_DIM + lane * 8);
#pragma unroll
    for (int e = 0; e < 8; e++) nv[k][e] = bf2f((unsigned short)nb[e]);
  }

  float ka[NTOPK];
#pragma unroll
  for (int k = 0; k < NTOPK; k++) {
    float snb = 0.f, sg = 0.f;
    const float aa = 2.f - p[k], bb = p[k];
#pragma unroll
    for (int e = 0; e < 8; e++) {
      snb += nv[k][e];
      sg += tanhf(fmaf(aa, ehv[e], bb * nv[k][e]));
    }
#pragma unroll
    for (int off = 32; off; off >>= 1) {
      snb += __shfl_xor(snb, off);
      sg += __shfl_xor(sg, off);
    }
    ka[k] = snb * sg;
  }
  float km = ka[0];
#pragma unroll
  for (int k = 1; k < NTOPK; k++) km = fmaxf(km, ka[k]);
  float kp[NTOPK]; float ks = 0.f;
#pragma unroll
  for (int k = 0; k < NTOPK; k++) { kp[k] = expf(ka[k] - km); ks += kp[k]; }
  const float kinv = 1.f / ks;

  const size_t tbase = ((size_t)(m >> 4) * 16 + (lane >> 2)) * 512 +
                       ((m & 15) + 16 * (lane & 3)) * 8;
  unsigned short o1[8], o2[8];
#pragma unroll
  for (int e = 0; e < 8; e++) {
    float o = 0.f;
#pragma unroll
    for (int k = 0; k < NTOPK; k++) o = fmaf(kp[k], nv[k][e], o);
    o *= kinv;
    o1[e] = f2bf(ehv[e] + o);
    o2[e] = f2bf(ehv[e] * o);
  }
  *(short8*)(s1T + tbase) = *(short8*)o1;
  *(short8*)(s2T + tbase) = *(short8*)o2;
}

// ---------------------------------------------------------------------------
__global__ __launch_bounds__(256) void gate_g_kernel(
    const float* __restrict__ ahid, const float* __restrict__ a2w,
    const float* __restrict__ a2b, float* __restrict__ g)
{
  const int lane = threadIdx.x & 63;
  const int m = blockIdx.x * 4 + (threadIdx.x >> 6);
  float s = 0.f;
  for (int j = lane; j < 256; j += 64)
    s = fmaf(a2w[j], ahid[(size_t)m * 256 + j], s);
#pragma unroll
  for (int off = 32; off; off >>= 1) s += __shfl_xor(s, off);
  if (lane == 0) g[m] = s + a2b[0];
}

__global__ __launch_bounds__(1024) void softmax_stats_kernel(
    const float* __restrict__ g, float* __restrict__ stats)
{
  __shared__ float red[16];
  __shared__ float red2[16];
  const int t = threadIdx.x;
  float mx = NEG_BIG;
  for (int i = t; i < M_NODES; i += 1024) mx = fmaxf(mx, g[i]);
#pragma unroll
  for (int off = 32; off; off >>= 1) mx = fmaxf(mx, __shfl_xor(mx, off));
  if ((t & 63) == 0) red[t >> 6] = mx;
  __syncthreads();
  float gmx = red[0];
  for (int i = 1; i < 16; i++) gmx = fmaxf(gmx, red[i]);
  float s = 0.f;
  for (int i = t; i < M_NODES; i += 1024) s += expf(g[i] - gmx);
#pragma unroll
  for (int off = 32; off; off >>= 1) s += __shfl_xor(s, off);
  if ((t & 63) == 0) red2[t >> 6] = s;
  __syncthreads();
  if (t == 0) {
    float tot = 0.f;
    for (int i = 0; i < 16; i++) tot += red2[i];
    stats[0] = gmx; stats[1] = tot;
  }
}

__global__ __launch_bounds__(256) void pooled_kernel(
    const unsigned short* __restrict__ emb, const float* __restrict__ g,
    const float* __restrict__ stats, float* __restrict__ pooled)
{
  const int t = threadIdx.x;
  const int r0 = blockIdx.x * 128;
  const float mx = stats[0];
  const float inv = 1.f / stats[1];
  float a0 = 0.f, a1 = 0.f;
  for (int r = 0; r < 128; r++) {
    const int m = r0 + r;
    const float wv = expf(g[m] - mx) * inv;
    a0 = fmaf(wv, bf2f(emb[(size_t)m * E_DIM + t]), a0);
    a1 = fmaf(wv, bf2f(emb[(size_t)m * E_DIM + 256 + t]), a1);
  }
  atomicAdd(&pooled[t], a0);
  atomicAdd(&pooled[t + 256], a1);
}

__global__ __launch_bounds__(512) void ln_kernel(
    const float* __restrict__ pooled, const float* __restrict__ lng,
    const float* __restrict__ lnb, float* __restrict__ out)
{
  __shared__ float red[8];
  __shared__ float red2[8];
  const int t = threadIdx.x;
  const float v = pooled[t];
  float s = v;
#pragma unroll
  for (int off = 32; off; off >>= 1) s += __shfl_xor(s, off);
  if ((t & 63) == 0) red[t >> 6] = s;
  __syncthreads();
  float tot = 0.f;
  for (int i = 0; i < 8; i++) tot += red[i];
  const float mu = tot / (float)E_DIM;
  const float d = v - mu;
  float q = d * d;
#pragma unroll
  for (int off = 32; off; off >>= 1) q += __shfl_xor(q, off);
  if ((t & 63) == 0) red2[t >> 6] = q;
  __syncthreads();
  float vt = 0.f;
  for (int i = 0; i < 8; i++) vt += red2[i];
  const float var = vt / (float)E_DIM;
  out[t] = d * rsqrtf(var + 1e-5f) * lng[t] + lnb[t];
}

// ---------------------------------------------------------------------------
extern "C" void kernel_launch(void* const* d_in, const int* in_sizes, int n_in,
                              void* d_out, int out_size, void* d_ws, size_t ws_size,
                              hipStream_t stream)
{
  const float* x     = (const float*)d_in[0];
  const float* fc1_w = (const float*)d_in[1];
  const float* fc1_b = (const float*)d_in[2];
  const float* wh_w  = (const float*)d_in[3];
  const float* wh_b  = (const float*)d_in[4];
  const float* wt_w  = (const float*)d_in[5];
  const float* wt_b  = (const float*)d_in[6];
  const float* l1_w  = (const float*)d_in[7];
  const float* l1_b  = (const float*)d_in[8];
  const float* l2_w  = (const float*)d_in[9];
  const float* l2_b  = (const float*)d_in[10];
  const float* a1_w  = (const float*)d_in[11];
  const float* a1_b  = (const float*)d_in[12];
  const float* a2_w  = (const float*)d_in[13];
  const float* a2_b  = (const float*)d_in[14];
  const float* ln_g  = (const float*)d_in[15];
  const float* ln_b  = (const float*)d_in[16];

  char* ws = (char*)d_ws;
  const size_t MiB = 1 << 20;
  // weight tiles [0, 3M) — live whole run
  unsigned short* fc1T = (unsigned short*)(ws + 0);
  unsigned short* whT  = (unsigned short*)(ws + 393216);
  unsigned short* wtT  = (unsigned short*)(ws + 917504);
  unsigned short* l1T  = (unsigned short*)(ws + 1441792);
  unsigned short* l2T  = (unsigned short*)(ws + 1966080);
  unsigned short* a1T  = (unsigned short*)(ws + 2490368);
  // activations:
  unsigned short* xT     = (unsigned short*)(ws + 3 * MiB);    // [3,9) wcast->gemm1
  float*          h      = (float*)(ws + 9 * MiB);             // [9,25) gemm1->hupd
  unsigned short* hT     = (unsigned short*)(ws + 25 * MiB);   // [25,33) hupd->gemm2
  unsigned short* ehT    = (unsigned short*)(ws + 33 * MiB);   // [33,41) gemm2->sgemm
  unsigned short* etT    = (unsigned short*)(ws + 41 * MiB);   // [41,49) gemm2->sgemm
  unsigned short* ehRow  = (unsigned short*)(ws + 49 * MiB);   // [49,57) gemm2->combine
  unsigned short* etRow  = (unsigned short*)(ws + 57 * MiB);   // [57,65) gemm2->combine
  float*          tmaxb  = (float*)(ws + 65 * MiB);            // [65,69) sgemm->scan (4MB)
  unsigned short* s1T    = (unsigned short*)(ws + 3 * MiB);    // [3,11) combine->gemm3 (xT,h dead)
  unsigned short* s2T    = (unsigned short*)(ws + 11 * MiB);   // [11,19) combine->gemm3
  unsigned short* embT   = (unsigned short*)(ws + 19 * MiB);   // [19,27) gemm3->gemm4 (h,hT dead)
  unsigned short* embRow = (unsigned short*)(ws + 27 * MiB);   // [27,35) gemm3->pooled (hT,ehT dead)
  float*          ahid   = (float*)(ws + 41 * MiB);            // [41,49) gemm4->gate (etT dead)
  unsigned short* scores = (unsigned short*)(ws + 96 * MiB);   // [96,224) sgemm->scan
  char*           smal   = ws + 69 * MiB;
  float* tkv    = (float*)(smal);                              // 8192*6*4 = 196608
  int*   tki    = (int*)(smal + 196608);                       // 196608
  float* colsum = (float*)(smal + 393216);
  float* g      = (float*)(smal + 395264);
  float* stats  = (float*)(smal + 428032);
  float* pooled = (float*)(smal + 432128);

  // zero tkv/tki (poison-safety: unwritten slot -> id 0, in-bounds) + colsum/
  // g/stats/pooled accumulators
  hipMemsetAsync(smal, 0, 436224, stream);

  // 0. cast x + all weights to bf16 tiled
  wcast_kernel<<<2208, 256, 0, stream>>>(x, fc1_w, wh_w, wt_w, l1_w, l2_w, a1_w,
                                         xT, fc1T, whT, wtT, l1T, l2T, a1T);
  // 1. h = lrelu(x @ fc1^T + b)
  mfma_gemm<0><<<dim3(8, 64), 256, 0, stream>>>(
      xT, nullptr, fc1T, nullptr, fc1_b, nullptr, h, nullptr, nullptr, nullptr, nullptr,
      512, 384);
  // 2. colmean + mix + bf16 tiled cast
  colsum_kernel<<<64, 256, 0, stream>>>(h, colsum);
  hupd_cast_kernel<<<2048, 256, 0, stream>>>(h, colsum, hT);
  // 3. e_h, e_t: tiled (for sgemm) + row-major (for combine)
  mfma_gemm<1><<<dim3(8, 64), 256, 0, stream>>>(
      hT, nullptr, whT, wtT, wh_b, wt_b, nullptr, ehT, etT, ehRow, etRow, 512, 512);
  // 4. full score GEMM (packed store + rounded seg maxima), exact top-6
  sgemm_kernel<<<dim3(64, 64), 256, 0, stream>>>(ehT, etT, scores, tmaxb);
  scan_topk_kernel<<<M_NODES / 4, 256, 0, stream>>>(scores, tmaxb, tkv, tki);
  // 5. combine -> s1T, s2T (bf16 tiled)
  combine_kernel<<<M_NODES / 4, 256, 0, stream>>>(ehRow, etRow, tkv, tki, s1T, s2T);
  // 6. emb = lrelu(s1@l1^T+b1)+lrelu(s2@l2^T+b2) -> bf16 tiled + bf16 row
  mfma_gemm<2><<<dim3(8, 64), 256, 0, stream>>>(
      s1T, s2T, l1T, l2T, l1_b, l2_b, nullptr, embT, nullptr, embRow, nullptr, 512, 512);
  // 7. ahid = lrelu(emb @ a1^T + b)  [8192x256]
  mfma_gemm<0><<<dim3(4, 64), 256, 0, stream>>>(
      embT, nullptr, a1T, nullptr, a1_b, nullptr, ahid, nullptr, nullptr, nullptr, nullptr,
      256, 512);
  // 8-11. readout
  gate_g_kernel<<<M_NODES / 4, 256, 0, stream>>>(ahid, a2_w, a2_b, g);
  softmax_stats_kernel<<<1, 1024, 0, stream>>>(g, stats);
  pooled_kernel<<<64, 256, 0, stream>>>(embRow, g, stats, pooled);
  ln_kernel<<<1, 512, 0, stream>>>(pooled, ln_g, ln_b, (float*)d_out);
}

// Round 10
// 322.954 us; speedup vs baseline: 2.7033x; 1.0467x over previous
//
#include <hip/hip_runtime.h>
#include <math.h>
#include <stdint.h>

#define M_NODES 8192
#define E_DIM   512
#define NTOPK   6
#define ATTN_SCALE 0.04419417382415922f  // 512^-0.5
#define NEG_BIG (-1e38f)
#define CAND_CAP 192

typedef __attribute__((ext_vector_type(8))) short short8;
typedef __attribute__((ext_vector_type(4))) float f32x4;

__device__ __forceinline__ float lrelu(float v) { return v > 0.f ? v : 0.01f * v; }

__device__ __forceinline__ unsigned short f2bf(float f) {
  uint32_t u = __float_as_uint(f);
  uint32_t r = (u + 0x7FFFu + ((u >> 16) & 1u)) >> 16;
  return (unsigned short)r;
}
__device__ __forceinline__ float bf2f(unsigned short s) {
  return __uint_as_float(((uint32_t)s) << 16);
}

// async 16B/lane global->LDS (wave-uniform LDS base, lane i lands at base+16i)
__device__ __forceinline__ void async_cp16(const void* gptr, void* lds) {
  auto g1 = reinterpret_cast<const __attribute__((address_space(1))) unsigned int*>(
      reinterpret_cast<uintptr_t>(gptr));
  auto l3 = reinterpret_cast<__attribute__((address_space(3))) unsigned int*>(
      reinterpret_cast<uintptr_t>(lds));
  __builtin_amdgcn_global_load_lds(g1, l3, 16, 0, 0);
}

// tiled bf16 layout: value (m,k), Ktiles=K/32:
//   idx = ((m>>4)*Ktiles + (k>>5))*512 + ((m&15) + 16*((k>>3)&3))*8 + (k&7)

// packed score layout (per 128x128 block bm,bn):
//   elem (r=wr*64+i*16+q*4+d, c=wc*64+(2*jj+ph)*16+lcol) at
//   (bm*64+bn)*16384 + (wr*4+i)*2048 + q*512 + (wc*32+jj*16+lcol)*8 + ph*4 + d

// ---------------------------------------------------------------------------
// Cast fp32 x + 6 weight matrices into bf16 frag-tiled layout.
// ---------------------------------------------------------------------------
__global__ __launch_bounds__(256) void wcast_kernel(
    const float* __restrict__ x, const float* __restrict__ fc1w,
    const float* __restrict__ whw, const float* __restrict__ wtw,
    const float* __restrict__ l1w, const float* __restrict__ l2w,
    const float* __restrict__ a1w,
    unsigned short* __restrict__ xT, unsigned short* __restrict__ fc1T,
    unsigned short* __restrict__ whT, unsigned short* __restrict__ wtT,
    unsigned short* __restrict__ l1T, unsigned short* __restrict__ l2T,
    unsigned short* __restrict__ a1T)
{
  const int gid = blockIdx.x * 256 + threadIdx.x;  // 0 .. 565247
  const float* src; unsigned short* dst; int K8, local;
  if (gid < 417792) {
    K8 = 48;
    if (gid < 393216) { src = x; dst = xT; local = gid; }
    else { src = fc1w; dst = fc1T; local = gid - 393216; }
  } else {
    K8 = 64;
    if (gid < 450560)      { src = whw; dst = whT; local = gid - 417792; }
    else if (gid < 483328) { src = wtw; dst = wtT; local = gid - 450560; }
    else if (gid < 516096) { src = l1w; dst = l1T; local = gid - 483328; }
    else if (gid < 548864) { src = l2w; dst = l2T; local = gid - 516096; }
    else                   { src = a1w; dst = a1T; local = gid - 548864; }
  }
  const int m = local / K8;
  const int k8 = local - m * K8;
  const float* p = src + (size_t)m * (K8 * 8) + k8 * 8;
  float4 v0 = ((const float4*)p)[0];
  float4 v1 = ((const float4*)p)[1];
  const int Kt = K8 >> 2;
  const size_t ti = ((size_t)(m >> 4) * Kt + (k8 >> 2)) * 512 + ((m & 15) + 16 * (k8 & 3)) * 8;
  uint4 pk;
  pk.x = (uint32_t)f2bf(v0.x) | ((uint32_t)f2bf(v0.y) << 16);
  pk.y = (uint32_t)f2bf(v0.z) | ((uint32_t)f2bf(v0.w) << 16);
  pk.z = (uint32_t)f2bf(v1.x) | ((uint32_t)f2bf(v1.y) << 16);
  pk.w = (uint32_t)f2bf(v1.z) | ((uint32_t)f2bf(v1.w) << 16);
  *(uint4*)(dst + ti) = pk;
}

// ---------------------------------------------------------------------------
// MFMA GEMM, tile 128(M) x 64(N), 4 waves each 32x64, K-step 32.
// MODE 0: Cf fp32 = lrelu(A@W1^T + b1)
// MODE 1: T1/T2 = bf16 tiled; Cbf/Cbf2 = bf16 row-major (both linear outputs)
// MODE 2: e = lrelu(A1@W1^T+b1)+lrelu(A2@W2^T+b2); T1 = bf16(e) tiled;
//         Cbf = bf16(e) row-major
// MODE 3: g[r] += sum_c lrelu(A@W1^T+b1)[r,c] * b2[c]  (fused gate readout;
//         Cf = g, b2 = a2 weights; a2 bias dropped — softmax shift-invariant)
// ---------------------------------------------------------------------------
template <int MODE>
__global__ __launch_bounds__(256) void mfma_gemm(
    const unsigned short* __restrict__ At1, const unsigned short* __restrict__ At2,
    const unsigned short* __restrict__ Wt1, const unsigned short* __restrict__ Wt2,
    const float* __restrict__ b1, const float* __restrict__ b2,
    float* __restrict__ Cf, unsigned short* __restrict__ T1,
    unsigned short* __restrict__ T2, unsigned short* __restrict__ Cbf,
    unsigned short* __restrict__ Cbf2, int N, int K)
{
  constexpr bool DUALW = (MODE == 1 || MODE == 2);
  __shared__ unsigned short As[2][8 * 512];
  __shared__ unsigned short Bs[2][4 * 512];
  const int Kt = K >> 5;
  const int tid = threadIdx.x, lane = tid & 63, w = tid >> 6;
  const int m0 = blockIdx.y * 128, n0 = blockIdx.x * 64;

  f32x4 acc0[2][4], acc1[2][4];
#pragma unroll
  for (int p = 0; p < 2; p++)
#pragma unroll
    for (int j = 0; j < 4; j++) {
      acc0[p][j] = (f32x4){0.f, 0.f, 0.f, 0.f};
      acc1[p][j] = (f32x4){0.f, 0.f, 0.f, 0.f};
    }

  for (int kt = 0; kt < Kt; kt++) {
    const unsigned short* a1p = At1 + ((size_t)((m0 >> 4) + 2 * w) * Kt + kt) * 512 + lane * 8;
    async_cp16(a1p, &As[0][(2 * w) * 512]);
    async_cp16(a1p + (size_t)Kt * 512, &As[0][(2 * w + 1) * 512]);
    if (MODE == 2) {
      const unsigned short* a2p = At2 + ((size_t)((m0 >> 4) + 2 * w) * Kt + kt) * 512 + lane * 8;
      async_cp16(a2p, &As[1][(2 * w) * 512]);
      async_cp16(a2p + (size_t)Kt * 512, &As[1][(2 * w + 1) * 512]);
    }
    const unsigned short* bp1 = Wt1 + ((size_t)((n0 >> 4) + w) * Kt + kt) * 512 + lane * 8;
    async_cp16(bp1, &Bs[0][w * 512]);
    if (DUALW) {
      const unsigned short* bp2 = Wt2 + ((size_t)((n0 >> 4) + w) * Kt + kt) * 512 + lane * 8;
      async_cp16(bp2, &Bs[1][w * 512]);
    }
    __syncthreads();
    short8 a[2], a2[2], bb[4], bb2[4];
#pragma unroll
    for (int p = 0; p < 2; p++) a[p] = *(const short8*)&As[0][(2 * w + p) * 512 + lane * 8];
    if (MODE == 2) {
#pragma unroll
      for (int p = 0; p < 2; p++) a2[p] = *(const short8*)&As[1][(2 * w + p) * 512 + lane * 8];
    }
#pragma unroll
    for (int j = 0; j < 4; j++) bb[j] = *(const short8*)&Bs[0][j * 512 + lane * 8];
    if (DUALW) {
#pragma unroll
      for (int j = 0; j < 4; j++) bb2[j] = *(const short8*)&Bs[1][j * 512 + lane * 8];
    }
#pragma unroll
    for (int p = 0; p < 2; p++)
#pragma unroll
      for (int j = 0; j < 4; j++) {
        acc0[p][j] = __builtin_amdgcn_mfma_f32_16x16x32_bf16(a[p], bb[j], acc0[p][j], 0, 0, 0);
        if (MODE == 1)
          acc1[p][j] = __builtin_amdgcn_mfma_f32_16x16x32_bf16(a[p], bb2[j], acc1[p][j], 0, 0, 0);
        if (MODE == 2)
          acc1[p][j] = __builtin_amdgcn_mfma_f32_16x16x32_bf16(a2[p], bb2[j], acc1[p][j], 0, 0, 0);
      }
    __syncthreads();
  }

  const int lrow = (lane >> 4) * 4, lcol = lane & 15;

  if (MODE == 3) {
    // fused gate: partial dot over this block's 64 cols, reduce over lcol
    float part[2][4] = {};
#pragma unroll
    for (int p = 0; p < 2; p++)
#pragma unroll
      for (int j = 0; j < 4; j++) {
        const int c = n0 + j * 16 + lcol;
        const float bias1 = b1[c];
        const float w2 = b2[c];
#pragma unroll
        for (int d = 0; d < 4; d++)
          part[p][d] = fmaf(lrelu(acc0[p][j][d] + bias1), w2, part[p][d]);
      }
#pragma unroll
    for (int p = 0; p < 2; p++)
#pragma unroll
      for (int d = 0; d < 4; d++) {
#pragma unroll
        for (int off = 1; off < 16; off <<= 1)
          part[p][d] += __shfl_xor(part[p][d], off);
      }
    if (lcol == 0) {
#pragma unroll
      for (int p = 0; p < 2; p++)
#pragma unroll
        for (int d = 0; d < 4; d++)
          atomicAdd(&Cf[m0 + w * 32 + p * 16 + lrow + d], part[p][d]);
    }
    return;
  }

  const int NT = N >> 5;
#pragma unroll
  for (int p = 0; p < 2; p++)
#pragma unroll
    for (int j = 0; j < 4; j++) {
      const int c = n0 + j * 16 + lcol;
      const float bias1 = b1[c];
      const float bias2 = DUALW ? b2[c] : 0.f;
#pragma unroll
      for (int d = 0; d < 4; d++) {
        const int r = m0 + w * 32 + p * 16 + lrow + d;
        const float v0 = acc0[p][j][d] + bias1;
        if (MODE == 0) {
          Cf[(size_t)r * N + c] = lrelu(v0);
        } else {
          const size_t ti = ((size_t)(r >> 4) * NT + (c >> 5)) * 512 +
                            ((r & 15) + 16 * ((c >> 3) & 3)) * 8 + (c & 7);
          if (MODE == 1) {
            const float v1 = acc1[p][j][d] + bias2;
            T1[ti] = f2bf(v0);
            T2[ti] = f2bf(v1);
            Cbf[(size_t)r * N + c] = f2bf(v0);
            Cbf2[(size_t)r * N + c] = f2bf(v1);
          } else {
            const float e = lrelu(v0) + lrelu(acc1[p][j][d] + bias2);
            T1[ti] = f2bf(e);
            Cbf[(size_t)r * N + c] = f2bf(e);
          }
        }
      }
    }
}

// ---------------------------------------------------------------------------
// Column sum of h over M
// ---------------------------------------------------------------------------
__global__ __launch_bounds__(256) void colsum_kernel(const float* __restrict__ h,
                                                     float* __restrict__ colsum)
{
  const int t = threadIdx.x;
  const int r0 = blockIdx.x * 128;
  float s0 = 0.f, s1 = 0.f;
  for (int r = 0; r < 128; r++) {
    s0 += h[(size_t)(r0 + r) * E_DIM + t];
    s1 += h[(size_t)(r0 + r) * E_DIM + 256 + t];
  }
  atomicAdd(&colsum[t], s0);
  atomicAdd(&colsum[t + 256], s1);
}

// h' = (h + colmean)*0.5 fused with bf16 tiled cast (Ktiles=16)
__global__ __launch_bounds__(256) void hupd_cast_kernel(
    const float* __restrict__ h, const float* __restrict__ colsum,
    unsigned short* __restrict__ hT)
{
  const int gid = blockIdx.x * 256 + threadIdx.x;  // 8192*64
  const int m = gid >> 6, k8 = gid & 63;
  const float* p = h + (size_t)m * E_DIM + k8 * 8;
  float4 v0 = ((const float4*)p)[0];
  float4 v1 = ((const float4*)p)[1];
  float4 c0 = *(const float4*)(colsum + k8 * 8);
  float4 c1 = *(const float4*)(colsum + k8 * 8 + 4);
  const float im = 1.f / (float)M_NODES;
  v0.x = (v0.x + c0.x * im) * 0.5f; v0.y = (v0.y + c0.y * im) * 0.5f;
  v0.z = (v0.z + c0.z * im) * 0.5f; v0.w = (v0.w + c0.w * im) * 0.5f;
  v1.x = (v1.x + c1.x * im) * 0.5f; v1.y = (v1.y + c1.y * im) * 0.5f;
  v1.z = (v1.z + c1.z * im) * 0.5f; v1.w = (v1.w + c1.w * im) * 0.5f;
  const size_t ti = ((size_t)(m >> 4) * 16 + (k8 >> 2)) * 512 + ((m & 15) + 16 * (k8 & 3)) * 8;
  uint4 pk;
  pk.x = (uint32_t)f2bf(v0.x) | ((uint32_t)f2bf(v0.y) << 16);
  pk.y = (uint32_t)f2bf(v0.z) | ((uint32_t)f2bf(v0.w) << 16);
  pk.z = (uint32_t)f2bf(v1.x) | ((uint32_t)f2bf(v1.y) << 16);
  pk.w = (uint32_t)f2bf(v1.z) | ((uint32_t)f2bf(v1.w) << 16);
  *(uint4*)(hT + ti) = pk;
}

// ---------------------------------------------------------------------------
// Full score GEMM: packed-fragment bf16 store + in-register seg maxima from
// the bf16-ROUNDED values (must match stored scores exactly — R8 lesson).
// __launch_bounds__(256,4): cap regs at 128 total (64 VGPR + 64 acc) so 4
// waves/SIMD can hide the 2-barrier K-loop drain (was 136 regs -> 3 waves).
// ---------------------------------------------------------------------------
__global__ __launch_bounds__(256, 4) void sgemm_kernel(
    const unsigned short* __restrict__ ehT, const unsigned short* __restrict__ etT,
    unsigned short* __restrict__ sc, float* __restrict__ tmax)
{
  __shared__ unsigned short As[8 * 512];
  __shared__ unsigned short Bs[8 * 512];
  const int tid = threadIdx.x, lane = tid & 63, w = tid >> 6;
  const int wr = w >> 1, wc = w & 1;
  const int m0 = blockIdx.y * 128;
  const int n0 = blockIdx.x * 128;

  f32x4 acc[4][4];
#pragma unroll
  for (int i = 0; i < 4; i++)
#pragma unroll
    for (int j = 0; j < 4; j++) acc[i][j] = (f32x4){0.f, 0.f, 0.f, 0.f};

  for (int kt = 0; kt < 16; kt++) {
    const int s0 = w, s1 = w + 4;
    async_cp16(ehT + ((size_t)((m0 >> 4) + s0) * 16 + kt) * 512 + lane * 8, &As[s0 * 512]);
    async_cp16(ehT + ((size_t)((m0 >> 4) + s1) * 16 + kt) * 512 + lane * 8, &As[s1 * 512]);
    async_cp16(etT + ((size_t)((n0 >> 4) + s0) * 16 + kt) * 512 + lane * 8, &Bs[s0 * 512]);
    async_cp16(etT + ((size_t)((n0 >> 4) + s1) * 16 + kt) * 512 + lane * 8, &Bs[s1 * 512]);
    __syncthreads();
    short8 a[4], b[4];
#pragma unroll
    for (int i = 0; i < 4; i++) a[i] = *(const short8*)&As[(wr * 4 + i) * 512 + lane * 8];
#pragma unroll
    for (int j = 0; j < 4; j++) b[j] = *(const short8*)&Bs[(wc * 4 + j) * 512 + lane * 8];
#pragma unroll
    for (int i = 0; i < 4; i++)
#pragma unroll
      for (int j = 0; j < 4; j++)
        acc[i][j] = __builtin_amdgcn_mfma_f32_16x16x32_bf16(a[i], b[j], acc[i][j], 0, 0, 0);
    __syncthreads();
  }

  // epilogue: direct fragment-packed store (C layout: col=lane&15, row=q*4+d)
  const int q = lane >> 4, lcol = lane & 15;
  const size_t blkbase = ((size_t)blockIdx.y * 64 + blockIdx.x) * 16384;

  float rm[4][4];
#pragma unroll
  for (int i = 0; i < 4; i++)
#pragma unroll
    for (int d = 0; d < 4; d++) rm[i][d] = NEG_BIG;

#pragma unroll
  for (int i = 0; i < 4; i++)
#pragma unroll
    for (int jj = 0; jj < 2; jj++) {
      unsigned short o[8];
#pragma unroll
      for (int d = 0; d < 4; d++) {
        o[d] = f2bf(acc[i][2 * jj][d]);
        o[4 + d] = f2bf(acc[i][2 * jj + 1][d]);
        rm[i][d] = fmaxf(rm[i][d], fmaxf(bf2f(o[d]), bf2f(o[4 + d])));
      }
      const size_t off = blkbase + (size_t)(wr * 4 + i) * 2048 + q * 512 +
                         (wc * 32 + jj * 16 + lcol) * 8;
      *(short8*)(sc + off) = *(short8*)o;
    }

  // butterfly max across the 16-lane lcol group (same q)
#pragma unroll
  for (int i = 0; i < 4; i++)
#pragma unroll
    for (int d = 0; d < 4; d++) {
#pragma unroll
      for (int off = 1; off < 16; off <<= 1)
        rm[i][d] = fmaxf(rm[i][d], __shfl_xor(rm[i][d], off));
    }

  if (lcol == 0) {
#pragma unroll
    for (int i = 0; i < 4; i++)
#pragma unroll
      for (int d = 0; d < 4; d++)
        tmax[(size_t)(m0 + wr * 64 + i * 16 + q * 4 + d) * 128 +
             blockIdx.x * 2 + wc] = rm[i][d];
  }
}

// ---------------------------------------------------------------------------
// Exact top-6 via threshold prefilter on packed scores.
// ---------------------------------------------------------------------------
__global__ __launch_bounds__(256) void scan_topk_kernel(
    const unsigned short* __restrict__ sc, const float* __restrict__ tmax,
    float* __restrict__ tkv, int* __restrict__ tki)
{
  __shared__ float cv[4][CAND_CAP];
  __shared__ int   ci[4][CAND_CAP];
  __shared__ int   cnt[4];
  __shared__ float taus[4];
  const int tid = threadIdx.x;
  const int lane = tid & 63;
  const int w = tid >> 6;
  const int rg = blockIdx.x;            // 4-row group id
  const int bm = rg >> 5;               // 128-row block
  const int g = rg & 31;                // group within block
  const int wr = g >> 4, gi = (g >> 2) & 3, gq = g & 3;
  const int r0 = bm * 128 + wr * 64 + gi * 16 + gq * 4;

  if (tid < 4) cnt[tid] = 0;

  // Phase A: wave w computes tau for row r0+w from its 128 segment maxima
  {
    const float* tm = tmax + (size_t)(r0 + w) * 128;
    const float v2 = fmaxf(tm[lane], tm[lane + 64]);
    uint32_t u = __float_as_uint(v2);
    u = ((int)u >= 0) ? (u | 0x80000000u) : ~u;
    uint32_t key = (u & ~63u) | (uint32_t)lane;
    float tau = 0.f;
#pragma unroll
    for (int it = 0; it < 6; it++) {
      uint32_t k = key;
#pragma unroll
      for (int off = 32; off; off >>= 1) {
        const uint32_t o = (uint32_t)__shfl_xor((int)k, off);
        k = k > o ? k : o;
      }
      const int wl = (int)(k & 63u);
      if (it == 5) tau = __shfl(v2, wl);
      if (lane == wl) key = 0u;
    }
    if (lane == 0) taus[w] = tau;
  }
  __syncthreads();
  const float t0 = taus[0], t1 = taus[1], t2 = taus[2], t3 = taus[3];

  // Phase B: wave w scans bn = 16w .. 16w+15 (1KB coalesced per bn)
  const size_t rowoff = (size_t)(wr * 4 + gi) * 2048 + gq * 512 + lane * 8;
  const int colbase = (lane >> 5) * 64 + 2 * ((lane >> 4) & 1) * 16 + (lane & 15);
  for (int t = 0; t < 16; t++) {
    const int bn = w * 16 + t;
    short8 u = *(const short8*)(sc + ((size_t)(bm * 64 + bn)) * 16384 + rowoff);
    const int cb = bn * 128 + colbase;
#pragma unroll
    for (int e = 0; e < 8; e++) {
      const float f = bf2f((unsigned short)u[e]);
      const int d = e & 3;
      const float tau = (d == 0) ? t0 : (d == 1) ? t1 : (d == 2) ? t2 : t3;
      if (f >= tau) {
        const int slot = atomicAdd(&cnt[d], 1);
        if (slot < CAND_CAP) {
          cv[d][slot] = f;
          ci[d][slot] = cb + (e >> 2) * 16;
        }
      }
    }
  }
  __syncthreads();

  // Phase C: wave w rank-selects row r0+w
  int n = cnt[w];
  n = n < CAND_CAP ? n : CAND_CAP;
  for (int c = lane; c < n; c += 64) {
    const float v = cv[w][c];
    const int idx = ci[w][c];
    int rank = 0;
    for (int j = 0; j < n; j++) {
      const float vj = cv[w][j];
      rank += (vj > v) || (vj == v && ci[w][j] < idx);
    }
    if (rank < NTOPK) {
      const size_t base = (size_t)(r0 + w) * NTOPK + rank;
      tkv[base] = v * ATTN_SCALE;
      tki[base] = idx;
    }
  }
}

// ---------------------------------------------------------------------------
// Per-row combine with row-major coalesced gathers.
// ---------------------------------------------------------------------------
__global__ __launch_bounds__(256) void combine_kernel(
    const unsigned short* __restrict__ ehRow, const unsigned short* __restrict__ etRow,
    const float* __restrict__ tkv, const int* __restrict__ tki,
    unsigned short* __restrict__ s1T, unsigned short* __restrict__ s2T)
{
  const int lane = threadIdx.x & 63;
  const int m = blockIdx.x * 4 + (threadIdx.x >> 6);

  float wv[NTOPK]; int id[NTOPK];
#pragma unroll
  for (int k = 0; k < NTOPK; k++) {
    wv[k] = tkv[(size_t)m * NTOPK + k];
    id[k] = tki[(size_t)m * NTOPK + k];
  }

  float mx = wv[0];
#pragma unroll
  for (int k = 1; k < NTOPK; k++) mx = fmaxf(mx, wv[k]);
  float p[NTOPK]; float s = 0.f;
#pragma unroll
  for (int k = 0; k < NTOPK; k++) { p[k] = expf(wv[k] - mx); s += p[k]; }
  const float inv = 1.f / s;
#pragma unroll
  for (int k = 0; k < NTOPK; k++) p[k] *= inv;

  short8 eh8 = *(const short8*)(ehRow + (size_t)m * E_DIM + lane * 8);
  float ehv[8];
#pragma unroll
  for (int e = 0; e < 8; e++) ehv[e] = bf2f((unsigned short)eh8[e]);

  float nv[NTOPK][8];
#pragma unroll
  for (int k = 0; k < NTOPK; k++) {
    short8 nb = *(const short8*)(etRow + (size_t)id[k] * E_DIM + lane * 8);
#pragma unroll
    for (int e = 0; e < 8; e++) nv[k][e] = bf2f((unsigned short)nb[e]);
  }

  float ka[NTOPK];
#pragma unroll
  for (int k = 0; k < NTOPK; k++) {
    float snb = 0.f, sg = 0.f;
    const float aa = 2.f - p[k], bb = p[k];
#pragma unroll
    for (int e = 0; e < 8; e++) {
      snb += nv[k][e];
      sg += tanhf(fmaf(aa, ehv[e], bb * nv[k][e]));
    }
#pragma unroll
    for (int off = 32; off; off >>= 1) {
      snb += __shfl_xor(snb, off);
      sg += __shfl_xor(sg, off);
    }
    ka[k] = snb * sg;
  }
  float km = ka[0];
#pragma unroll
  for (int k = 1; k < NTOPK; k++) km = fmaxf(km, ka[k]);
  float kp[NTOPK]; float ks = 0.f;
#pragma unroll
  for (int k = 0; k < NTOPK; k++) { kp[k] = expf(ka[k] - km); ks += kp[k]; }
  const float kinv = 1.f / ks;

  const size_t tbase = ((size_t)(m >> 4) * 16 + (lane >> 2)) * 512 +
                       ((m & 15) + 16 * (lane & 3)) * 8;
  unsigned short o1[8], o2[8];
#pragma unroll
  for (int e = 0; e < 8; e++) {
    float o = 0.f;
#pragma unroll
    for (int k = 0; k < NTOPK; k++) o = fmaf(kp[k], nv[k][e], o);
    o *= kinv;
    o1[e] = f2bf(ehv[e] + o);
    o2[e] = f2bf(ehv[e] * o);
  }
  *(short8*)(s1T + tbase) = *(short8*)o1;
  *(short8*)(s2T + tbase) = *(short8*)o2;
}

// ---------------------------------------------------------------------------
__global__ __launch_bounds__(1024) void softmax_stats_kernel(
    const float* __restrict__ g, float* __restrict__ stats)
{
  __shared__ float red[16];
  __shared__ float red2[16];
  const int t = threadIdx.x;
  float mx = NEG_BIG;
  for (int i = t; i < M_NODES; i += 1024) mx = fmaxf(mx, g[i]);
#pragma unroll
  for (int off = 32; off; off >>= 1) mx = fmaxf(mx, __shfl_xor(mx, off));
  if ((t & 63) == 0) red[t >> 6] = mx;
  __syncthreads();
  float gmx = red[0];
  for (int i = 1; i < 16; i++) gmx = fmaxf(gmx, red[i]);
  float s = 0.f;
  for (int i = t; i < M_NODES; i += 1024) s += expf(g[i] - gmx);
#pragma unroll
  for (int off = 32; off; off >>= 1) s += __shfl_xor(s, off);
  if ((t & 63) == 0) red2[t >> 6] = s;
  __syncthreads();
  if (t == 0) {
    float tot = 0.f;
    for (int i = 0; i < 16; i++) tot += red2[i];
    stats[0] = gmx; stats[1] = tot;
  }
}

__global__ __launch_bounds__(256) void pooled_kernel(
    const unsigned short* __restrict__ emb, const float* __restrict__ g,
    const float* __restrict__ stats, float* __restrict__ pooled)
{
  const int t = threadIdx.x;
  const int r0 = blockIdx.x * 128;
  const float mx = stats[0];
  const float inv = 1.f / stats[1];
  float a0 = 0.f, a1 = 0.f;
  for (int r = 0; r < 128; r++) {
    const int m = r0 + r;
    const float wv = expf(g[m] - mx) * inv;
    a0 = fmaf(wv, bf2f(emb[(size_t)m * E_DIM + t]), a0);
    a1 = fmaf(wv, bf2f(emb[(size_t)m * E_DIM + 256 + t]), a1);
  }
  atomicAdd(&pooled[t], a0);
  atomicAdd(&pooled[t + 256], a1);
}

__global__ __launch_bounds__(512) void ln_kernel(
    const float* __restrict__ pooled, const float* __restrict__ lng,
    const float* __restrict__ lnb, float* __restrict__ out)
{
  __shared__ float red[8];
  __shared__ float red2[8];
  const int t = threadIdx.x;
  const float v = pooled[t];
  float s = v;
#pragma unroll
  for (int off = 32; off; off >>= 1) s += __shfl_xor(s, off);
  if ((t & 63) == 0) red[t >> 6] = s;
  __syncthreads();
  float tot = 0.f;
  for (int i = 0; i < 8; i++) tot += red[i];
  const float mu = tot / (float)E_DIM;
  const float d = v - mu;
  float q = d * d;
#pragma unroll
  for (int off = 32; off; off >>= 1) q += __shfl_xor(q, off);
  if ((t & 63) == 0) red2[t >> 6] = q;
  __syncthreads();
  float vt = 0.f;
  for (int i = 0; i < 8; i++) vt += red2[i];
  const float var = vt / (float)E_DIM;
  out[t] = d * rsqrtf(var + 1e-5f) * lng[t] + lnb[t];
}

// ---------------------------------------------------------------------------
extern "C" void kernel_launch(void* const* d_in, const int* in_sizes, int n_in,
                              void* d_out, int out_size, void* d_ws, size_t ws_size,
                              hipStream_t stream)
{
  const float* x     = (const float*)d_in[0];
  const float* fc1_w = (const float*)d_in[1];
  const float* fc1_b = (const float*)d_in[2];
  const float* wh_w  = (const float*)d_in[3];
  const float* wh_b  = (const float*)d_in[4];
  const float* wt_w  = (const float*)d_in[5];
  const float* wt_b  = (const float*)d_in[6];
  const float* l1_w  = (const float*)d_in[7];
  const float* l1_b  = (const float*)d_in[8];
  const float* l2_w  = (const float*)d_in[9];
  const float* l2_b  = (const float*)d_in[10];
  const float* a1_w  = (const float*)d_in[11];
  const float* a1_b  = (const float*)d_in[12];
  const float* a2_w  = (const float*)d_in[13];
  const float* a2_b  = (const float*)d_in[14];
  const float* ln_g  = (const float*)d_in[15];
  const float* ln_b  = (const float*)d_in[16];
  (void)a2_b;  // exactly cancels in softmax (shift invariance)

  char* ws = (char*)d_ws;
  const size_t MiB = 1 << 20;
  // weight tiles [0, 3M) — live whole run
  unsigned short* fc1T = (unsigned short*)(ws + 0);
  unsigned short* whT  = (unsigned short*)(ws + 393216);
  unsigned short* wtT  = (unsigned short*)(ws + 917504);
  unsigned short* l1T  = (unsigned short*)(ws + 1441792);
  unsigned short* l2T  = (unsigned short*)(ws + 1966080);
  unsigned short* a1T  = (unsigned short*)(ws + 2490368);
  // activations:
  unsigned short* xT     = (unsigned short*)(ws + 3 * MiB);    // [3,9) wcast->gemm1
  float*          h      = (float*)(ws + 9 * MiB);             // [9,25) gemm1->hupd
  unsigned short* hT     = (unsigned short*)(ws + 25 * MiB);   // [25,33) hupd->gemm2
  unsigned short* ehT    = (unsigned short*)(ws + 33 * MiB);   // [33,41) gemm2->sgemm
  unsigned short* etT    = (unsigned short*)(ws + 41 * MiB);   // [41,49) gemm2->sgemm
  unsigned short* ehRow  = (unsigned short*)(ws + 49 * MiB);   // [49,57) gemm2->combine
  unsigned short* etRow  = (unsigned short*)(ws + 57 * MiB);   // [57,65) gemm2->combine
  float*          tmaxb  = (float*)(ws + 65 * MiB);            // [65,69) sgemm->scan (4MB)
  unsigned short* s1T    = (unsigned short*)(ws + 3 * MiB);    // [3,11) combine->gemm3 (xT,h dead)
  unsigned short* s2T    = (unsigned short*)(ws + 11 * MiB);   // [11,19) combine->gemm3
  unsigned short* embT   = (unsigned short*)(ws + 19 * MiB);   // [19,27) gemm3->gemm4 (h,hT dead)
  unsigned short* embRow = (unsigned short*)(ws + 27 * MiB);   // [27,35) gemm3->pooled (hT,ehT dead)
  unsigned short* scores = (unsigned short*)(ws + 96 * MiB);   // [96,224) sgemm->scan
  char*           smal   = ws + 69 * MiB;
  float* tkv    = (float*)(smal);                              // 8192*6*4 = 196608
  int*   tki    = (int*)(smal + 196608);                       // 196608
  float* colsum = (float*)(smal + 393216);
  float* g      = (float*)(smal + 395264);
  float* stats  = (float*)(smal + 428032);
  float* pooled = (float*)(smal + 432128);

  // zero tkv/tki (poison-safety) + colsum/g/stats/pooled accumulators
  hipMemsetAsync(smal, 0, 436224, stream);

  // 0. cast x + all weights to bf16 tiled
  wcast_kernel<<<2208, 256, 0, stream>>>(x, fc1_w, wh_w, wt_w, l1_w, l2_w, a1_w,
                                         xT, fc1T, whT, wtT, l1T, l2T, a1T);
  // 1. h = lrelu(x @ fc1^T + b)
  mfma_gemm<0><<<dim3(8, 64), 256, 0, stream>>>(
      xT, nullptr, fc1T, nullptr, fc1_b, nullptr, h, nullptr, nullptr, nullptr, nullptr,
      512, 384);
  // 2. colmean + mix + bf16 tiled cast
  colsum_kernel<<<64, 256, 0, stream>>>(h, colsum);
  hupd_cast_kernel<<<2048, 256, 0, stream>>>(h, colsum, hT);
  // 3. e_h, e_t: tiled (for sgemm) + row-major (for combine)
  mfma_gemm<1><<<dim3(8, 64), 256, 0, stream>>>(
      hT, nullptr, whT, wtT, wh_b, wt_b, nullptr, ehT, etT, ehRow, etRow, 512, 512);
  // 4. full score GEMM (packed store + rounded seg maxima), exact top-6
  sgemm_kernel<<<dim3(64, 64), 256, 0, stream>>>(ehT, etT, scores, tmaxb);
  scan_topk_kernel<<<M_NODES / 4, 256, 0, stream>>>(scores, tmaxb, tkv, tki);
  // 5. combine -> s1T, s2T (bf16 tiled)
  combine_kernel<<<M_NODES / 4, 256, 0, stream>>>(ehRow, etRow, tkv, tki, s1T, s2T);
  // 6. emb = lrelu(s1@l1^T+b1)+lrelu(s2@l2^T+b2) -> bf16 tiled + bf16 row
  mfma_gemm<2><<<dim3(8, 64), 256, 0, stream>>>(
      s1T, s2T, l1T, l2T, l1_b, l2_b, nullptr, embT, nullptr, embRow, nullptr, 512, 512);
  // 7+8 fused: g[m] = sum_c lrelu(emb@a1^T+b)[m,c] * a2w[c]  (a2 bias dropped)
  mfma_gemm<3><<<dim3(4, 64), 256, 0, stream>>>(
      embT, nullptr, a1T, nullptr, a1_b, a2_w, g, nullptr, nullptr, nullptr, nullptr,
      256, 512);
  // 9-11. readout
  softmax_stats_kernel<<<1, 1024, 0, stream>>>(g, stats);
  pooled_kernel<<<64, 256, 0, stream>>>(embRow, g, stats, pooled);
  ln_kernel<<<1, 512, 0, stream>>>(pooled, ln_g, ln_b, (float*)d_out);
}

// Round 11
// 306.326 us; speedup vs baseline: 2.8501x; 1.0543x over previous
//
#include <hip/hip_runtime.h>
#include <math.h>
#include <stdint.h>

#define M_NODES 8192
#define E_DIM   512
#define NTOPK   6
#define ATTN_SCALE 0.04419417382415922f  // 512^-0.5
#define NEG_BIG (-1e38f)
#define CAND_CAP 192

typedef __attribute__((ext_vector_type(8))) short short8;
typedef __attribute__((ext_vector_type(4))) float f32x4;

__device__ __forceinline__ float lrelu(float v) { return v > 0.f ? v : 0.01f * v; }

__device__ __forceinline__ unsigned short f2bf(float f) {
  uint32_t u = __float_as_uint(f);
  uint32_t r = (u + 0x7FFFu + ((u >> 16) & 1u)) >> 16;
  return (unsigned short)r;
}
__device__ __forceinline__ float bf2f(unsigned short s) {
  return __uint_as_float(((uint32_t)s) << 16);
}

// async 16B/lane global->LDS (wave-uniform LDS base, lane i lands at base+16i)
__device__ __forceinline__ void async_cp16(const void* gptr, void* lds) {
  auto g1 = reinterpret_cast<const __attribute__((address_space(1))) unsigned int*>(
      reinterpret_cast<uintptr_t>(gptr));
  auto l3 = reinterpret_cast<__attribute__((address_space(3))) unsigned int*>(
      reinterpret_cast<uintptr_t>(lds));
  __builtin_amdgcn_global_load_lds(g1, l3, 16, 0, 0);
}

// tiled bf16 layout: value (m,k), Ktiles=K/32:
//   idx = ((m>>4)*Ktiles + (k>>5))*512 + ((m&15) + 16*((k>>3)&3))*8 + (k&7)

// score layout (row-contiguous granules): ushort index
//   (row*64 + bn)*128 + (wc*16 + lcol)*4 + j   where col = bn*128 + wc*64 + j*16 + lcol
// -> per (row,bn): 256B contiguous; per row: 16KB contiguous.

// ---------------------------------------------------------------------------
// Cast fp32 x + 6 weight matrices into bf16 frag-tiled layout.
// ---------------------------------------------------------------------------
__global__ __launch_bounds__(256) void wcast_kernel(
    const float* __restrict__ x, const float* __restrict__ fc1w,
    const float* __restrict__ whw, const float* __restrict__ wtw,
    const float* __restrict__ l1w, const float* __restrict__ l2w,
    const float* __restrict__ a1w,
    unsigned short* __restrict__ xT, unsigned short* __restrict__ fc1T,
    unsigned short* __restrict__ whT, unsigned short* __restrict__ wtT,
    unsigned short* __restrict__ l1T, unsigned short* __restrict__ l2T,
    unsigned short* __restrict__ a1T)
{
  const int gid = blockIdx.x * 256 + threadIdx.x;  // 0 .. 565247
  const float* src; unsigned short* dst; int K8, local;
  if (gid < 417792) {
    K8 = 48;
    if (gid < 393216) { src = x; dst = xT; local = gid; }
    else { src = fc1w; dst = fc1T; local = gid - 393216; }
  } else {
    K8 = 64;
    if (gid < 450560)      { src = whw; dst = whT; local = gid - 417792; }
    else if (gid < 483328) { src = wtw; dst = wtT; local = gid - 450560; }
    else if (gid < 516096) { src = l1w; dst = l1T; local = gid - 483328; }
    else if (gid < 548864) { src = l2w; dst = l2T; local = gid - 516096; }
    else                   { src = a1w; dst = a1T; local = gid - 548864; }
  }
  const int m = local / K8;
  const int k8 = local - m * K8;
  const float* p = src + (size_t)m * (K8 * 8) + k8 * 8;
  float4 v0 = ((const float4*)p)[0];
  float4 v1 = ((const float4*)p)[1];
  const int Kt = K8 >> 2;
  const size_t ti = ((size_t)(m >> 4) * Kt + (k8 >> 2)) * 512 + ((m & 15) + 16 * (k8 & 3)) * 8;
  uint4 pk;
  pk.x = (uint32_t)f2bf(v0.x) | ((uint32_t)f2bf(v0.y) << 16);
  pk.y = (uint32_t)f2bf(v0.z) | ((uint32_t)f2bf(v0.w) << 16);
  pk.z = (uint32_t)f2bf(v1.x) | ((uint32_t)f2bf(v1.y) << 16);
  pk.w = (uint32_t)f2bf(v1.z) | ((uint32_t)f2bf(v1.w) << 16);
  *(uint4*)(dst + ti) = pk;
}

// ---------------------------------------------------------------------------
// MFMA GEMM, tile 128(M) x 64(N), 4 waves each 32x64, K-step 32.
// MODE 1: T1/T2 = bf16 tiled; Cbf/Cbf2 = bf16 row-major (both linear outputs)
// MODE 2: e = lrelu(A1@W1^T+b1)+lrelu(A2@W2^T+b2); T1 = bf16(e) tiled;
//         Cbf = bf16(e) row-major
// MODE 3: g[r] += sum_c lrelu(A@W1^T+b1)[r,c] * b2[c]  (fused gate readout)
// MODE 4: Cbf = bf16(lrelu(A@W1^T+b1)) row-major + colsum atomics into Cf
// ---------------------------------------------------------------------------
template <int MODE>
__global__ __launch_bounds__(256) void mfma_gemm(
    const unsigned short* __restrict__ At1, const unsigned short* __restrict__ At2,
    const unsigned short* __restrict__ Wt1, const unsigned short* __restrict__ Wt2,
    const float* __restrict__ b1, const float* __restrict__ b2,
    float* __restrict__ Cf, unsigned short* __restrict__ T1,
    unsigned short* __restrict__ T2, unsigned short* __restrict__ Cbf,
    unsigned short* __restrict__ Cbf2, int N, int K)
{
  constexpr bool DUALW = (MODE == 1 || MODE == 2);
  __shared__ unsigned short As[2][8 * 512];
  __shared__ unsigned short Bs[2][4 * 512];
  const int Kt = K >> 5;
  const int tid = threadIdx.x, lane = tid & 63, w = tid >> 6;
  const int m0 = blockIdx.y * 128, n0 = blockIdx.x * 64;

  f32x4 acc0[2][4], acc1[2][4];
#pragma unroll
  for (int p = 0; p < 2; p++)
#pragma unroll
    for (int j = 0; j < 4; j++) {
      acc0[p][j] = (f32x4){0.f, 0.f, 0.f, 0.f};
      acc1[p][j] = (f32x4){0.f, 0.f, 0.f, 0.f};
    }

  for (int kt = 0; kt < Kt; kt++) {
    const unsigned short* a1p = At1 + ((size_t)((m0 >> 4) + 2 * w) * Kt + kt) * 512 + lane * 8;
    async_cp16(a1p, &As[0][(2 * w) * 512]);
    async_cp16(a1p + (size_t)Kt * 512, &As[0][(2 * w + 1) * 512]);
    if (MODE == 2) {
      const unsigned short* a2p = At2 + ((size_t)((m0 >> 4) + 2 * w) * Kt + kt) * 512 + lane * 8;
      async_cp16(a2p, &As[1][(2 * w) * 512]);
      async_cp16(a2p + (size_t)Kt * 512, &As[1][(2 * w + 1) * 512]);
    }
    const unsigned short* bp1 = Wt1 + ((size_t)((n0 >> 4) + w) * Kt + kt) * 512 + lane * 8;
    async_cp16(bp1, &Bs[0][w * 512]);
    if (DUALW) {
      const unsigned short* bp2 = Wt2 + ((size_t)((n0 >> 4) + w) * Kt + kt) * 512 + lane * 8;
      async_cp16(bp2, &Bs[1][w * 512]);
    }
    __syncthreads();
    short8 a[2], a2[2], bb[4], bb2[4];
#pragma unroll
    for (int p = 0; p < 2; p++) a[p] = *(const short8*)&As[0][(2 * w + p) * 512 + lane * 8];
    if (MODE == 2) {
#pragma unroll
      for (int p = 0; p < 2; p++) a2[p] = *(const short8*)&As[1][(2 * w + p) * 512 + lane * 8];
    }
#pragma unroll
    for (int j = 0; j < 4; j++) bb[j] = *(const short8*)&Bs[0][j * 512 + lane * 8];
    if (DUALW) {
#pragma unroll
      for (int j = 0; j < 4; j++) bb2[j] = *(const short8*)&Bs[1][j * 512 + lane * 8];
    }
#pragma unroll
    for (int p = 0; p < 2; p++)
#pragma unroll
      for (int j = 0; j < 4; j++) {
        acc0[p][j] = __builtin_amdgcn_mfma_f32_16x16x32_bf16(a[p], bb[j], acc0[p][j], 0, 0, 0);
        if (MODE == 1)
          acc1[p][j] = __builtin_amdgcn_mfma_f32_16x16x32_bf16(a[p], bb2[j], acc1[p][j], 0, 0, 0);
        if (MODE == 2)
          acc1[p][j] = __builtin_amdgcn_mfma_f32_16x16x32_bf16(a2[p], bb2[j], acc1[p][j], 0, 0, 0);
      }
    __syncthreads();
  }

  const int lrow = (lane >> 4) * 4, lcol = lane & 15;

  if (MODE == 3) {
    // fused gate: partial dot over this block's 64 cols, reduce over lcol
    float part[2][4] = {};
#pragma unroll
    for (int p = 0; p < 2; p++)
#pragma unroll
      for (int j = 0; j < 4; j++) {
        const int c = n0 + j * 16 + lcol;
        const float bias1 = b1[c];
        const float w2 = b2[c];
#pragma unroll
        for (int d = 0; d < 4; d++)
          part[p][d] = fmaf(lrelu(acc0[p][j][d] + bias1), w2, part[p][d]);
      }
#pragma unroll
    for (int p = 0; p < 2; p++)
#pragma unroll
      for (int d = 0; d < 4; d++) {
#pragma unroll
        for (int off = 1; off < 16; off <<= 1)
          part[p][d] += __shfl_xor(part[p][d], off);
      }
    if (lcol == 0) {
#pragma unroll
      for (int p = 0; p < 2; p++)
#pragma unroll
        for (int d = 0; d < 4; d++)
          atomicAdd(&Cf[m0 + w * 32 + p * 16 + lrow + d], part[p][d]);
    }
    return;
  }

  if (MODE == 4) {
    // bf16 row-major store + fused column-sum atomics
    float colp[4] = {};
#pragma unroll
    for (int p = 0; p < 2; p++)
#pragma unroll
      for (int j = 0; j < 4; j++) {
        const int c = n0 + j * 16 + lcol;
        const float bias1 = b1[c];
#pragma unroll
        for (int d = 0; d < 4; d++) {
          const int r = m0 + w * 32 + p * 16 + lrow + d;
          const float v = lrelu(acc0[p][j][d] + bias1);
          Cbf[(size_t)r * N + c] = f2bf(v);
          colp[j] += v;
        }
      }
#pragma unroll
    for (int j = 0; j < 4; j++) {
      colp[j] += __shfl_xor(colp[j], 16);
      colp[j] += __shfl_xor(colp[j], 32);
    }
    if (lane < 16) {
#pragma unroll
      for (int j = 0; j < 4; j++)
        atomicAdd(&Cf[n0 + j * 16 + lcol], colp[j]);
    }
    return;
  }

  const int NT = N >> 5;
#pragma unroll
  for (int p = 0; p < 2; p++)
#pragma unroll
    for (int j = 0; j < 4; j++) {
      const int c = n0 + j * 16 + lcol;
      const float bias1 = b1[c];
      const float bias2 = DUALW ? b2[c] : 0.f;
#pragma unroll
      for (int d = 0; d < 4; d++) {
        const int r = m0 + w * 32 + p * 16 + lrow + d;
        const float v0 = acc0[p][j][d] + bias1;
        const size_t ti = ((size_t)(r >> 4) * NT + (c >> 5)) * 512 +
                          ((r & 15) + 16 * ((c >> 3) & 3)) * 8 + (c & 7);
        if (MODE == 1) {
          const float v1 = acc1[p][j][d] + bias2;
          T1[ti] = f2bf(v0);
          T2[ti] = f2bf(v1);
          Cbf[(size_t)r * N + c] = f2bf(v0);
          Cbf2[(size_t)r * N + c] = f2bf(v1);
        } else {
          const float e = lrelu(v0) + lrelu(acc1[p][j][d] + bias2);
          T1[ti] = f2bf(e);
          Cbf[(size_t)r * N + c] = f2bf(e);
        }
      }
    }
}

// ---------------------------------------------------------------------------
// h' = (h_bf16 + colmean)*0.5 fused with bf16 tiled cast (Ktiles=16)
// ---------------------------------------------------------------------------
__global__ __launch_bounds__(256) void hupd_cast_kernel(
    const unsigned short* __restrict__ hRow, const float* __restrict__ colsum,
    unsigned short* __restrict__ hT)
{
  const int gid = blockIdx.x * 256 + threadIdx.x;  // 8192*64
  const int m = gid >> 6, k8 = gid & 63;
  short8 hv = *(const short8*)(hRow + (size_t)m * E_DIM + k8 * 8);
  float4 c0 = *(const float4*)(colsum + k8 * 8);
  float4 c1 = *(const float4*)(colsum + k8 * 8 + 4);
  const float im = 1.f / (float)M_NODES;
  float v[8];
#pragma unroll
  for (int e = 0; e < 8; e++) v[e] = bf2f((unsigned short)hv[e]);
  v[0] = (v[0] + c0.x * im) * 0.5f; v[1] = (v[1] + c0.y * im) * 0.5f;
  v[2] = (v[2] + c0.z * im) * 0.5f; v[3] = (v[3] + c0.w * im) * 0.5f;
  v[4] = (v[4] + c1.x * im) * 0.5f; v[5] = (v[5] + c1.y * im) * 0.5f;
  v[6] = (v[6] + c1.z * im) * 0.5f; v[7] = (v[7] + c1.w * im) * 0.5f;
  const size_t ti = ((size_t)(m >> 4) * 16 + (k8 >> 2)) * 512 + ((m & 15) + 16 * (k8 & 3)) * 8;
  uint4 pk;
  pk.x = (uint32_t)f2bf(v[0]) | ((uint32_t)f2bf(v[1]) << 16);
  pk.y = (uint32_t)f2bf(v[2]) | ((uint32_t)f2bf(v[3]) << 16);
  pk.z = (uint32_t)f2bf(v[4]) | ((uint32_t)f2bf(v[5]) << 16);
  pk.w = (uint32_t)f2bf(v[6]) | ((uint32_t)f2bf(v[7]) << 16);
  *(uint4*)(hT + ti) = pk;
}

// ---------------------------------------------------------------------------
// Full score GEMM: row-contiguous 8B-granule bf16 store + seg maxima from the
// bf16-ROUNDED values (must match stored scores exactly — R8 lesson).
// ---------------------------------------------------------------------------
__global__ __launch_bounds__(256, 4) void sgemm_kernel(
    const unsigned short* __restrict__ ehT, const unsigned short* __restrict__ etT,
    unsigned short* __restrict__ sc, float* __restrict__ tmax)
{
  __shared__ unsigned short As[8 * 512];
  __shared__ unsigned short Bs[8 * 512];
  const int tid = threadIdx.x, lane = tid & 63, w = tid >> 6;
  const int wr = w >> 1, wc = w & 1;
  const int m0 = blockIdx.y * 128;
  const int n0 = blockIdx.x * 128;

  f32x4 acc[4][4];
#pragma unroll
  for (int i = 0; i < 4; i++)
#pragma unroll
    for (int j = 0; j < 4; j++) acc[i][j] = (f32x4){0.f, 0.f, 0.f, 0.f};

  for (int kt = 0; kt < 16; kt++) {
    const int s0 = w, s1 = w + 4;
    async_cp16(ehT + ((size_t)((m0 >> 4) + s0) * 16 + kt) * 512 + lane * 8, &As[s0 * 512]);
    async_cp16(ehT + ((size_t)((m0 >> 4) + s1) * 16 + kt) * 512 + lane * 8, &As[s1 * 512]);
    async_cp16(etT + ((size_t)((n0 >> 4) + s0) * 16 + kt) * 512 + lane * 8, &Bs[s0 * 512]);
    async_cp16(etT + ((size_t)((n0 >> 4) + s1) * 16 + kt) * 512 + lane * 8, &Bs[s1 * 512]);
    __syncthreads();
    short8 a[4], b[4];
#pragma unroll
    for (int i = 0; i < 4; i++) a[i] = *(const short8*)&As[(wr * 4 + i) * 512 + lane * 8];
#pragma unroll
    for (int j = 0; j < 4; j++) b[j] = *(const short8*)&Bs[(wc * 4 + j) * 512 + lane * 8];
#pragma unroll
    for (int i = 0; i < 4; i++)
#pragma unroll
      for (int j = 0; j < 4; j++)
        acc[i][j] = __builtin_amdgcn_mfma_f32_16x16x32_bf16(a[i], b[j], acc[i][j], 0, 0, 0);
    __syncthreads();
  }

  // epilogue: row-contiguous 8B granules (C layout: col=lane&15, row=q*4+d)
  const int q = lane >> 4, lcol = lane & 15;
  const int bn = blockIdx.x;

  float rm[4][4];
#pragma unroll
  for (int i = 0; i < 4; i++)
#pragma unroll
    for (int d = 0; d < 4; d++) rm[i][d] = NEG_BIG;

#pragma unroll
  for (int i = 0; i < 4; i++)
#pragma unroll
    for (int d = 0; d < 4; d++) {
      unsigned short o[4];
#pragma unroll
      for (int j = 0; j < 4; j++) {
        o[j] = f2bf(acc[i][j][d]);
        rm[i][d] = fmaxf(rm[i][d], bf2f(o[j]));
      }
      const int row = m0 + wr * 64 + i * 16 + q * 4 + d;
      const size_t off = ((size_t)row * 64 + bn) * 128 + (wc * 16 + lcol) * 4;
      *(uint2*)(sc + off) = *(uint2*)o;
    }

  // butterfly max across the 16-lane lcol group (same q)
#pragma unroll
  for (int i = 0; i < 4; i++)
#pragma unroll
    for (int d = 0; d < 4; d++) {
#pragma unroll
      for (int off = 1; off < 16; off <<= 1)
        rm[i][d] = fmaxf(rm[i][d], __shfl_xor(rm[i][d], off));
    }

  if (lcol == 0) {
#pragma unroll
    for (int i = 0; i < 4; i++)
#pragma unroll
      for (int d = 0; d < 4; d++)
        tmax[(size_t)(m0 + wr * 64 + i * 16 + q * 4 + d) * 128 +
             bn * 2 + wc] = rm[i][d];
  }
}

// ---------------------------------------------------------------------------
// Fused exact top-6 (threshold prefilter + block skipping) + combine.
// One wave per row. Phase A: tau + per-128col block skip mask. Phase B: scan
// only candidate blocks (~21/64, 256B coalesced each). Phase C: rank-select
// -> LDS top6. Phase D: softmax/gather/gate/e_Nh -> s1T/s2T.
// ---------------------------------------------------------------------------
__global__ __launch_bounds__(256) void scan_combine_kernel(
    const unsigned short* __restrict__ sc, const float* __restrict__ tmax,
    const unsigned short* __restrict__ ehRow, const unsigned short* __restrict__ etRow,
    unsigned short* __restrict__ s1T, unsigned short* __restrict__ s2T)
{
  __shared__ float cv[4][CAND_CAP];
  __shared__ int   ci[4][CAND_CAP];
  __shared__ int   cnt[4];
  __shared__ float t6v[4][8];
  __shared__ int   t6i[4][8];
  const int tid = threadIdx.x;
  const int lane = tid & 63;
  const int w = tid >> 6;
  const int row = blockIdx.x * 4 + w;

  if (lane == 0) cnt[w] = 0;
  if (lane < 8) { t6v[w][lane] = 0.f; t6i[w][lane] = 0; }

  // Phase A: tau from 128 segment maxima + 64 block maxima for skipping
  const float* tm = tmax + (size_t)row * 128;
  const float v2 = fmaxf(tm[lane], tm[lane + 64]);
  const float bmax = fmaxf(tm[2 * lane], tm[2 * lane + 1]);
  uint32_t u = __float_as_uint(v2);
  u = ((int)u >= 0) ? (u | 0x80000000u) : ~u;
  uint32_t key = (u & ~63u) | (uint32_t)lane;
  float tau = 0.f;
#pragma unroll
  for (int it = 0; it < 6; it++) {
    uint32_t k = key;
#pragma unroll
    for (int off = 32; off; off >>= 1) {
      const uint32_t o = (uint32_t)__shfl_xor((int)k, off);
      k = k > o ? k : o;
    }
    const int wl = (int)(k & 63u);
    if (it == 5) tau = __shfl(v2, wl);
    if (lane == wl) key = 0u;
  }

  // Phase B: scan only blocks whose max >= tau (wave-uniform mask)
  unsigned long long mask = __ballot(bmax >= tau);
  const unsigned short* rp = sc + (size_t)row * 8192;  // 64 bn * 128 ushorts
  while (mask) {
    const int bn = __ffsll(mask) - 1;
    mask &= mask - 1;
    const uint32_t uu = *(const uint32_t*)(rp + bn * 128 + lane * 2);
    const float f0 = bf2f((unsigned short)(uu & 0xFFFFu));
    const float f1 = bf2f((unsigned short)(uu >> 16));
#pragma unroll
    for (int e = 0; e < 2; e++) {
      const float f = e ? f1 : f0;
      if (f >= tau) {
        const int idx128 = lane * 2 + e;
        const int g = idx128 >> 2, j = idx128 & 3;
        const int col = bn * 128 + (g >> 4) * 64 + j * 16 + (g & 15);
        const int slot = atomicAdd(&cnt[w], 1);
        if (slot < CAND_CAP) { cv[w][slot] = f; ci[w][slot] = col; }
      }
    }
  }
  __syncthreads();

  // Phase C: rank-select (ties -> lower index first, matching lax.top_k)
  int n = cnt[w];
  n = n < CAND_CAP ? n : CAND_CAP;
  for (int c = lane; c < n; c += 64) {
    const float v = cv[w][c];
    const int idx = ci[w][c];
    int rank = 0;
    for (int j = 0; j < n; j++) {
      const float vj = cv[w][j];
      rank += (vj > v) || (vj == v && ci[w][j] < idx);
    }
    if (rank < NTOPK) { t6v[w][rank] = v; t6i[w][rank] = idx; }
  }
  __syncthreads();

  // Phase D: combine for row m = row
  const int m = row;
  float wv[NTOPK]; int id[NTOPK];
#pragma unroll
  for (int k = 0; k < NTOPK; k++) {
    wv[k] = t6v[w][k] * ATTN_SCALE;
    id[k] = t6i[w][k];
  }

  float mx = wv[0];
#pragma unroll
  for (int k = 1; k < NTOPK; k++) mx = fmaxf(mx, wv[k]);
  float p[NTOPK]; float s = 0.f;
#pragma unroll
  for (int k = 0; k < NTOPK; k++) { p[k] = expf(wv[k] - mx); s += p[k]; }
  const float inv = 1.f / s;
#pragma unroll
  for (int k = 0; k < NTOPK; k++) p[k] *= inv;

  short8 eh8 = *(const short8*)(ehRow + (size_t)m * E_DIM + lane * 8);
  float ehv[8];
#pragma unroll
  for (int e = 0; e < 8; e++) ehv[e] = bf2f((unsigned short)eh8[e]);

  float nv[NTOPK][8];
#pragma unroll
  for (int k = 0; k < NTOPK; k++) {
    short8 nb = *(const short8*)(etRow + (size_t)id[k] * E_DIM + lane * 8);
#pragma unroll
    for (int e = 0; e < 8; e++) nv[k][e] = bf2f((unsigned short)nb[e]);
  }

  float ka[NTOPK];
#pragma unroll
  for (int k = 0; k < NTOPK; k++) {
    float snb = 0.f, sg = 0.f;
    const float aa = 2.f - p[k], bb = p[k];
#pragma unroll
    for (int e = 0; e < 8; e++) {
      snb += nv[k][e];
      sg += tanhf(fmaf(aa, ehv[e], bb * nv[k][e]));
    }
#pragma unroll
    for (int off = 32; off; off >>= 1) {
      snb += __shfl_xor(snb, off);
      sg += __shfl_xor(sg, off);
    }
    ka[k] = snb * sg;
  }
  float km = ka[0];
#pragma unroll
  for (int k = 1; k < NTOPK; k++) km = fmaxf(km, ka[k]);
  float kp[NTOPK]; float ks = 0.f;
#pragma unroll
  for (int k = 0; k < NTOPK; k++) { kp[k] = expf(ka[k] - km); ks += kp[k]; }
  const float kinv = 1.f / ks;

  const size_t tbase = ((size_t)(m >> 4) * 16 + (lane >> 2)) * 512 +
                       ((m & 15) + 16 * (lane & 3)) * 8;
  unsigned short o1[8], o2[8];
#pragma unroll
  for (int e = 0; e < 8; e++) {
    float o = 0.f;
#pragma unroll
    for (int k = 0; k < NTOPK; k++) o = fmaf(kp[k], nv[k][e], o);
    o *= kinv;
    o1[e] = f2bf(ehv[e] + o);
    o2[e] = f2bf(ehv[e] * o);
  }
  *(short8*)(s1T + tbase) = *(short8*)o1;
  *(short8*)(s2T + tbase) = *(short8*)o2;
}

// ---------------------------------------------------------------------------
// pooled: unshifted exp(g) weights (|g| small, fp32-safe) + wsum atomic.
// ---------------------------------------------------------------------------
__global__ __launch_bounds__(256) void pooled_kernel(
    const unsigned short* __restrict__ emb, const float* __restrict__ g,
    float* __restrict__ pooled, float* __restrict__ wsum)
{
  const int t = threadIdx.x;
  const int r0 = blockIdx.x * 128;
  float a0 = 0.f, a1 = 0.f, lsum = 0.f;
  for (int r = 0; r < 128; r++) {
    const int m = r0 + r;
    const float wv = expf(g[m]);
    lsum += wv;
    a0 = fmaf(wv, bf2f(emb[(size_t)m * E_DIM + t]), a0);
    a1 = fmaf(wv, bf2f(emb[(size_t)m * E_DIM + 256 + t]), a1);
  }
  atomicAdd(&pooled[t], a0);
  atomicAdd(&pooled[t + 256], a1);
  if (t == 0) atomicAdd(wsum, lsum);
}

__global__ __launch_bounds__(512) void ln_kernel(
    const float* __restrict__ pooled, const float* __restrict__ wsum,
    const float* __restrict__ lng, const float* __restrict__ lnb,
    float* __restrict__ out)
{
  __shared__ float red[8];
  __shared__ float red2[8];
  const int t = threadIdx.x;
  const float v = pooled[t] / wsum[0];
  float s = v;
#pragma unroll
  for (int off = 32; off; off >>= 1) s += __shfl_xor(s, off);
  if ((t & 63) == 0) red[t >> 6] = s;
  __syncthreads();
  float tot = 0.f;
  for (int i = 0; i < 8; i++) tot += red[i];
  const float mu = tot / (float)E_DIM;
  const float d = v - mu;
  float q = d * d;
#pragma unroll
  for (int off = 32; off; off >>= 1) q += __shfl_xor(q, off);
  if ((t & 63) == 0) red2[t >> 6] = q;
  __syncthreads();
  float vt = 0.f;
  for (int i = 0; i < 8; i++) vt += red2[i];
  const float var = vt / (float)E_DIM;
  out[t] = d * rsqrtf(var + 1e-5f) * lng[t] + lnb[t];
}

// ---------------------------------------------------------------------------
extern "C" void kernel_launch(void* const* d_in, const int* in_sizes, int n_in,
                              void* d_out, int out_size, void* d_ws, size_t ws_size,
                              hipStream_t stream)
{
  const float* x     = (const float*)d_in[0];
  const float* fc1_w = (const float*)d_in[1];
  const float* fc1_b = (const float*)d_in[2];
  const float* wh_w  = (const float*)d_in[3];
  const float* wh_b  = (const float*)d_in[4];
  const float* wt_w  = (const float*)d_in[5];
  const float* wt_b  = (const float*)d_in[6];
  const float* l1_w  = (const float*)d_in[7];
  const float* l1_b  = (const float*)d_in[8];
  const float* l2_w  = (const float*)d_in[9];
  const float* l2_b  = (const float*)d_in[10];
  const float* a1_w  = (const float*)d_in[11];
  const float* a1_b  = (const float*)d_in[12];
  const float* a2_w  = (const float*)d_in[13];
  const float* a2_b  = (const float*)d_in[14];
  const float* ln_g  = (const float*)d_in[15];
  const float* ln_b  = (const float*)d_in[16];
  (void)a2_b;  // exactly cancels in softmax (shift invariance)

  char* ws = (char*)d_ws;
  const size_t MiB = 1 << 20;
  // weight tiles [0, 3M) — live whole run
  unsigned short* fc1T = (unsigned short*)(ws + 0);
  unsigned short* whT  = (unsigned short*)(ws + 393216);
  unsigned short* wtT  = (unsigned short*)(ws + 917504);
  unsigned short* l1T  = (unsigned short*)(ws + 1441792);
  unsigned short* l2T  = (unsigned short*)(ws + 1966080);
  unsigned short* a1T  = (unsigned short*)(ws + 2490368);
  // activations:
  unsigned short* xT     = (unsigned short*)(ws + 3 * MiB);    // [3,9) wcast->gemm1
  unsigned short* hRow   = (unsigned short*)(ws + 9 * MiB);    // [9,17) gemm1->hupd
  unsigned short* hT     = (unsigned short*)(ws + 25 * MiB);   // [25,33) hupd->gemm2
  unsigned short* ehT    = (unsigned short*)(ws + 33 * MiB);   // [33,41) gemm2->sgemm
  unsigned short* etT    = (unsigned short*)(ws + 41 * MiB);   // [41,49) gemm2->sgemm
  unsigned short* ehRow  = (unsigned short*)(ws + 49 * MiB);   // [49,57) gemm2->scan_combine
  unsigned short* etRow  = (unsigned short*)(ws + 57 * MiB);   // [57,65) gemm2->scan_combine
  float*          tmaxb  = (float*)(ws + 65 * MiB);            // [65,69) sgemm->scan (4MB)
  unsigned short* s1T    = (unsigned short*)(ws + 3 * MiB);    // [3,11) scan_combine->gemm3
  unsigned short* s2T    = (unsigned short*)(ws + 11 * MiB);   // [11,19) scan_combine->gemm3
  unsigned short* embT   = (unsigned short*)(ws + 19 * MiB);   // [19,27) gemm3->gemm4
  unsigned short* embRow = (unsigned short*)(ws + 27 * MiB);   // [27,35) gemm3->pooled
  unsigned short* scores = (unsigned short*)(ws + 96 * MiB);   // [96,224) sgemm->scan
  char*           smal   = ws + 69 * MiB;
  float* colsum = (float*)(smal);            // 2048 B
  float* g      = (float*)(smal + 4096);     // 32768 B
  float* stats  = (float*)(smal + 36864);    // wsum
  float* pooled = (float*)(smal + 40960);    // 2048 B

  // zero colsum/g/wsum/pooled accumulators
  hipMemsetAsync(smal, 0, 43008, stream);

  // 0. cast x + all weights to bf16 tiled
  wcast_kernel<<<2208, 256, 0, stream>>>(x, fc1_w, wh_w, wt_w, l1_w, l2_w, a1_w,
                                         xT, fc1T, whT, wtT, l1T, l2T, a1T);
  // 1. h = lrelu(x @ fc1^T + b) -> bf16 row + fused column sums
  mfma_gemm<4><<<dim3(8, 64), 256, 0, stream>>>(
      xT, nullptr, fc1T, nullptr, fc1_b, nullptr, colsum, nullptr, nullptr, hRow, nullptr,
      512, 384);
  // 2. mix with colmean + bf16 tiled cast
  hupd_cast_kernel<<<2048, 256, 0, stream>>>(hRow, colsum, hT);
  // 3. e_h, e_t: tiled (for sgemm) + row-major (for combine)
  mfma_gemm<1><<<dim3(8, 64), 256, 0, stream>>>(
      hT, nullptr, whT, wtT, wh_b, wt_b, nullptr, ehT, etT, ehRow, etRow, 512, 512);
  // 4. full score GEMM (row-granule store + rounded seg maxima)
  sgemm_kernel<<<dim3(64, 64), 256, 0, stream>>>(ehT, etT, scores, tmaxb);
  // 5. fused exact top-6 (block-skipping scan) + combine -> s1T, s2T
  scan_combine_kernel<<<M_NODES / 4, 256, 0, stream>>>(
      scores, tmaxb, ehRow, etRow, s1T, s2T);
  // 6. emb = lrelu(s1@l1^T+b1)+lrelu(s2@l2^T+b2) -> bf16 tiled + bf16 row
  mfma_gemm<2><<<dim3(8, 64), 256, 0, stream>>>(
      s1T, s2T, l1T, l2T, l1_b, l2_b, nullptr, embT, nullptr, embRow, nullptr, 512, 512);
  // 7+8 fused: g[m] = sum_c lrelu(emb@a1^T+b)[m,c] * a2w[c]
  mfma_gemm<3><<<dim3(4, 64), 256, 0, stream>>>(
      embT, nullptr, a1T, nullptr, a1_b, a2_w, g, nullptr, nullptr, nullptr, nullptr,
      256, 512);
  // 9-10. pooled (fused softmax weights) + layernorm
  pooled_kernel<<<64, 256, 0, stream>>>(embRow, g, pooled, stats);
  ln_kernel<<<1, 512, 0, stream>>>(pooled, stats, ln_g, ln_b, (float*)d_out);
}

// Round 12
// 293.743 us; speedup vs baseline: 2.9722x; 1.0428x over previous
//
#include <hip/hip_runtime.h>
#include <math.h>
#include <stdint.h>

#define M_NODES 8192
#define E_DIM   512
#define NTOPK   6
#define ATTN_SCALE 0.04419417382415922f  // 512^-0.5
#define NEG_BIG (-1e38f)
#define CAND_CAP 192

typedef __attribute__((ext_vector_type(8))) short short8;
typedef __attribute__((ext_vector_type(4))) float f32x4;

__device__ __forceinline__ float lrelu(float v) { return v > 0.f ? v : 0.01f * v; }

__device__ __forceinline__ unsigned short f2bf(float f) {
  uint32_t u = __float_as_uint(f);
  uint32_t r = (u + 0x7FFFu + ((u >> 16) & 1u)) >> 16;
  return (unsigned short)r;
}
__device__ __forceinline__ float bf2f(unsigned short s) {
  return __uint_as_float(((uint32_t)s) << 16);
}

// async 16B/lane global->LDS (wave-uniform LDS base, lane i lands at base+16i)
__device__ __forceinline__ void async_cp16(const void* gptr, void* lds) {
  auto g1 = reinterpret_cast<const __attribute__((address_space(1))) unsigned int*>(
      reinterpret_cast<uintptr_t>(gptr));
  auto l3 = reinterpret_cast<__attribute__((address_space(3))) unsigned int*>(
      reinterpret_cast<uintptr_t>(lds));
  __builtin_amdgcn_global_load_lds(g1, l3, 16, 0, 0);
}

// tiled bf16 layout: value (m,k), Ktiles=K/32:
//   idx = ((m>>4)*Ktiles + (k>>5))*512 + ((m&15) + 16*((k>>3)&3))*8 + (k&7)

// score layout (row-contiguous granules): ushort index
//   (row*64 + bn)*128 + (wc*16 + lcol)*4 + j   where col = bn*128 + wc*64 + j*16 + lcol

// ---------------------------------------------------------------------------
// Cast fp32 x + 6 weight matrices into bf16 frag-tiled layout.
// ---------------------------------------------------------------------------
__global__ __launch_bounds__(256) void wcast_kernel(
    const float* __restrict__ x, const float* __restrict__ fc1w,
    const float* __restrict__ whw, const float* __restrict__ wtw,
    const float* __restrict__ l1w, const float* __restrict__ l2w,
    const float* __restrict__ a1w,
    unsigned short* __restrict__ xT, unsigned short* __restrict__ fc1T,
    unsigned short* __restrict__ whT, unsigned short* __restrict__ wtT,
    unsigned short* __restrict__ l1T, unsigned short* __restrict__ l2T,
    unsigned short* __restrict__ a1T)
{
  const int gid = blockIdx.x * 256 + threadIdx.x;  // 0 .. 565247
  const float* src; unsigned short* dst; int K8, local;
  if (gid < 417792) {
    K8 = 48;
    if (gid < 393216) { src = x; dst = xT; local = gid; }
    else { src = fc1w; dst = fc1T; local = gid - 393216; }
  } else {
    K8 = 64;
    if (gid < 450560)      { src = whw; dst = whT; local = gid - 417792; }
    else if (gid < 483328) { src = wtw; dst = wtT; local = gid - 450560; }
    else if (gid < 516096) { src = l1w; dst = l1T; local = gid - 483328; }
    else if (gid < 548864) { src = l2w; dst = l2T; local = gid - 516096; }
    else                   { src = a1w; dst = a1T; local = gid - 548864; }
  }
  const int m = local / K8;
  const int k8 = local - m * K8;
  const float* p = src + (size_t)m * (K8 * 8) + k8 * 8;
  float4 v0 = ((const float4*)p)[0];
  float4 v1 = ((const float4*)p)[1];
  const int Kt = K8 >> 2;
  const size_t ti = ((size_t)(m >> 4) * Kt + (k8 >> 2)) * 512 + ((m & 15) + 16 * (k8 & 3)) * 8;
  uint4 pk;
  pk.x = (uint32_t)f2bf(v0.x) | ((uint32_t)f2bf(v0.y) << 16);
  pk.y = (uint32_t)f2bf(v0.z) | ((uint32_t)f2bf(v0.w) << 16);
  pk.z = (uint32_t)f2bf(v1.x) | ((uint32_t)f2bf(v1.y) << 16);
  pk.w = (uint32_t)f2bf(v1.z) | ((uint32_t)f2bf(v1.w) << 16);
  *(uint4*)(dst + ti) = pk;
}

// ---------------------------------------------------------------------------
// gemm1: hT = bf16(0.5*lrelu(x @ fc1^T + b)) tiled + fused column sums.
// sgemm-structure 128x128 tile, grid (4,64), K=384 (Kt=12).
// ---------------------------------------------------------------------------
__global__ __launch_bounds__(256, 4) void gemm1_kernel(
    const unsigned short* __restrict__ xT, const unsigned short* __restrict__ fc1T,
    const float* __restrict__ b1, unsigned short* __restrict__ hT,
    float* __restrict__ colsum)
{
  __shared__ unsigned short As[8 * 512];
  __shared__ unsigned short Bs[8 * 512];
  const int tid = threadIdx.x, lane = tid & 63, w = tid >> 6;
  const int wr = w >> 1, wc = w & 1;
  const int m0 = blockIdx.y * 128;
  const int n0 = blockIdx.x * 128;

  f32x4 acc[4][4];
#pragma unroll
  for (int i = 0; i < 4; i++)
#pragma unroll
    for (int j = 0; j < 4; j++) acc[i][j] = (f32x4){0.f, 0.f, 0.f, 0.f};

  for (int kt = 0; kt < 12; kt++) {
    const int s0 = w, s1 = w + 4;
    async_cp16(xT + ((size_t)((m0 >> 4) + s0) * 12 + kt) * 512 + lane * 8, &As[s0 * 512]);
    async_cp16(xT + ((size_t)((m0 >> 4) + s1) * 12 + kt) * 512 + lane * 8, &As[s1 * 512]);
    async_cp16(fc1T + ((size_t)((n0 >> 4) + s0) * 12 + kt) * 512 + lane * 8, &Bs[s0 * 512]);
    async_cp16(fc1T + ((size_t)((n0 >> 4) + s1) * 12 + kt) * 512 + lane * 8, &Bs[s1 * 512]);
    __syncthreads();
    short8 a[4], b[4];
#pragma unroll
    for (int i = 0; i < 4; i++) a[i] = *(const short8*)&As[(wr * 4 + i) * 512 + lane * 8];
#pragma unroll
    for (int j = 0; j < 4; j++) b[j] = *(const short8*)&Bs[(wc * 4 + j) * 512 + lane * 8];
#pragma unroll
    for (int i = 0; i < 4; i++)
#pragma unroll
      for (int j = 0; j < 4; j++)
        acc[i][j] = __builtin_amdgcn_mfma_f32_16x16x32_bf16(a[i], b[j], acc[i][j], 0, 0, 0);
    __syncthreads();
  }

  const int q = lane >> 4, lcol = lane & 15;
  float colp[4] = {};
#pragma unroll
  for (int i = 0; i < 4; i++)
#pragma unroll
    for (int j = 0; j < 4; j++) {
      const int c = n0 + wc * 64 + j * 16 + lcol;
      const float bias = b1[c];
#pragma unroll
      for (int d = 0; d < 4; d++) {
        const int r = m0 + wr * 64 + i * 16 + q * 4 + d;
        const float v = 0.5f * lrelu(acc[i][j][d] + bias);
        hT[((size_t)(r >> 4) * 16 + (c >> 5)) * 512 +
           ((r & 15) + 16 * ((c >> 3) & 3)) * 8 + (c & 7)] = f2bf(v);
        colp[j] += v;
      }
    }
#pragma unroll
  for (int j = 0; j < 4; j++) {
    colp[j] += __shfl_xor(colp[j], 16);
    colp[j] += __shfl_xor(colp[j], 32);
  }
  if (lane < 16) {
#pragma unroll
    for (int j = 0; j < 4; j++)
      atomicAdd(&colsum[n0 + wc * 64 + j * 16 + lcol], colp[j]);
  }
}

// ---------------------------------------------------------------------------
// meanproj: biasHT[c1024] = {wh_b|wt_b}[c] + (colsum/M) . {wh_w|wt_w}[c,:]
// (colsum holds 0.5-scaled sums, so this is Wh·(0.5·mean).) One wave per c.
// ---------------------------------------------------------------------------
__global__ __launch_bounds__(256) void meanproj_kernel(
    const float* __restrict__ colsum, const float* __restrict__ whw,
    const float* __restrict__ wtw, const float* __restrict__ whb,
    const float* __restrict__ wtb, float* __restrict__ biasHT)
{
  const int lane = threadIdx.x & 63;
  const int c1024 = blockIdx.x * 4 + (threadIdx.x >> 6);
  const bool isH = c1024 < 512;
  const int c = isH ? c1024 : c1024 - 512;
  const float* W = (isH ? whw : wtw) + (size_t)c * 512 + lane * 8;
  const float* cs = colsum + lane * 8;
  float s = 0.f;
#pragma unroll
  for (int e = 0; e < 8; e++) s = fmaf(cs[e], W[e], s);
#pragma unroll
  for (int off = 32; off; off >>= 1) s += __shfl_xor(s, off);
  if (lane == 0)
    biasHT[c1024] = (isH ? whb : wtb)[c] + s * (1.f / (float)M_NODES);
}

// ---------------------------------------------------------------------------
// dual_gemm: [e_h | e_t] = hT @ [Wh|Wt]^T + biasHT  (stacked 1024-col weight,
// whT/wtT contiguous). sgemm-structure 128x128 tile, grid (8,64). Outputs:
// tiled (for sgemm) + row-major (for combine); H/T split is block-uniform.
// ---------------------------------------------------------------------------
__global__ __launch_bounds__(256, 4) void dual_gemm(
    const unsigned short* __restrict__ hT, const unsigned short* __restrict__ wstackT,
    const float* __restrict__ biasHT,
    unsigned short* __restrict__ ehT, unsigned short* __restrict__ etT,
    unsigned short* __restrict__ ehRow, unsigned short* __restrict__ etRow)
{
  __shared__ unsigned short As[8 * 512];
  __shared__ unsigned short Bs[8 * 512];
  const int tid = threadIdx.x, lane = tid & 63, w = tid >> 6;
  const int wr = w >> 1, wc = w & 1;
  const int m0 = blockIdx.y * 128;
  const int n0 = blockIdx.x * 128;  // [0,1024)

  f32x4 acc[4][4];
#pragma unroll
  for (int i = 0; i < 4; i++)
#pragma unroll
    for (int j = 0; j < 4; j++) acc[i][j] = (f32x4){0.f, 0.f, 0.f, 0.f};

  for (int kt = 0; kt < 16; kt++) {
    const int s0 = w, s1 = w + 4;
    async_cp16(hT + ((size_t)((m0 >> 4) + s0) * 16 + kt) * 512 + lane * 8, &As[s0 * 512]);
    async_cp16(hT + ((size_t)((m0 >> 4) + s1) * 16 + kt) * 512 + lane * 8, &As[s1 * 512]);
    async_cp16(wstackT + ((size_t)((n0 >> 4) + s0) * 16 + kt) * 512 + lane * 8, &Bs[s0 * 512]);
    async_cp16(wstackT + ((size_t)((n0 >> 4) + s1) * 16 + kt) * 512 + lane * 8, &Bs[s1 * 512]);
    __syncthreads();
    short8 a[4], b[4];
#pragma unroll
    for (int i = 0; i < 4; i++) a[i] = *(const short8*)&As[(wr * 4 + i) * 512 + lane * 8];
#pragma unroll
    for (int j = 0; j < 4; j++) b[j] = *(const short8*)&Bs[(wc * 4 + j) * 512 + lane * 8];
#pragma unroll
    for (int i = 0; i < 4; i++)
#pragma unroll
      for (int j = 0; j < 4; j++)
        acc[i][j] = __builtin_amdgcn_mfma_f32_16x16x32_bf16(a[i], b[j], acc[i][j], 0, 0, 0);
    __syncthreads();
  }

  const int q = lane >> 4, lcol = lane & 15;
  const bool isH = (n0 < 512);                 // block-uniform
  const int cb = isH ? n0 : (n0 - 512);
  unsigned short* T = isH ? ehT : etT;
  unsigned short* R = isH ? ehRow : etRow;

#pragma unroll
  for (int i = 0; i < 4; i++)
#pragma unroll
    for (int j = 0; j < 4; j++) {
      const int cl = wc * 64 + j * 16 + lcol;
      const float bias = biasHT[n0 + cl];
      const int c = cb + cl;
#pragma unroll
      for (int d = 0; d < 4; d++) {
        const int r = m0 + wr * 64 + i * 16 + q * 4 + d;
        const unsigned short us = f2bf(acc[i][j][d] + bias);
        T[((size_t)(r >> 4) * 16 + (c >> 5)) * 512 +
          ((r & 15) + 16 * ((c >> 3) & 3)) * 8 + (c & 7)] = us;
        R[(size_t)r * E_DIM + c] = us;
      }
    }
}

// ---------------------------------------------------------------------------
// MFMA GEMM, tile 128(M) x 64(N), 4 waves each 32x64, K-step 32.
// MODE 2: e = lrelu(A1@W1^T+b1)+lrelu(A2@W2^T+b2); T1 = bf16(e) tiled;
//         Cbf = bf16(e) row-major
// MODE 3: g[r] += sum_c lrelu(A@W1^T+b1)[r,c] * b2[c]  (fused gate readout)
// ---------------------------------------------------------------------------
template <int MODE>
__global__ __launch_bounds__(256) void mfma_gemm(
    const unsigned short* __restrict__ At1, const unsigned short* __restrict__ At2,
    const unsigned short* __restrict__ Wt1, const unsigned short* __restrict__ Wt2,
    const float* __restrict__ b1, const float* __restrict__ b2,
    float* __restrict__ Cf, unsigned short* __restrict__ T1,
    unsigned short* __restrict__ Cbf, int N, int K)
{
  constexpr bool DUALW = (MODE == 2);
  __shared__ unsigned short As[2][8 * 512];
  __shared__ unsigned short Bs[2][4 * 512];
  const int Kt = K >> 5;
  const int tid = threadIdx.x, lane = tid & 63, w = tid >> 6;
  const int m0 = blockIdx.y * 128, n0 = blockIdx.x * 64;

  f32x4 acc0[2][4], acc1[2][4];
#pragma unroll
  for (int p = 0; p < 2; p++)
#pragma unroll
    for (int j = 0; j < 4; j++) {
      acc0[p][j] = (f32x4){0.f, 0.f, 0.f, 0.f};
      acc1[p][j] = (f32x4){0.f, 0.f, 0.f, 0.f};
    }

  for (int kt = 0; kt < Kt; kt++) {
    const unsigned short* a1p = At1 + ((size_t)((m0 >> 4) + 2 * w) * Kt + kt) * 512 + lane * 8;
    async_cp16(a1p, &As[0][(2 * w) * 512]);
    async_cp16(a1p + (size_t)Kt * 512, &As[0][(2 * w + 1) * 512]);
    if (MODE == 2) {
      const unsigned short* a2p = At2 + ((size_t)((m0 >> 4) + 2 * w) * Kt + kt) * 512 + lane * 8;
      async_cp16(a2p, &As[1][(2 * w) * 512]);
      async_cp16(a2p + (size_t)Kt * 512, &As[1][(2 * w + 1) * 512]);
    }
    const unsigned short* bp1 = Wt1 + ((size_t)((n0 >> 4) + w) * Kt + kt) * 512 + lane * 8;
    async_cp16(bp1, &Bs[0][w * 512]);
    if (DUALW) {
      const unsigned short* bp2 = Wt2 + ((size_t)((n0 >> 4) + w) * Kt + kt) * 512 + lane * 8;
      async_cp16(bp2, &Bs[1][w * 512]);
    }
    __syncthreads();
    short8 a[2], a2[2], bb[4], bb2[4];
#pragma unroll
    for (int p = 0; p < 2; p++) a[p] = *(const short8*)&As[0][(2 * w + p) * 512 + lane * 8];
    if (MODE == 2) {
#pragma unroll
      for (int p = 0; p < 2; p++) a2[p] = *(const short8*)&As[1][(2 * w + p) * 512 + lane * 8];
    }
#pragma unroll
    for (int j = 0; j < 4; j++) bb[j] = *(const short8*)&Bs[0][j * 512 + lane * 8];
    if (DUALW) {
#pragma unroll
      for (int j = 0; j < 4; j++) bb2[j] = *(const short8*)&Bs[1][j * 512 + lane * 8];
    }
#pragma unroll
    for (int p = 0; p < 2; p++)
#pragma unroll
      for (int j = 0; j < 4; j++) {
        acc0[p][j] = __builtin_amdgcn_mfma_f32_16x16x32_bf16(a[p], bb[j], acc0[p][j], 0, 0, 0);
        if (MODE == 2)
          acc1[p][j] = __builtin_amdgcn_mfma_f32_16x16x32_bf16(a2[p], bb2[j], acc1[p][j], 0, 0, 0);
      }
    __syncthreads();
  }

  const int lrow = (lane >> 4) * 4, lcol = lane & 15;

  if (MODE == 3) {
    float part[2][4] = {};
#pragma unroll
    for (int p = 0; p < 2; p++)
#pragma unroll
      for (int j = 0; j < 4; j++) {
        const int c = n0 + j * 16 + lcol;
        const float bias1 = b1[c];
        const float w2 = b2[c];
#pragma unroll
        for (int d = 0; d < 4; d++)
          part[p][d] = fmaf(lrelu(acc0[p][j][d] + bias1), w2, part[p][d]);
      }
#pragma unroll
    for (int p = 0; p < 2; p++)
#pragma unroll
      for (int d = 0; d < 4; d++) {
#pragma unroll
        for (int off = 1; off < 16; off <<= 1)
          part[p][d] += __shfl_xor(part[p][d], off);
      }
    if (lcol == 0) {
#pragma unroll
      for (int p = 0; p < 2; p++)
#pragma unroll
        for (int d = 0; d < 4; d++)
          atomicAdd(&Cf[m0 + w * 32 + p * 16 + lrow + d], part[p][d]);
    }
    return;
  }

  const int NT = N >> 5;
#pragma unroll
  for (int p = 0; p < 2; p++)
#pragma unroll
    for (int j = 0; j < 4; j++) {
      const int c = n0 + j * 16 + lcol;
      const float bias1 = b1[c];
      const float bias2 = b2[c];
#pragma unroll
      for (int d = 0; d < 4; d++) {
        const int r = m0 + w * 32 + p * 16 + lrow + d;
        const float e = lrelu(acc0[p][j][d] + bias1) + lrelu(acc1[p][j][d] + bias2);
        T1[((size_t)(r >> 4) * NT + (c >> 5)) * 512 +
           ((r & 15) + 16 * ((c >> 3) & 3)) * 8 + (c & 7)] = f2bf(e);
        Cbf[(size_t)r * N + c] = f2bf(e);
      }
    }
}

// ---------------------------------------------------------------------------
// Full score GEMM: row-contiguous 8B-granule bf16 store + seg maxima from the
// bf16-ROUNDED values (must match stored scores exactly — R8 lesson).
// ---------------------------------------------------------------------------
__global__ __launch_bounds__(256, 4) void sgemm_kernel(
    const unsigned short* __restrict__ ehT, const unsigned short* __restrict__ etT,
    unsigned short* __restrict__ sc, float* __restrict__ tmax)
{
  __shared__ unsigned short As[8 * 512];
  __shared__ unsigned short Bs[8 * 512];
  const int tid = threadIdx.x, lane = tid & 63, w = tid >> 6;
  const int wr = w >> 1, wc = w & 1;
  const int m0 = blockIdx.y * 128;
  const int n0 = blockIdx.x * 128;

  f32x4 acc[4][4];
#pragma unroll
  for (int i = 0; i < 4; i++)
#pragma unroll
    for (int j = 0; j < 4; j++) acc[i][j] = (f32x4){0.f, 0.f, 0.f, 0.f};

  for (int kt = 0; kt < 16; kt++) {
    const int s0 = w, s1 = w + 4;
    async_cp16(ehT + ((size_t)((m0 >> 4) + s0) * 16 + kt) * 512 + lane * 8, &As[s0 * 512]);
    async_cp16(ehT + ((size_t)((m0 >> 4) + s1) * 16 + kt) * 512 + lane * 8, &As[s1 * 512]);
    async_cp16(etT + ((size_t)((n0 >> 4) + s0) * 16 + kt) * 512 + lane * 8, &Bs[s0 * 512]);
    async_cp16(etT + ((size_t)((n0 >> 4) + s1) * 16 + kt) * 512 + lane * 8, &Bs[s1 * 512]);
    __syncthreads();
    short8 a[4], b[4];
#pragma unroll
    for (int i = 0; i < 4; i++) a[i] = *(const short8*)&As[(wr * 4 + i) * 512 + lane * 8];
#pragma unroll
    for (int j = 0; j < 4; j++) b[j] = *(const short8*)&Bs[(wc * 4 + j) * 512 + lane * 8];
#pragma unroll
    for (int i = 0; i < 4; i++)
#pragma unroll
      for (int j = 0; j < 4; j++)
        acc[i][j] = __builtin_amdgcn_mfma_f32_16x16x32_bf16(a[i], b[j], acc[i][j], 0, 0, 0);
    __syncthreads();
  }

  const int q = lane >> 4, lcol = lane & 15;
  const int bn = blockIdx.x;

  float rm[4][4];
#pragma unroll
  for (int i = 0; i < 4; i++)
#pragma unroll
    for (int d = 0; d < 4; d++) rm[i][d] = NEG_BIG;

#pragma unroll
  for (int i = 0; i < 4; i++)
#pragma unroll
    for (int d = 0; d < 4; d++) {
      unsigned short o[4];
#pragma unroll
      for (int j = 0; j < 4; j++) {
        o[j] = f2bf(acc[i][j][d]);
        rm[i][d] = fmaxf(rm[i][d], bf2f(o[j]));
      }
      const int row = m0 + wr * 64 + i * 16 + q * 4 + d;
      const size_t off = ((size_t)row * 64 + bn) * 128 + (wc * 16 + lcol) * 4;
      *(uint2*)(sc + off) = *(uint2*)o;
    }

#pragma unroll
  for (int i = 0; i < 4; i++)
#pragma unroll
    for (int d = 0; d < 4; d++) {
#pragma unroll
      for (int off = 1; off < 16; off <<= 1)
        rm[i][d] = fmaxf(rm[i][d], __shfl_xor(rm[i][d], off));
    }

  if (lcol == 0) {
#pragma unroll
    for (int i = 0; i < 4; i++)
#pragma unroll
      for (int d = 0; d < 4; d++)
        tmax[(size_t)(m0 + wr * 64 + i * 16 + q * 4 + d) * 128 +
             bn * 2 + wc] = rm[i][d];
  }
}

// ---------------------------------------------------------------------------
// Fused exact top-6 (threshold prefilter + block skipping) + combine.
// ---------------------------------------------------------------------------
__global__ __launch_bounds__(256) void scan_combine_kernel(
    const unsigned short* __restrict__ sc, const float* __restrict__ tmax,
    const unsigned short* __restrict__ ehRow, const unsigned short* __restrict__ etRow,
    unsigned short* __restrict__ s1T, unsigned short* __restrict__ s2T)
{
  __shared__ float cv[4][CAND_CAP];
  __shared__ int   ci[4][CAND_CAP];
  __shared__ int   cnt[4];
  __shared__ float t6v[4][8];
  __shared__ int   t6i[4][8];
  const int tid = threadIdx.x;
  const int lane = tid & 63;
  const int w = tid >> 6;
  const int row = blockIdx.x * 4 + w;

  if (lane == 0) cnt[w] = 0;
  if (lane < 8) { t6v[w][lane] = 0.f; t6i[w][lane] = 0; }

  // Phase A: tau from 128 segment maxima + 64 block maxima for skipping
  const float* tm = tmax + (size_t)row * 128;
  const float v2 = fmaxf(tm[lane], tm[lane + 64]);
  const float bmax = fmaxf(tm[2 * lane], tm[2 * lane + 1]);
  uint32_t u = __float_as_uint(v2);
  u = ((int)u >= 0) ? (u | 0x80000000u) : ~u;
  uint32_t key = (u & ~63u) | (uint32_t)lane;
  float tau = 0.f;
#pragma unroll
  for (int it = 0; it < 6; it++) {
    uint32_t k = key;
#pragma unroll
    for (int off = 32; off; off >>= 1) {
      const uint32_t o = (uint32_t)__shfl_xor((int)k, off);
      k = k > o ? k : o;
    }
    const int wl = (int)(k & 63u);
    if (it == 5) tau = __shfl(v2, wl);
    if (lane == wl) key = 0u;
  }

  // Phase B: scan only blocks whose max >= tau (wave-uniform mask)
  unsigned long long mask = __ballot(bmax >= tau);
  const unsigned short* rp = sc + (size_t)row * 8192;
  while (mask) {
    const int bn = __ffsll(mask) - 1;
    mask &= mask - 1;
    const uint32_t uu = *(const uint32_t*)(rp + bn * 128 + lane * 2);
    const float f0 = bf2f((unsigned short)(uu & 0xFFFFu));
    const float f1 = bf2f((unsigned short)(uu >> 16));
#pragma unroll
    for (int e = 0; e < 2; e++) {
      const float f = e ? f1 : f0;
      if (f >= tau) {
        const int idx128 = lane * 2 + e;
        const int g = idx128 >> 2, j = idx128 & 3;
        const int col = bn * 128 + (g >> 4) * 64 + j * 16 + (g & 15);
        const int slot = atomicAdd(&cnt[w], 1);
        if (slot < CAND_CAP) { cv[w][slot] = f; ci[w][slot] = col; }
      }
    }
  }
  __syncthreads();

  // Phase C: rank-select (ties -> lower index first, matching lax.top_k)
  int n = cnt[w];
  n = n < CAND_CAP ? n : CAND_CAP;
  for (int c = lane; c < n; c += 64) {
    const float v = cv[w][c];
    const int idx = ci[w][c];
    int rank = 0;
    for (int j = 0; j < n; j++) {
      const float vj = cv[w][j];
      rank += (vj > v) || (vj == v && ci[w][j] < idx);
    }
    if (rank < NTOPK) { t6v[w][rank] = v; t6i[w][rank] = idx; }
  }
  __syncthreads();

  // Phase D: combine for row m = row
  const int m = row;
  float wv[NTOPK]; int id[NTOPK];
#pragma unroll
  for (int k = 0; k < NTOPK; k++) {
    wv[k] = t6v[w][k] * ATTN_SCALE;
    id[k] = t6i[w][k];
  }

  float mx = wv[0];
#pragma unroll
  for (int k = 1; k < NTOPK; k++) mx = fmaxf(mx, wv[k]);
  float p[NTOPK]; float s = 0.f;
#pragma unroll
  for (int k = 0; k < NTOPK; k++) { p[k] = expf(wv[k] - mx); s += p[k]; }
  const float inv = 1.f / s;
#pragma unroll
  for (int k = 0; k < NTOPK; k++) p[k] *= inv;

  short8 eh8 = *(const short8*)(ehRow + (size_t)m * E_DIM + lane * 8);
  float ehv[8];
#pragma unroll
  for (int e = 0; e < 8; e++) ehv[e] = bf2f((unsigned short)eh8[e]);

  float nv[NTOPK][8];
#pragma unroll
  for (int k = 0; k < NTOPK; k++) {
    short8 nb = *(const short8*)(etRow + (size_t)id[k] * E_DIM + lane * 8);
#pragma unroll
    for (int e = 0; e < 8; e++) nv[k][e] = bf2f((unsigned short)nb[e]);
  }

  float ka[NTOPK];
#pragma unroll
  for (int k = 0; k < NTOPK; k++) {
    float snb = 0.f, sg = 0.f;
    const float aa = 2.f - p[k], bb = p[k];
#pragma unroll
    for (int e = 0; e < 8; e++) {
      snb += nv[k][e];
      sg += tanhf(fmaf(aa, ehv[e], bb * nv[k][e]));
    }
#pragma unroll
    for (int off = 32; off; off >>= 1) {
      snb += __shfl_xor(snb, off);
      sg += __shfl_xor(sg, off);
    }
    ka[k] = snb * sg;
  }
  float km = ka[0];
#pragma unroll
  for (int k = 1; k < NTOPK; k++) km = fmaxf(km, ka[k]);
  float kp[NTOPK]; float ks = 0.f;
#pragma unroll
  for (int k = 0; k < NTOPK; k++) { kp[k] = expf(ka[k] - km); ks += kp[k]; }
  const float kinv = 1.f / ks;

  const size_t tbase = ((size_t)(m >> 4) * 16 + (lane >> 2)) * 512 +
                       ((m & 15) + 16 * (lane & 3)) * 8;
  unsigned short o1[8], o2[8];
#pragma unroll
  for (int e = 0; e < 8; e++) {
    float o = 0.f;
#pragma unroll
    for (int k = 0; k < NTOPK; k++) o = fmaf(kp[k], nv[k][e], o);
    o *= kinv;
    o1[e] = f2bf(ehv[e] + o);
    o2[e] = f2bf(ehv[e] * o);
  }
  *(short8*)(s1T + tbase) = *(short8*)o1;
  *(short8*)(s2T + tbase) = *(short8*)o2;
}

// ---------------------------------------------------------------------------
// pooled: unshifted exp(g) weights (|g| small, fp32-safe) + wsum atomic.
// ---------------------------------------------------------------------------
__global__ __launch_bounds__(256) void pooled_kernel(
    const unsigned short* __restrict__ emb, const float* __restrict__ g,
    float* __restrict__ pooled, float* __restrict__ wsum)
{
  const int t = threadIdx.x;
  const int r0 = blockIdx.x * 128;
  float a0 = 0.f, a1 = 0.f, lsum = 0.f;
  for (int r = 0; r < 128; r++) {
    const int m = r0 + r;
    const float wv = expf(g[m]);
    lsum += wv;
    a0 = fmaf(wv, bf2f(emb[(size_t)m * E_DIM + t]), a0);
    a1 = fmaf(wv, bf2f(emb[(size_t)m * E_DIM + 256 + t]), a1);
  }
  atomicAdd(&pooled[t], a0);
  atomicAdd(&pooled[t + 256], a1);
  if (t == 0) atomicAdd(wsum, lsum);
}

__global__ __launch_bounds__(512) void ln_kernel(
    const float* __restrict__ pooled, const float* __restrict__ wsum,
    const float* __restrict__ lng, const float* __restrict__ lnb,
    float* __restrict__ out)
{
  __shared__ float red[8];
  __shared__ float red2[8];
  const int t = threadIdx.x;
  const float v = pooled[t] / wsum[0];
  float s = v;
#pragma unroll
  for (int off = 32; off; off >>= 1) s += __shfl_xor(s, off);
  if ((t & 63) == 0) red[t >> 6] = s;
  __syncthreads();
  float tot = 0.f;
  for (int i = 0; i < 8; i++) tot += red[i];
  const float mu = tot / (float)E_DIM;
  const float d = v - mu;
  float q = d * d;
#pragma unroll
  for (int off = 32; off; off >>= 1) q += __shfl_xor(q, off);
  if ((t & 63) == 0) red2[t >> 6] = q;
  __syncthreads();
  float vt = 0.f;
  for (int i = 0; i < 8; i++) vt += red2[i];
  const float var = vt / (float)E_DIM;
  out[t] = d * rsqrtf(var + 1e-5f) * lng[t] + lnb[t];
}

// ---------------------------------------------------------------------------
extern "C" void kernel_launch(void* const* d_in, const int* in_sizes, int n_in,
                              void* d_out, int out_size, void* d_ws, size_t ws_size,
                              hipStream_t stream)
{
  const float* x     = (const float*)d_in[0];
  const float* fc1_w = (const float*)d_in[1];
  const float* fc1_b = (const float*)d_in[2];
  const float* wh_w  = (const float*)d_in[3];
  const float* wh_b  = (const float*)d_in[4];
  const float* wt_w  = (const float*)d_in[5];
  const float* wt_b  = (const float*)d_in[6];
  const float* l1_w  = (const float*)d_in[7];
  const float* l1_b  = (const float*)d_in[8];
  const float* l2_w  = (const float*)d_in[9];
  const float* l2_b  = (const float*)d_in[10];
  const float* a1_w  = (const float*)d_in[11];
  const float* a1_b  = (const float*)d_in[12];
  const float* a2_w  = (const float*)d_in[13];
  const float* a2_b  = (const float*)d_in[14];
  const float* ln_g  = (const float*)d_in[15];
  const float* ln_b  = (const float*)d_in[16];
  (void)a2_b;  // exactly cancels in softmax (shift invariance)

  char* ws = (char*)d_ws;
  const size_t MiB = 1 << 20;
  // weight tiles [0, 3M) — live whole run. NOTE: whT/wtT and l1T/l2T are each
  // contiguous pairs -> valid stacked 1024-row tiled tensors.
  unsigned short* fc1T = (unsigned short*)(ws + 0);
  unsigned short* whT  = (unsigned short*)(ws + 393216);
  unsigned short* wtT  = (unsigned short*)(ws + 917504);
  unsigned short* l1T  = (unsigned short*)(ws + 1441792);
  unsigned short* l2T  = (unsigned short*)(ws + 1966080);
  unsigned short* a1T  = (unsigned short*)(ws + 2490368);
  // activations:
  unsigned short* xT     = (unsigned short*)(ws + 3 * MiB);    // [3,9) wcast->gemm1
  unsigned short* hT     = (unsigned short*)(ws + 25 * MiB);   // [25,33) gemm1->dual_gemm
  unsigned short* ehT    = (unsigned short*)(ws + 33 * MiB);   // [33,41) dual_gemm->sgemm
  unsigned short* etT    = (unsigned short*)(ws + 41 * MiB);   // [41,49) dual_gemm->sgemm
  unsigned short* ehRow  = (unsigned short*)(ws + 49 * MiB);   // [49,57) dual_gemm->scan_combine
  unsigned short* etRow  = (unsigned short*)(ws + 57 * MiB);   // [57,65) dual_gemm->scan_combine
  float*          tmaxb  = (float*)(ws + 65 * MiB);            // [65,69) sgemm->scan (4MB)
  unsigned short* s1T    = (unsigned short*)(ws + 3 * MiB);    // [3,11) scan_combine->gemm3
  unsigned short* s2T    = (unsigned short*)(ws + 11 * MiB);   // [11,19) scan_combine->gemm3
  unsigned short* embT   = (unsigned short*)(ws + 19 * MiB);   // [19,27) gemm3->gemm4
  unsigned short* embRow = (unsigned short*)(ws + 27 * MiB);   // [27,35) gemm3->pooled
  unsigned short* scores = (unsigned short*)(ws + 96 * MiB);   // [96,224) sgemm->scan
  char*           smal   = ws + 69 * MiB;
  float* colsum = (float*)(smal);            // [0, 2048)
  float* biasHT = (float*)(smal + 2048);     // [2048, 6144)
  float* g      = (float*)(smal + 8192);     // [8192, 40960)
  float* stats  = (float*)(smal + 40960);    // wsum
  float* pooled = (float*)(smal + 45056);    // [45056, 47104)

  // zero colsum/g/wsum/pooled accumulators (biasHT fully overwritten)
  hipMemsetAsync(smal, 0, 47104, stream);

  // 0. cast x + all weights to bf16 tiled
  wcast_kernel<<<2208, 256, 0, stream>>>(x, fc1_w, wh_w, wt_w, l1_w, l2_w, a1_w,
                                         xT, fc1T, whT, wtT, l1T, l2T, a1T);
  // 1. hT = bf16(0.5*lrelu(x@fc1^T+b)) tiled + fused column sums
  gemm1_kernel<<<dim3(4, 64), 256, 0, stream>>>(xT, fc1T, fc1_b, hT, colsum);
  // 2. rank-1 mean projection folded into e_h/e_t biases
  meanproj_kernel<<<256, 256, 0, stream>>>(colsum, wh_w, wt_w, wh_b, wt_b, biasHT);
  // 3. [e_h|e_t] = hT @ [Wh|Wt]^T + biasHT -> tiled + row-major
  dual_gemm<<<dim3(8, 64), 256, 0, stream>>>(hT, whT, biasHT, ehT, etT, ehRow, etRow);
  // 4. full score GEMM (row-granule store + rounded seg maxima)
  sgemm_kernel<<<dim3(64, 64), 256, 0, stream>>>(ehT, etT, scores, tmaxb);
  // 5. fused exact top-6 (block-skipping scan) + combine -> s1T, s2T
  scan_combine_kernel<<<M_NODES / 4, 256, 0, stream>>>(
      scores, tmaxb, ehRow, etRow, s1T, s2T);
  // 6. emb = lrelu(s1@l1^T+b1)+lrelu(s2@l2^T+b2) -> bf16 tiled + bf16 row
  mfma_gemm<2><<<dim3(8, 64), 256, 0, stream>>>(
      s1T, s2T, l1T, l2T, l1_b, l2_b, nullptr, embT, embRow, 512, 512);
  // 7+8 fused: g[m] = sum_c lrelu(emb@a1^T+b)[m,c] * a2w[c]
  mfma_gemm<3><<<dim3(4, 64), 256, 0, stream>>>(
      embT, nullptr, a1T, nullptr, a1_b, a2_w, g, nullptr, nullptr, 256, 512);
  // 9-10. pooled (fused softmax weights) + layernorm
  pooled_kernel<<<64, 256, 0, stream>>>(embRow, g, pooled, stats);
  ln_kernel<<<1, 512, 0, stream>>>(pooled, stats, ln_g, ln_b, (float*)d_out);
}